// Round 1
// baseline (2740.701 us; speedup 1.0000x reference)
//
#include <hip/hip_runtime.h>
#include <math.h>

constexpr int cB = 2, cC = 64, cH = 48, cW = 48, cL = 48 * 48;
constexpr int cBR = 128, cDI = 128, cNS = 16, cRK = 4, cK = 4;
constexpr float cEPS = 1e-5f;

__device__ __forceinline__ float bnrelu(float v, float g, float b) {
    float y = v * (g * rsqrtf(1.0f + cEPS)) + b;
    return y > 0.f ? y : 0.f;
}
__device__ __forceinline__ float silu(float v) {
    return v / (1.f + expf(-v));
}

// ---------------- pools ----------------
__global__ void k_pool3(const float* __restrict__ x, float* __restrict__ out) {
    int idx = blockIdx.x * 256 + threadIdx.x;
    if (idx >= cB * cC * cL) return;
    int w = idx % cW, h = (idx / cW) % cH, bc = idx / cL;
    const float* p = x + bc * cL;
    float s = 0.f;
    for (int dh = -1; dh <= 1; dh++) {
        int hh = h + dh; if (hh < 0 || hh >= cH) continue;
        for (int dw = -1; dw <= 1; dw++) {
            int ww = w + dw; if (ww < 0 || ww >= cW) continue;
            s += p[hh * cW + ww];
        }
    }
    out[idx] = s * (1.f / 9.f);
}

template <int KS, int ST, int PD, int OS>
__global__ void k_pool(const float* __restrict__ x, float* __restrict__ out) {
    int idx = blockIdx.x * 256 + threadIdx.x;
    if (idx >= cB * cC * OS * OS) return;
    int w = idx % OS, h = (idx / OS) % OS, bc = idx / (OS * OS);
    const float* p = x + bc * cL;
    float s = 0.f;
    for (int kh = 0; kh < KS; kh++) {
        int hh = h * ST - PD + kh; if (hh < 0 || hh >= cH) continue;
        for (int kw = 0; kw < KS; kw++) {
            int ww = w * ST - PD + kw; if (ww < 0 || ww >= cW) continue;
            s += p[hh * cW + ww];
        }
    }
    out[idx] = s * (1.f / (KS * KS));
}

__global__ void k_gmean(const float* __restrict__ x, float* __restrict__ out) {
    int bc = blockIdx.x;  // B*C blocks
    const float* p = x + bc * cL;
    float s = 0.f;
    for (int i = threadIdx.x; i < cL; i += 256) s += p[i];
    __shared__ float sm[4];
    for (int m = 32; m > 0; m >>= 1) s += __shfl_down(s, m);
    if ((threadIdx.x & 63) == 0) sm[threadIdx.x >> 6] = s;
    __syncthreads();
    if (threadIdx.x == 0) out[bc] = (sm[0] + sm[1] + sm[2] + sm[3]) * (1.f / cL);
}

// --------- bn_relu + 1x1 conv (64 -> 128), in (B,64,HW) out (B,128,HW) ---------
__global__ void __launch_bounds__(128) k_c1(const float* __restrict__ in, const float* __restrict__ g,
                                            const float* __restrict__ bb, const float* __restrict__ w,
                                            float* __restrict__ out, int HW) {
    int pos = blockIdx.x;
    int b = pos / HW, pp = pos % HW;
    __shared__ float v[64];
    int t = threadIdx.x;
    if (t < 64) v[t] = bnrelu(in[(b * 64 + t) * HW + pp], g[t], bb[t]);
    __syncthreads();
    float acc = 0.f;
    const float* wr = w + t * 64;
#pragma unroll 16
    for (int c = 0; c < 64; c++) acc += v[c] * wr[c];
    out[(b * 128 + t) * HW + pp] = acc;
}

// ---------------- bilinear (half-pixel, clamped) ----------------
__device__ __forceinline__ float bilin(const float* __restrict__ p, int S, float sy, float sx) {
    float fy = floorf(sy), fx = floorf(sx);
    int iy = (int)fy, ix = (int)fx;
    float ay = sy - fy, ax = sx - fx;
    int y0 = min(max(iy, 0), S - 1), y1 = min(max(iy + 1, 0), S - 1);
    int x0 = min(max(ix, 0), S - 1), x1 = min(max(ix + 1, 0), S - 1);
    float v00 = p[y0 * S + x0], v01 = p[y0 * S + x1];
    float v10 = p[y1 * S + x0], v11 = p[y1 * S + x1];
    float a = v00 + (v01 - v00) * ax;
    float b = v10 + (v11 - v10) * ax;
    return a + (b - a) * ay;
}

// ------- build cat (already bn_relu'd with comp params), layout (B,640,L) -------
__global__ void __launch_bounds__(128) k_cat(
    const float* __restrict__ x, const float* __restrict__ s0g, const float* __restrict__ s0b,
    const float* __restrict__ s0w, const float* __restrict__ s1g, const float* __restrict__ s1b,
    const float* __restrict__ s1w, const float* __restrict__ pool3, const float* __restrict__ c2,
    const float* __restrict__ c3, const float* __restrict__ c4, const float* __restrict__ cg,
    const float* __restrict__ cbb, float* __restrict__ catact) {
    int pos = blockIdx.x;
    int b = pos / cL, l = pos % cL;
    int h = l / cW, w = l % cW;
    __shared__ float xv[64], p3v[64];
    int t = threadIdx.x;
    if (t < 64) {
        xv[t] = bnrelu(x[(b * 64 + t) * cL + l], s0g[t], s0b[t]);
        p3v[t] = bnrelu(pool3[(b * 64 + t) * cL + l], s1g[t], s1b[t]);
    }
    __syncthreads();
    float x0 = 0.f, y1 = 0.f;
    const float* w0 = s0w + t * 64;
    const float* w1 = s1w + t * 64;
#pragma unroll 8
    for (int c = 0; c < 64; c++) { x0 += xv[c] * w0[c]; y1 += p3v[c] * w1[c]; }
    y1 += x0;
    float y2 = x0 + bilin(c2 + (b * 128 + t) * 576, 24, h * 0.5f - 0.25f, w * 0.5f - 0.25f);
    float y3 = x0 + bilin(c3 + (b * 128 + t) * 144, 12, h * 0.25f - 0.375f, w * 0.25f - 0.375f);
    float y4 = x0 + c4[b * 128 + t];
    float* base = catact + b * 640 * cL + l;
    base[(0 + t) * cL]   = bnrelu(x0, cg[t],       cbb[t]);
    base[(128 + t) * cL] = bnrelu(y1, cg[128 + t], cbb[128 + t]);
    base[(256 + t) * cL] = bnrelu(y2, cg[256 + t], cbb[256 + t]);
    base[(384 + t) * cL] = bnrelu(y3, cg[384 + t], cbb[384 + t]);
    base[(512 + t) * cL] = bnrelu(y4, cg[512 + t], cbb[512 + t]);
}

// ------- transpose comp_w (64,640,3,3) -> wt[(tap*640+ch)*64+o] -------
__global__ void k_wt(const float* __restrict__ cw, float* __restrict__ wt) {
    int idx = blockIdx.x * 256 + threadIdx.x;
    if (idx >= 64 * 640 * 9) return;
    int o = idx & 63;
    int rest = idx >> 6;
    int ch = rest % 640, tap = rest / 640;
    wt[idx] = cw[(o * 640 + ch) * 9 + tap];
}

// ------- comp 3x3 conv (640->64, pad 1) + shortcut 1x1, out p (B,64,L) -------
__global__ void __launch_bounds__(64) k_comp(const float* __restrict__ catact, const float* __restrict__ wt,
                                             const float* __restrict__ x, const float* __restrict__ scg,
                                             const float* __restrict__ scb, const float* __restrict__ scw,
                                             float* __restrict__ p) {
    int pos = blockIdx.x;
    int b = pos / cL, l = pos % cL;
    int h = l / cW, w = l % cW;
    int o = threadIdx.x;
    float acc = 0.f;
    const float* cb = catact + b * 640 * cL;
    for (int kh = 0; kh < 3; kh++) {
        int hh = h + kh - 1; if (hh < 0 || hh >= cH) continue;
        for (int kw = 0; kw < 3; kw++) {
            int ww = w + kw - 1; if (ww < 0 || ww >= cW) continue;
            const float* ap = cb + hh * cW + ww;
            const float* wp = wt + (kh * 3 + kw) * 640 * 64 + o;
#pragma unroll 8
            for (int ch = 0; ch < 640; ch++) acc += ap[ch * cL] * wp[ch * 64];
        }
    }
    float acc2 = 0.f;
    const float* xp = x + b * 64 * cL + l;
    const float* sw = scw + o * 64;
#pragma unroll 8
    for (int c = 0; c < 64; c++) acc2 += bnrelu(xp[c * cL], scg[c], scb[c]) * sw[c];
    p[(b * 64 + o) * cL + l] = acc + acc2;
}

// ------- in_proj: xz = p_vec @ W^T; xc -> (B,128,L), z -> (B,L,128) -------
__global__ void __launch_bounds__(256) k_inproj(const float* __restrict__ p, const float* __restrict__ wip,
                                                float* __restrict__ xc, float* __restrict__ z) {
    int pos = blockIdx.x;
    int b = pos / cL, l = pos % cL;
    __shared__ float v[64];
    int t = threadIdx.x;
    if (t < 64) v[t] = p[(b * 64 + t) * cL + l];
    __syncthreads();
    float acc = 0.f;
    const float* wr = wip + t * 64;
#pragma unroll 16
    for (int c = 0; c < 64; c++) acc += v[c] * wr[c];
    if (t < 128) xc[(b * 128 + t) * cL + l] = acc;
    else z[(b * cL + l) * 128 + (t - 128)] = acc;
}

// ------- depthwise 3x3 + bias + silu -------
__global__ void k_dw(const float* __restrict__ xc, const float* __restrict__ dww,
                     const float* __restrict__ dwb, float* __restrict__ xca) {
    int idx = blockIdx.x * 256 + threadIdx.x;
    if (idx >= cB * cDI * cL) return;
    int w = idx % cW, h = (idx / cW) % cH;
    int bd = idx / cL, d = bd % cDI;
    const float* pl = xc + bd * cL;
    float acc = dwb[d];
    const float* kw = dww + d * 9;
    for (int i = 0; i < 3; i++) {
        int hh = h + i - 1; if (hh < 0 || hh >= cH) continue;
        for (int j = 0; j < 3; j++) {
            int ww = w + j - 1; if (ww < 0 || ww >= cW) continue;
            acc += pl[hh * cW + ww] * kw[i * 3 + j];
        }
    }
    xca[idx] = silu(acc);
}

// xs index mapping: offset into the (H*W) plane for direction k at scan pos l
__device__ __forceinline__ int xs_index(int k, int l) {
    int lp = (k & 2) ? (cL - 1 - l) : l;
    if (k & 1) { int w = lp / cH, h = lp % cH; return h * cW + w; }
    return lp;
}

// ------- x_dbl[b,k,l,36] = xs[b,k,:,l] . x_proj_w[k,c,:] -------
__global__ void __launch_bounds__(64) k_xdbl(const float* __restrict__ xca, const float* __restrict__ xpw,
                                             float* __restrict__ xdbl) {
    int pos = blockIdx.x;  // (b*4+k)*L + l
    int l = pos % cL;
    int bk = pos / cL;
    int k = bk % 4, b = bk / 4;
    __shared__ float v[128];
    int t = threadIdx.x;
    int off = xs_index(k, l);
    const float* base = xca + b * 128 * cL + off;
    v[t] = base[t * cL];
    v[t + 64] = base[(t + 64) * cL];
    __syncthreads();
    if (t < 36) {
        const float* wr = xpw + (k * 36 + t) * 128;
        float acc = 0.f;
#pragma unroll 16
        for (int d = 0; d < 128; d++) acc += v[d] * wr[d];
        xdbl[pos * 36 + t] = acc;
    }
}

// ------- selective scan: block = (b,k,dgroup of 4); tid = ld*16 + n -------
__global__ void __launch_bounds__(64) k_scan(const float* __restrict__ xca, const float* __restrict__ xdbl,
                                             const float* __restrict__ dtw, const float* __restrict__ dtb,
                                             const float* __restrict__ Alogs, const float* __restrict__ Dsv,
                                             float* __restrict__ y) {
    int blk = blockIdx.x;  // (b*4+k)*32 + dg
    int dg = blk % 32;
    int bk = blk / 32;
    int k = bk % 4, b = bk / 4;
    int t = threadIdx.x;
    int ld = t >> 4, n = t & 15;
    int d = dg * 4 + ld;
    int kd = k * 128 + d;
    float A = -expf(Alogs[kd * 16 + n]);
    float w0 = dtw[kd * 4 + 0], w1 = dtw[kd * 4 + 1], w2 = dtw[kd * 4 + 2], w3 = dtw[kd * 4 + 3];
    float db = dtb[kd];
    float Dsd = Dsv[kd];
    const float* xrow = xca + (b * 128 + d) * cL;
    const float* xd = xdbl + (bk * cL) * 36;
    float* yrow = y + (bk * 128 + d) * cL;
    float h = 0.f;
    float p0, p1, p2, p3, pB, pC, px;
    p0 = xd[0]; p1 = xd[1]; p2 = xd[2]; p3 = xd[3];
    pB = xd[4 + n]; pC = xd[20 + n];
    px = xrow[xs_index(k, 0)];
    for (int l = 0; l < cL; l++) {
        float c0 = p0, c1 = p1, c2 = p2, c3 = p3, vB = pB, vC = pC, cx = px;
        if (l + 1 < cL) {
            const float* r = xd + (l + 1) * 36;
            p0 = r[0]; p1 = r[1]; p2 = r[2]; p3 = r[3];
            pB = r[4 + n]; pC = r[20 + n];
            px = xrow[xs_index(k, l + 1)];
        }
        float pre = db + w0 * c0 + w1 * c1 + w2 * c2 + w3 * c3;
        float delta = pre > 20.f ? pre : log1pf(expf(pre));
        float du = delta * cx;
        float a = expf(delta * A);
        h = a * h + du * vB;
        float contrib = h * vC;
        contrib += __shfl_xor(contrib, 1);
        contrib += __shfl_xor(contrib, 2);
        contrib += __shfl_xor(contrib, 4);
        contrib += __shfl_xor(contrib, 8);
        if (n == 0) yrow[l] = contrib + cx * Dsd;
    }
}

// ------- combine 4 dirs + layernorm + gate + out_proj -> x1 (B,64,L) -------
__global__ void __launch_bounds__(128) k_comb(const float* __restrict__ y, const float* __restrict__ z,
                                              const float* __restrict__ lng, const float* __restrict__ lnb,
                                              const float* __restrict__ opw, float* __restrict__ x1) {
    int pos = blockIdx.x;
    int b = pos / cL, l = pos % cL;
    int h = l / cW, w = l % cW;
    int lwh = w * cH + h;
    int t = threadIdx.x;  // d
    const float* yb = y + b * 4 * 128 * cL;
    float v = yb[(0 * 128 + t) * cL + l] + yb[(2 * 128 + t) * cL + (cL - 1 - l)] +
              yb[(1 * 128 + t) * cL + lwh] + yb[(3 * 128 + t) * cL + (cL - 1 - lwh)];
    __shared__ float red[2];
    __shared__ float vv[128];
    float s = v;
    for (int m = 32; m > 0; m >>= 1) s += __shfl_down(s, m);
    if ((t & 63) == 0) red[t >> 6] = s;
    __syncthreads();
    float mu = (red[0] + red[1]) * (1.f / 128.f);
    float dv = v - mu;
    float s2 = dv * dv;
    for (int m = 32; m > 0; m >>= 1) s2 += __shfl_down(s2, m);
    __syncthreads();
    if ((t & 63) == 0) red[t >> 6] = s2;
    __syncthreads();
    float var = (red[0] + red[1]) * (1.f / 128.f);
    float yn = dv * rsqrtf(var + cEPS) * lng[t] + lnb[t];
    float zz = z[(b * cL + l) * 128 + t];
    vv[t] = yn * silu(zz);
    __syncthreads();
    if (t < 64) {
        const float* wr = opw + t * 128;
        float acc = 0.f;
#pragma unroll 16
        for (int d2 = 0; d2 < 128; d2++) acc += vv[d2] * wr[d2];
        x1[(b * 64 + t) * cL + l] = acc;
    }
}

// ------- final MLP: silu(fc1(x1)) -> fc2 + residual -------
__global__ void __launch_bounds__(128) k_final(const float* __restrict__ x1, const float* __restrict__ f1w,
                                               const float* __restrict__ f1b, const float* __restrict__ f2w,
                                               const float* __restrict__ f2b, float* __restrict__ out) {
    int pos = blockIdx.x;
    int b = pos / cL, l = pos % cL;
    int t = threadIdx.x;
    __shared__ float xv[64], h1[128];
    if (t < 64) xv[t] = x1[(b * 64 + t) * cL + l];
    __syncthreads();
    float acc = f1b[t];
    const float* wr = f1w + t * 64;
#pragma unroll 16
    for (int c = 0; c < 64; c++) acc += xv[c] * wr[c];
    h1[t] = silu(acc);
    __syncthreads();
    if (t < 64) {
        float acc2 = f2b[t];
        const float* w2 = f2w + t * 128;
#pragma unroll 16
        for (int j = 0; j < 128; j++) acc2 += h1[j] * w2[j];
        out[(b * 64 + t) * cL + l] = acc2 + xv[t];
    }
}

extern "C" void kernel_launch(void* const* d_in, const int* in_sizes, int n_in,
                              void* d_out, int out_size, void* d_ws, size_t ws_size,
                              hipStream_t stream) {
    (void)in_sizes; (void)n_in; (void)out_size; (void)ws_size;
    const float* x    = (const float*)d_in[0];
    const float* s0g  = (const float*)d_in[1];
    const float* s0b  = (const float*)d_in[2];
    const float* s0w  = (const float*)d_in[3];
    const float* s1g  = (const float*)d_in[4];
    const float* s1b  = (const float*)d_in[5];
    const float* s1w  = (const float*)d_in[6];
    const float* s2g  = (const float*)d_in[7];
    const float* s2b  = (const float*)d_in[8];
    const float* s2w  = (const float*)d_in[9];
    const float* s3g  = (const float*)d_in[10];
    const float* s3b  = (const float*)d_in[11];
    const float* s3w  = (const float*)d_in[12];
    const float* s4g  = (const float*)d_in[13];
    const float* s4b  = (const float*)d_in[14];
    const float* s4w  = (const float*)d_in[15];
    const float* cg   = (const float*)d_in[16];
    const float* cbb  = (const float*)d_in[17];
    const float* cw   = (const float*)d_in[18];
    const float* scg  = (const float*)d_in[19];
    const float* scb  = (const float*)d_in[20];
    const float* scw  = (const float*)d_in[21];
    const float* ipw  = (const float*)d_in[22];
    const float* dww  = (const float*)d_in[23];
    const float* dwb  = (const float*)d_in[24];
    const float* xpw  = (const float*)d_in[25];
    const float* dtw  = (const float*)d_in[26];
    const float* dtb  = (const float*)d_in[27];
    const float* Alog = (const float*)d_in[28];
    const float* Dsv  = (const float*)d_in[29];
    const float* lng  = (const float*)d_in[30];
    const float* lnb  = (const float*)d_in[31];
    const float* opw  = (const float*)d_in[32];
    const float* f1w  = (const float*)d_in[33];
    const float* f1b  = (const float*)d_in[34];
    const float* f2w  = (const float*)d_in[35];
    const float* f2b  = (const float*)d_in[36];
    float* out = (float*)d_out;

    float* ws = (float*)d_ws;
    size_t off = 0;
    float* pool3  = ws + off; off += (size_t)cB * 64 * cL;        // 294912
    float* pool5  = ws + off; off += (size_t)cB * 64 * 576;       // 73728
    float* pool9  = ws + off; off += (size_t)cB * 64 * 144;       // 18432
    float* gmean  = ws + off; off += (size_t)cB * 64;             // 128
    float* c2     = ws + off; off += (size_t)cB * 128 * 576;      // 147456
    float* c3     = ws + off; off += (size_t)cB * 128 * 144;      // 36864
    float* c4     = ws + off; off += (size_t)cB * 128;            // 256
    float* catact = ws + off; off += (size_t)cB * 640 * cL;       // 2949120
    float* wt     = ws + off; off += (size_t)64 * 640 * 9;        // 368640
    float* pbuf   = ws + off; off += (size_t)cB * 64 * cL;        // 294912
    float* xc     = ws + off; off += (size_t)cB * 128 * cL;       // 589824
    float* xca    = ws + off; off += (size_t)cB * 128 * cL;       // 589824
    float* zbuf   = ws + off; off += (size_t)cB * cL * 128;       // 589824
    float* xdbl   = ws + off; off += (size_t)cB * 4 * cL * 36;    // 663552
    float* ybuf   = ws + off; off += (size_t)cB * 4 * 128 * cL;   // 2359296
    float* x1     = ws + off; off += (size_t)cB * 64 * cL;        // 294912

    k_pool3<<<(cB * 64 * cL + 255) / 256, 256, 0, stream>>>(x, pool3);
    k_pool<5, 2, 2, 24><<<(cB * 64 * 576 + 255) / 256, 256, 0, stream>>>(x, pool5);
    k_pool<9, 4, 4, 12><<<(cB * 64 * 144 + 255) / 256, 256, 0, stream>>>(x, pool9);
    k_gmean<<<cB * 64, 256, 0, stream>>>(x, gmean);
    k_c1<<<cB * 576, 128, 0, stream>>>(pool5, s2g, s2b, s2w, c2, 576);
    k_c1<<<cB * 144, 128, 0, stream>>>(pool9, s3g, s3b, s3w, c3, 144);
    k_c1<<<cB, 128, 0, stream>>>(gmean, s4g, s4b, s4w, c4, 1);
    k_wt<<<(64 * 640 * 9 + 255) / 256, 256, 0, stream>>>(cw, wt);
    k_cat<<<cB * cL, 128, 0, stream>>>(x, s0g, s0b, s0w, s1g, s1b, s1w, pool3, c2, c3, c4, cg, cbb, catact);
    k_comp<<<cB * cL, 64, 0, stream>>>(catact, wt, x, scg, scb, scw, pbuf);
    k_inproj<<<cB * cL, 256, 0, stream>>>(pbuf, ipw, xc, zbuf);
    k_dw<<<(cB * 128 * cL + 255) / 256, 256, 0, stream>>>(xc, dww, dwb, xca);
    k_xdbl<<<cB * 4 * cL, 64, 0, stream>>>(xca, xpw, xdbl);
    k_scan<<<cB * 4 * 32, 64, 0, stream>>>(xca, xdbl, dtw, dtb, Alog, Dsv, ybuf);
    k_comb<<<cB * cL, 128, 0, stream>>>(ybuf, zbuf, lng, lnb, opw, x1);
    k_final<<<cB * cL, 128, 0, stream>>>(x1, f1w, f1b, f2w, f2b, out);
}

// Round 2
// 731.538 us; speedup vs baseline: 3.7465x; 3.7465x over previous
//
#include <hip/hip_runtime.h>
#include <math.h>

constexpr int cB = 2, cC = 64, cH = 48, cW = 48, cL = 48 * 48;
constexpr int cBR = 128, cDI = 128, cNS = 16, cRK = 4, cK = 4;
constexpr float cEPS = 1e-5f;
constexpr int NCH = 16;          // scan chunks
constexpr int CHL = cL / NCH;    // 144 positions per chunk

__device__ __forceinline__ float bnrelu(float v, float g, float b) {
    float y = v * (g * rsqrtf(1.0f + cEPS)) + b;
    return y > 0.f ? y : 0.f;
}
__device__ __forceinline__ float silu(float v) {
    return v / (1.f + expf(-v));
}

// ---------------- pools ----------------
__global__ void k_pool3(const float* __restrict__ x, float* __restrict__ out) {
    int idx = blockIdx.x * 256 + threadIdx.x;
    if (idx >= cB * cC * cL) return;
    int w = idx % cW, h = (idx / cW) % cH, bc = idx / cL;
    const float* p = x + bc * cL;
    float s = 0.f;
    for (int dh = -1; dh <= 1; dh++) {
        int hh = h + dh; if (hh < 0 || hh >= cH) continue;
        for (int dw = -1; dw <= 1; dw++) {
            int ww = w + dw; if (ww < 0 || ww >= cW) continue;
            s += p[hh * cW + ww];
        }
    }
    out[idx] = s * (1.f / 9.f);
}

template <int KS, int ST, int PD, int OS>
__global__ void k_pool(const float* __restrict__ x, float* __restrict__ out) {
    int idx = blockIdx.x * 256 + threadIdx.x;
    if (idx >= cB * cC * OS * OS) return;
    int w = idx % OS, h = (idx / OS) % OS, bc = idx / (OS * OS);
    const float* p = x + bc * cL;
    float s = 0.f;
    for (int kh = 0; kh < KS; kh++) {
        int hh = h * ST - PD + kh; if (hh < 0 || hh >= cH) continue;
        for (int kw = 0; kw < KS; kw++) {
            int ww = w * ST - PD + kw; if (ww < 0 || ww >= cW) continue;
            s += p[hh * cW + ww];
        }
    }
    out[idx] = s * (1.f / (KS * KS));
}

__global__ void k_gmean(const float* __restrict__ x, float* __restrict__ out) {
    int bc = blockIdx.x;
    const float* p = x + bc * cL;
    float s = 0.f;
    for (int i = threadIdx.x; i < cL; i += 256) s += p[i];
    __shared__ float sm[4];
    for (int m = 32; m > 0; m >>= 1) s += __shfl_down(s, m);
    if ((threadIdx.x & 63) == 0) sm[threadIdx.x >> 6] = s;
    __syncthreads();
    if (threadIdx.x == 0) out[bc] = (sm[0] + sm[1] + sm[2] + sm[3]) * (1.f / cL);
}

// --------- bn_relu + 1x1 conv (64 -> 128) ---------
__global__ void __launch_bounds__(128) k_c1(const float* __restrict__ in, const float* __restrict__ g,
                                            const float* __restrict__ bb, const float* __restrict__ w,
                                            float* __restrict__ out, int HW) {
    int pos = blockIdx.x;
    int b = pos / HW, pp = pos % HW;
    __shared__ float v[64];
    int t = threadIdx.x;
    if (t < 64) v[t] = bnrelu(in[(b * 64 + t) * HW + pp], g[t], bb[t]);
    __syncthreads();
    float acc = 0.f;
    const float* wr = w + t * 64;
#pragma unroll 16
    for (int c = 0; c < 64; c++) acc += v[c] * wr[c];
    out[(b * 128 + t) * HW + pp] = acc;
}

// ---------------- bilinear (half-pixel, clamped) ----------------
__device__ __forceinline__ float bilin(const float* __restrict__ p, int S, float sy, float sx) {
    float fy = floorf(sy), fx = floorf(sx);
    int iy = (int)fy, ix = (int)fx;
    float ay = sy - fy, ax = sx - fx;
    int y0 = min(max(iy, 0), S - 1), y1 = min(max(iy + 1, 0), S - 1);
    int x0 = min(max(ix, 0), S - 1), x1 = min(max(ix + 1, 0), S - 1);
    float v00 = p[y0 * S + x0], v01 = p[y0 * S + x1];
    float v10 = p[y1 * S + x0], v11 = p[y1 * S + x1];
    float a = v00 + (v01 - v00) * ax;
    float b = v10 + (v11 - v10) * ax;
    return a + (b - a) * ay;
}

// ------- build cat (already bn_relu'd with comp params), layout (B,640,L) -------
__global__ void __launch_bounds__(128) k_cat(
    const float* __restrict__ x, const float* __restrict__ s0g, const float* __restrict__ s0b,
    const float* __restrict__ s0w, const float* __restrict__ s1g, const float* __restrict__ s1b,
    const float* __restrict__ s1w, const float* __restrict__ pool3, const float* __restrict__ c2,
    const float* __restrict__ c3, const float* __restrict__ c4, const float* __restrict__ cg,
    const float* __restrict__ cbb, float* __restrict__ catact) {
    int pos = blockIdx.x;
    int b = pos / cL, l = pos % cL;
    int h = l / cW, w = l % cW;
    __shared__ float xv[64], p3v[64];
    int t = threadIdx.x;
    if (t < 64) {
        xv[t] = bnrelu(x[(b * 64 + t) * cL + l], s0g[t], s0b[t]);
        p3v[t] = bnrelu(pool3[(b * 64 + t) * cL + l], s1g[t], s1b[t]);
    }
    __syncthreads();
    float x0 = 0.f, y1 = 0.f;
    const float* w0 = s0w + t * 64;
    const float* w1 = s1w + t * 64;
#pragma unroll 8
    for (int c = 0; c < 64; c++) { x0 += xv[c] * w0[c]; y1 += p3v[c] * w1[c]; }
    y1 += x0;
    float y2 = x0 + bilin(c2 + (b * 128 + t) * 576, 24, h * 0.5f - 0.25f, w * 0.5f - 0.25f);
    float y3 = x0 + bilin(c3 + (b * 128 + t) * 144, 12, h * 0.25f - 0.375f, w * 0.25f - 0.375f);
    float y4 = x0 + c4[b * 128 + t];
    float* base = catact + b * 640 * cL + l;
    base[(0 + t) * cL]   = bnrelu(x0, cg[t],       cbb[t]);
    base[(128 + t) * cL] = bnrelu(y1, cg[128 + t], cbb[128 + t]);
    base[(256 + t) * cL] = bnrelu(y2, cg[256 + t], cbb[256 + t]);
    base[(384 + t) * cL] = bnrelu(y3, cg[384 + t], cbb[384 + t]);
    base[(512 + t) * cL] = bnrelu(y4, cg[512 + t], cbb[512 + t]);
}

// ------- transpose comp_w (64,640,3,3) -> wt[(tap*640+ch)*64+o] -------
__global__ void k_wt(const float* __restrict__ cw, float* __restrict__ wt) {
    int idx = blockIdx.x * 256 + threadIdx.x;
    if (idx >= 64 * 640 * 9) return;
    int o = idx & 63;
    int rest = idx >> 6;
    int ch = rest % 640, tap = rest / 640;
    wt[idx] = cw[(o * 640 + ch) * 9 + tap];
}

// ------- comp 3x3 conv (640->64, pad 1) + shortcut; 4 pixels/block, split-ch halves -------
__global__ void __launch_bounds__(128) k_comp(const float* __restrict__ catact, const float* __restrict__ wt,
                                              const float* __restrict__ x, const float* __restrict__ scg,
                                              const float* __restrict__ scb, const float* __restrict__ scw,
                                              float* __restrict__ p) {
    int pos = blockIdx.x;  // b*(cL/4)+q
    int b = pos / (cL / 4), q = pos % (cL / 4);
    int l0 = q * 4;
    int h = l0 / cW, w0 = l0 % cW;
    int t = threadIdx.x;
    int o = t & 63, half = t >> 6;
    float a0 = 0.f, a1 = 0.f, a2 = 0.f, a3 = 0.f;
    const float* cb = catact + (size_t)b * 640 * cL;
    int ch0 = half * 320, ch1 = ch0 + 320;
    for (int kh = 0; kh < 3; kh++) {
        int hh = h + kh - 1; if (hh < 0 || hh >= cH) continue;
        const float* arow = cb + hh * cW;
        const float* wbase = wt + (size_t)kh * 3 * 640 * 64 + o;
        for (int ch = ch0; ch < ch1; ch++) {
            const float* ap = arow + (size_t)ch * cL;
            float av0 = (w0 - 1 >= 0) ? ap[w0 - 1] : 0.f;
            float av1 = ap[w0];
            float av2 = ap[w0 + 1];
            float av3 = ap[w0 + 2];
            float av4 = ap[w0 + 3];
            float av5 = (w0 + 4 < cW) ? ap[w0 + 4] : 0.f;
            float wv0 = wbase[(size_t)ch * 64];
            float wv1 = wbase[(size_t)(640 + ch) * 64];
            float wv2 = wbase[(size_t)(1280 + ch) * 64];
            a0 += wv0 * av0 + wv1 * av1 + wv2 * av2;
            a1 += wv0 * av1 + wv1 * av2 + wv2 * av3;
            a2 += wv0 * av2 + wv1 * av3 + wv2 * av4;
            a3 += wv0 * av3 + wv1 * av4 + wv2 * av5;
        }
    }
    __shared__ float sm[256];
    if (half == 1) { sm[o] = a0; sm[64 + o] = a1; sm[128 + o] = a2; sm[192 + o] = a3; }
    __syncthreads();
    if (half == 0) {
        a0 += sm[o]; a1 += sm[64 + o]; a2 += sm[128 + o]; a3 += sm[192 + o];
        const float* xp = x + (size_t)b * 64 * cL + l0;
        const float* sw = scw + o * 64;
        float s0 = 0.f, s1 = 0.f, s2 = 0.f, s3 = 0.f;
#pragma unroll 8
        for (int c = 0; c < 64; c++) {
            float wv = sw[c]; float g = scg[c], bb = scb[c];
            const float* xr = xp + (size_t)c * cL;
            s0 += bnrelu(xr[0], g, bb) * wv;
            s1 += bnrelu(xr[1], g, bb) * wv;
            s2 += bnrelu(xr[2], g, bb) * wv;
            s3 += bnrelu(xr[3], g, bb) * wv;
        }
        float* pr = p + ((size_t)b * 64 + o) * cL + l0;
        pr[0] = a0 + s0; pr[1] = a1 + s1; pr[2] = a2 + s2; pr[3] = a3 + s3;
    }
}

// ------- in_proj: xc -> channel-last (B,L,128), z -> (B,L,128) -------
__global__ void __launch_bounds__(256) k_inproj(const float* __restrict__ p, const float* __restrict__ wip,
                                                float* __restrict__ xc, float* __restrict__ z) {
    int pos = blockIdx.x;
    int b = pos / cL, l = pos % cL;
    __shared__ float v[64];
    int t = threadIdx.x;
    if (t < 64) v[t] = p[(b * 64 + t) * cL + l];
    __syncthreads();
    float acc = 0.f;
    const float* wr = wip + t * 64;
#pragma unroll 16
    for (int c = 0; c < 64; c++) acc += v[c] * wr[c];
    if (t < 128) xc[((size_t)b * cL + l) * 128 + t] = acc;
    else z[((size_t)b * cL + l) * 128 + (t - 128)] = acc;
}

// ------- depthwise 3x3 + bias + silu; channel-last in/out -------
__global__ void k_dw(const float* __restrict__ xc, const float* __restrict__ dww,
                     const float* __restrict__ dwb, float* __restrict__ xca) {
    int idx = blockIdx.x * 256 + threadIdx.x;
    if (idx >= cB * cL * cDI) return;
    int d = idx & 127;
    int rest = idx >> 7;
    int l = rest % cL, b = rest / cL;
    int h = l / cW, w = l % cW;
    const float* base = xc + (size_t)b * cL * 128 + d;
    float acc = dwb[d];
    const float* kw = dww + d * 9;
    for (int i = 0; i < 3; i++) {
        int hh = h + i - 1; if (hh < 0 || hh >= cH) continue;
        for (int j = 0; j < 3; j++) {
            int ww = w + j - 1; if (ww < 0 || ww >= cW) continue;
            acc += base[(size_t)(hh * cW + ww) * 128] * kw[i * 3 + j];
        }
    }
    xca[idx] = silu(acc);
}

// xs index mapping: offset into the (H*W) plane for direction k at scan pos l
__device__ __forceinline__ int xs_index(int k, int l) {
    int lp = (k & 2) ? (cL - 1 - l) : l;
    if (k & 1) { int w = lp / cH, h = lp % cH; return h * cW + w; }
    return lp;
}

// ------- x_dbl + softplus(delta) + xs snapshot; per (bk,l) block of 128 -------
// outputs: bc[bk][l][32] (B then C), delta[bk][l][128], xsv[bk][l][128]
__global__ void __launch_bounds__(128) k_xdbl2(const float* __restrict__ xca, const float* __restrict__ xpw,
                                               const float* __restrict__ dtw, const float* __restrict__ dtb,
                                               float* __restrict__ bc, float* __restrict__ delta,
                                               float* __restrict__ xsv) {
    int pos = blockIdx.x;  // bk*L + l
    int l = pos % cL;
    int bk = pos / cL;
    int k = bk % 4, b = bk / 4;
    __shared__ float v[128];
    __shared__ float dts[4];
    int t = threadIdx.x;
    int off = xs_index(k, l);
    v[t] = xca[((size_t)b * cL + off) * 128 + t];
    __syncthreads();
    if (t < 36) {
        const float* wr = xpw + (k * 36 + t) * 128;
        float acc = 0.f;
#pragma unroll 16
        for (int d = 0; d < 128; d++) acc += v[d] * wr[d];
        if (t < 4) dts[t] = acc;
        else bc[(size_t)pos * 32 + (t - 4)] = acc;
    }
    __syncthreads();
    const float* wd = dtw + (size_t)(k * 128 + t) * 4;
    float pre = dtb[k * 128 + t] + wd[0] * dts[0] + wd[1] * dts[1] + wd[2] * dts[2] + wd[3] * dts[3];
    float dl = pre > 20.f ? pre : log1pf(expf(pre));
    delta[(size_t)pos * 128 + t] = dl;
    xsv[(size_t)pos * 128 + t] = v[t];
}

// ------- scan pass 1: per-chunk local scan from h=0; record P_end, h_end -------
// block = ((bk*32+dg)*NCH + c), 64 threads = 4 d x 16 n
__global__ void __launch_bounds__(64) k_scan1(const float* __restrict__ delta, const float* __restrict__ xsv,
                                              const float* __restrict__ bc, const float* __restrict__ Alogs,
                                              float* __restrict__ Pend, float* __restrict__ hend) {
    int blk = blockIdx.x;
    int c = blk % NCH;
    int g = blk / NCH;
    int dg = g % 32, bk = g / 32;
    int k = bk % 4;
    int t = threadIdx.x;
    int ld = t >> 4, n = t & 15;
    int d = dg * 4 + ld;
    float A = -expf(Alogs[(k * 128 + d) * 16 + n]);
    const float* dp = delta + (size_t)bk * cL * 128 + d;
    const float* xp = xsv + (size_t)bk * cL * 128 + d;
    const float* bp = bc + (size_t)bk * cL * 32 + n;
    int l0 = c * CHL, l1 = l0 + CHL;
    float P = 1.f, h = 0.f;
#pragma unroll 4
    for (int l = l0; l < l1; l++) {
        float dl = dp[(size_t)l * 128];
        float a = expf(dl * A);
        h = a * h + dl * xp[(size_t)l * 128] * bp[(size_t)l * 32];
        P *= a;
    }
    Pend[(size_t)blk * 64 + t] = P;
    hend[(size_t)blk * 64 + t] = h;
}

// ------- scan pass 2: sequential combine over chunks (tiny) -------
__global__ void __launch_bounds__(256) k_scan2(const float* __restrict__ Pend, const float* __restrict__ hend,
                                               float* __restrict__ hin) {
    int id = blockIdx.x * 256 + threadIdx.x;  // g*64 + t, 16384 total
    int t = id & 63;
    int g = id >> 6;
    float h = 0.f;
    for (int c = 0; c < NCH; c++) {
        size_t idx = ((size_t)g * NCH + c) * 64 + t;
        hin[idx] = h;
        h = Pend[idx] * h + hend[idx];
    }
}

// ------- scan pass 3: re-scan with correct h_in, emit y -------
__global__ void __launch_bounds__(64) k_scan3(const float* __restrict__ delta, const float* __restrict__ xsv,
                                              const float* __restrict__ bc, const float* __restrict__ Alogs,
                                              const float* __restrict__ Dsv, const float* __restrict__ hin,
                                              float* __restrict__ y) {
    int blk = blockIdx.x;
    int c = blk % NCH;
    int g = blk / NCH;
    int dg = g % 32, bk = g / 32;
    int k = bk % 4;
    int t = threadIdx.x;
    int ld = t >> 4, n = t & 15;
    int d = dg * 4 + ld;
    float A = -expf(Alogs[(k * 128 + d) * 16 + n]);
    float Dsd = Dsv[k * 128 + d];
    const float* dp = delta + (size_t)bk * cL * 128 + d;
    const float* xp = xsv + (size_t)bk * cL * 128 + d;
    const float* bp = bc + (size_t)bk * cL * 32 + n;
    const float* cp = bc + (size_t)bk * cL * 32 + 16 + n;
    float* yrow = y + ((size_t)bk * 128 + d) * cL;
    int l0 = c * CHL, l1 = l0 + CHL;
    float h = hin[(size_t)blk * 64 + t];
#pragma unroll 2
    for (int l = l0; l < l1; l++) {
        float dl = dp[(size_t)l * 128];
        float xv = xp[(size_t)l * 128];
        float a = expf(dl * A);
        h = a * h + dl * xv * bp[(size_t)l * 32];
        float contrib = h * cp[(size_t)l * 32];
        contrib += __shfl_xor(contrib, 1);
        contrib += __shfl_xor(contrib, 2);
        contrib += __shfl_xor(contrib, 4);
        contrib += __shfl_xor(contrib, 8);
        if (n == 0) yrow[l] = contrib + xv * Dsd;
    }
}

// ------- combine 4 dirs + layernorm + gate + out_proj -> x1 (B,64,L) -------
__global__ void __launch_bounds__(128) k_comb(const float* __restrict__ y, const float* __restrict__ z,
                                              const float* __restrict__ lng, const float* __restrict__ lnb,
                                              const float* __restrict__ opw, float* __restrict__ x1) {
    int pos = blockIdx.x;
    int b = pos / cL, l = pos % cL;
    int h = l / cW, w = l % cW;
    int lwh = w * cH + h;
    int t = threadIdx.x;  // d
    const float* yb = y + (size_t)b * 4 * 128 * cL;
    float v = yb[(0 * 128 + t) * cL + l] + yb[(2 * 128 + t) * cL + (cL - 1 - l)] +
              yb[(1 * 128 + t) * cL + lwh] + yb[(3 * 128 + t) * cL + (cL - 1 - lwh)];
    __shared__ float red[2];
    __shared__ float vv[128];
    float s = v;
    for (int m = 32; m > 0; m >>= 1) s += __shfl_down(s, m);
    if ((t & 63) == 0) red[t >> 6] = s;
    __syncthreads();
    float mu = (red[0] + red[1]) * (1.f / 128.f);
    float dv = v - mu;
    float s2 = dv * dv;
    for (int m = 32; m > 0; m >>= 1) s2 += __shfl_down(s2, m);
    __syncthreads();
    if ((t & 63) == 0) red[t >> 6] = s2;
    __syncthreads();
    float var = (red[0] + red[1]) * (1.f / 128.f);
    float yn = dv * rsqrtf(var + cEPS) * lng[t] + lnb[t];
    float zz = z[((size_t)b * cL + l) * 128 + t];
    vv[t] = yn * silu(zz);
    __syncthreads();
    if (t < 64) {
        const float* wr = opw + t * 128;
        float acc = 0.f;
#pragma unroll 16
        for (int d2 = 0; d2 < 128; d2++) acc += vv[d2] * wr[d2];
        x1[(b * 64 + t) * cL + l] = acc;
    }
}

// ------- final MLP: silu(fc1(x1)) -> fc2 + residual -------
__global__ void __launch_bounds__(128) k_final(const float* __restrict__ x1, const float* __restrict__ f1w,
                                               const float* __restrict__ f1b, const float* __restrict__ f2w,
                                               const float* __restrict__ f2b, float* __restrict__ out) {
    int pos = blockIdx.x;
    int b = pos / cL, l = pos % cL;
    int t = threadIdx.x;
    __shared__ float xv[64], h1[128];
    if (t < 64) xv[t] = x1[(b * 64 + t) * cL + l];
    __syncthreads();
    float acc = f1b[t];
    const float* wr = f1w + t * 64;
#pragma unroll 16
    for (int c = 0; c < 64; c++) acc += xv[c] * wr[c];
    h1[t] = silu(acc);
    __syncthreads();
    if (t < 64) {
        float acc2 = f2b[t];
        const float* w2 = f2w + t * 128;
#pragma unroll 16
        for (int j = 0; j < 128; j++) acc2 += h1[j] * w2[j];
        out[(b * 64 + t) * cL + l] = acc2 + xv[t];
    }
}

extern "C" void kernel_launch(void* const* d_in, const int* in_sizes, int n_in,
                              void* d_out, int out_size, void* d_ws, size_t ws_size,
                              hipStream_t stream) {
    (void)in_sizes; (void)n_in; (void)out_size; (void)ws_size;
    const float* x    = (const float*)d_in[0];
    const float* s0g  = (const float*)d_in[1];
    const float* s0b  = (const float*)d_in[2];
    const float* s0w  = (const float*)d_in[3];
    const float* s1g  = (const float*)d_in[4];
    const float* s1b  = (const float*)d_in[5];
    const float* s1w  = (const float*)d_in[6];
    const float* s2g  = (const float*)d_in[7];
    const float* s2b  = (const float*)d_in[8];
    const float* s2w  = (const float*)d_in[9];
    const float* s3g  = (const float*)d_in[10];
    const float* s3b  = (const float*)d_in[11];
    const float* s3w  = (const float*)d_in[12];
    const float* s4g  = (const float*)d_in[13];
    const float* s4b  = (const float*)d_in[14];
    const float* s4w  = (const float*)d_in[15];
    const float* cg   = (const float*)d_in[16];
    const float* cbb  = (const float*)d_in[17];
    const float* cw   = (const float*)d_in[18];
    const float* scg  = (const float*)d_in[19];
    const float* scb  = (const float*)d_in[20];
    const float* scw  = (const float*)d_in[21];
    const float* ipw  = (const float*)d_in[22];
    const float* dww  = (const float*)d_in[23];
    const float* dwb  = (const float*)d_in[24];
    const float* xpw  = (const float*)d_in[25];
    const float* dtw  = (const float*)d_in[26];
    const float* dtb  = (const float*)d_in[27];
    const float* Alog = (const float*)d_in[28];
    const float* Dsv  = (const float*)d_in[29];
    const float* lng  = (const float*)d_in[30];
    const float* lnb  = (const float*)d_in[31];
    const float* opw  = (const float*)d_in[32];
    const float* f1w  = (const float*)d_in[33];
    const float* f1b  = (const float*)d_in[34];
    const float* f2w  = (const float*)d_in[35];
    const float* f2b  = (const float*)d_in[36];
    float* out = (float*)d_out;

    float* ws = (float*)d_ws;
    size_t off = 0;
    // --- region that dies before the scan stage (delta/xsv are overlaid here) ---
    float* pool3  = ws + off; off += (size_t)cB * 64 * cL;        // 294912
    float* pool5  = ws + off; off += (size_t)cB * 64 * 576;       // 73728
    float* pool9  = ws + off; off += (size_t)cB * 64 * 144;       // 18432
    float* gmean  = ws + off; off += (size_t)cB * 64;             // 128
    float* c2     = ws + off; off += (size_t)cB * 128 * 576;      // 147456
    float* c3     = ws + off; off += (size_t)cB * 128 * 144;      // 36864
    float* c4     = ws + off; off += (size_t)cB * 128;            // 256
    float* catact = ws + off; off += (size_t)cB * 640 * cL;       // 2949120
    float* wt     = ws + off; off += (size_t)64 * 640 * 9;        // 368640
    float* pbuf   = ws + off; off += (size_t)cB * 64 * cL;        // 294912
    float* xc     = ws + off; off += (size_t)cB * cL * 128;       // 589824 (channel-last)
    // cumulative here = 4,774,272 floats
    // --- live buffers ---
    float* xca    = ws + off; off += (size_t)cB * cL * 128;       // 589824 (channel-last)
    float* zbuf   = ws + off; off += (size_t)cB * cL * 128;       // 589824
    float* bcbuf  = ws + off; off += (size_t)cB * 4 * cL * 32;    // 589824
    float* Pend   = ws + off; off += (size_t)cB * 4 * 128 * 16 * NCH; // 262144... (8*32*NCH*64)
    float* hend   = ws + off; off += (size_t)8 * 32 * NCH * 64;   // 262144
    float* hin    = ws + off; off += (size_t)8 * 32 * NCH * 64;   // 262144
    float* ybuf   = ws + off; off += (size_t)cB * 4 * 128 * cL;   // 2359296
    float* x1     = ws + off; off += (size_t)cB * 64 * cL;        // 294912
    // --- overlays on the dead region (4,718,592 <= 4,774,272) ---
    float* delta  = ws + 0;                    // 2,359,296 floats
    float* xsv    = ws + (size_t)cB * 4 * cL * 128;  // 2,359,296 floats

    k_pool3<<<(cB * 64 * cL + 255) / 256, 256, 0, stream>>>(x, pool3);
    k_pool<5, 2, 2, 24><<<(cB * 64 * 576 + 255) / 256, 256, 0, stream>>>(x, pool5);
    k_pool<9, 4, 4, 12><<<(cB * 64 * 144 + 255) / 256, 256, 0, stream>>>(x, pool9);
    k_gmean<<<cB * 64, 256, 0, stream>>>(x, gmean);
    k_c1<<<cB * 576, 128, 0, stream>>>(pool5, s2g, s2b, s2w, c2, 576);
    k_c1<<<cB * 144, 128, 0, stream>>>(pool9, s3g, s3b, s3w, c3, 144);
    k_c1<<<cB, 128, 0, stream>>>(gmean, s4g, s4b, s4w, c4, 1);
    k_wt<<<(64 * 640 * 9 + 255) / 256, 256, 0, stream>>>(cw, wt);
    k_cat<<<cB * cL, 128, 0, stream>>>(x, s0g, s0b, s0w, s1g, s1b, s1w, pool3, c2, c3, c4, cg, cbb, catact);
    k_comp<<<cB * (cL / 4), 128, 0, stream>>>(catact, wt, x, scg, scb, scw, pbuf);
    k_inproj<<<cB * cL, 256, 0, stream>>>(pbuf, ipw, xc, zbuf);
    k_dw<<<(cB * cL * 128 + 255) / 256, 256, 0, stream>>>(xc, dww, dwb, xca);
    k_xdbl2<<<cB * 4 * cL, 128, 0, stream>>>(xca, xpw, dtw, dtb, bcbuf, delta, xsv);
    k_scan1<<<8 * 32 * NCH, 64, 0, stream>>>(delta, xsv, bcbuf, Alog, Pend, hend);
    k_scan2<<<64, 256, 0, stream>>>(Pend, hend, hin);
    k_scan3<<<8 * 32 * NCH, 64, 0, stream>>>(delta, xsv, bcbuf, Alog, Dsv, hin, ybuf);
    k_comb<<<cB * cL, 128, 0, stream>>>(ybuf, zbuf, lng, lnb, opw, x1);
    k_final<<<cB * cL, 128, 0, stream>>>(x1, f1w, f1b, f2w, f2b, out);
}

// Round 3
// 608.123 us; speedup vs baseline: 4.5068x; 1.2029x over previous
//
#include <hip/hip_runtime.h>
#include <math.h>

constexpr int cB = 2, cC = 64, cH = 48, cW = 48, cL = 48 * 48;
constexpr int cBR = 128, cDI = 128, cNS = 16, cRK = 4, cK = 4;
constexpr float cEPS = 1e-5f;
constexpr int NCH = 16;          // scan chunks
constexpr int CHL = cL / NCH;    // 144 positions per chunk
constexpr int KTOT = 5824;       // 9*640 conv + 64 shortcut

typedef unsigned short u16;
typedef short s16x8 __attribute__((ext_vector_type(8)));
typedef float f32x4 __attribute__((ext_vector_type(4)));

__device__ __forceinline__ float bnrelu(float v, float g, float b) {
    float y = v * (g * rsqrtf(1.0f + cEPS)) + b;
    return y > 0.f ? y : 0.f;
}
__device__ __forceinline__ float silu(float v) {
    return v / (1.f + expf(-v));
}
__device__ __forceinline__ u16 f2bf(float f) {
    unsigned int u = __float_as_uint(f);
    u = (u + 0x7fffu + ((u >> 16) & 1u)) >> 16;
    return (u16)u;
}

// ---------------- pools ----------------
__global__ void k_pool3(const float* __restrict__ x, float* __restrict__ out) {
    int idx = blockIdx.x * 256 + threadIdx.x;
    if (idx >= cB * cC * cL) return;
    int w = idx % cW, h = (idx / cW) % cH, bc = idx / cL;
    const float* p = x + bc * cL;
    float s = 0.f;
    for (int dh = -1; dh <= 1; dh++) {
        int hh = h + dh; if (hh < 0 || hh >= cH) continue;
        for (int dw = -1; dw <= 1; dw++) {
            int ww = w + dw; if (ww < 0 || ww >= cW) continue;
            s += p[hh * cW + ww];
        }
    }
    out[idx] = s * (1.f / 9.f);
}

template <int KS, int ST, int PD, int OS>
__global__ void k_pool(const float* __restrict__ x, float* __restrict__ out) {
    int idx = blockIdx.x * 256 + threadIdx.x;
    if (idx >= cB * cC * OS * OS) return;
    int w = idx % OS, h = (idx / OS) % OS, bc = idx / (OS * OS);
    const float* p = x + bc * cL;
    float s = 0.f;
    for (int kh = 0; kh < KS; kh++) {
        int hh = h * ST - PD + kh; if (hh < 0 || hh >= cH) continue;
        for (int kw = 0; kw < KS; kw++) {
            int ww = w * ST - PD + kw; if (ww < 0 || ww >= cW) continue;
            s += p[hh * cW + ww];
        }
    }
    out[idx] = s * (1.f / (KS * KS));
}

__global__ void k_gmean(const float* __restrict__ x, float* __restrict__ out) {
    int bc = blockIdx.x;
    const float* p = x + bc * cL;
    float s = 0.f;
    for (int i = threadIdx.x; i < cL; i += 256) s += p[i];
    __shared__ float sm[4];
    for (int m = 32; m > 0; m >>= 1) s += __shfl_down(s, m);
    if ((threadIdx.x & 63) == 0) sm[threadIdx.x >> 6] = s;
    __syncthreads();
    if (threadIdx.x == 0) out[bc] = (sm[0] + sm[1] + sm[2] + sm[3]) * (1.f / cL);
}

// --------- bn_relu + 1x1 conv (64 -> 128) ---------
__global__ void __launch_bounds__(128) k_c1(const float* __restrict__ in, const float* __restrict__ g,
                                            const float* __restrict__ bb, const float* __restrict__ w,
                                            float* __restrict__ out, int HW) {
    int pos = blockIdx.x;
    int b = pos / HW, pp = pos % HW;
    __shared__ float v[64];
    int t = threadIdx.x;
    if (t < 64) v[t] = bnrelu(in[(b * 64 + t) * HW + pp], g[t], bb[t]);
    __syncthreads();
    float acc = 0.f;
    const float* wr = w + t * 64;
#pragma unroll 16
    for (int c = 0; c < 64; c++) acc += v[c] * wr[c];
    out[(b * 128 + t) * HW + pp] = acc;
}

// ---------------- bilinear (half-pixel, clamped) ----------------
__device__ __forceinline__ float bilin(const float* __restrict__ p, int S, float sy, float sx) {
    float fy = floorf(sy), fx = floorf(sx);
    int iy = (int)fy, ix = (int)fx;
    float ay = sy - fy, ax = sx - fx;
    int y0 = min(max(iy, 0), S - 1), y1 = min(max(iy + 1, 0), S - 1);
    int x0 = min(max(ix, 0), S - 1), x1 = min(max(ix + 1, 0), S - 1);
    float v00 = p[y0 * S + x0], v01 = p[y0 * S + x1];
    float v10 = p[y1 * S + x0], v11 = p[y1 * S + x1];
    float a = v00 + (v01 - v00) * ax;
    float b = v10 + (v11 - v10) * ax;
    return a + (b - a) * ay;
}

// ------- build cat (bn_relu'd, channel-last bf16) + shortcut-input snapshot -------
__global__ void __launch_bounds__(128) k_cat(
    const float* __restrict__ x, const float* __restrict__ s0g, const float* __restrict__ s0b,
    const float* __restrict__ s0w, const float* __restrict__ s1g, const float* __restrict__ s1b,
    const float* __restrict__ s1w, const float* __restrict__ pool3, const float* __restrict__ c2,
    const float* __restrict__ c3, const float* __restrict__ c4, const float* __restrict__ cg,
    const float* __restrict__ cbb, const float* __restrict__ scg, const float* __restrict__ scb,
    u16* __restrict__ catbf, u16* __restrict__ xbf) {
    int pos = blockIdx.x;
    int b = pos / cL, l = pos % cL;
    int h = l / cW, w = l % cW;
    __shared__ float xv[64], p3v[64];
    int t = threadIdx.x;
    if (t < 64) {
        float xraw = x[(b * 64 + t) * cL + l];
        xv[t] = bnrelu(xraw, s0g[t], s0b[t]);
        p3v[t] = bnrelu(pool3[(b * 64 + t) * cL + l], s1g[t], s1b[t]);
        xbf[((size_t)b * cL + l) * 64 + t] = f2bf(bnrelu(xraw, scg[t], scb[t]));
    }
    __syncthreads();
    float x0 = 0.f, y1 = 0.f;
    const float* w0 = s0w + t * 64;
    const float* w1 = s1w + t * 64;
#pragma unroll 8
    for (int c = 0; c < 64; c++) { x0 += xv[c] * w0[c]; y1 += p3v[c] * w1[c]; }
    y1 += x0;
    float y2 = x0 + bilin(c2 + (b * 128 + t) * 576, 24, h * 0.5f - 0.25f, w * 0.5f - 0.25f);
    float y3 = x0 + bilin(c3 + (b * 128 + t) * 144, 12, h * 0.25f - 0.375f, w * 0.25f - 0.375f);
    float y4 = x0 + c4[b * 128 + t];
    u16* base = catbf + ((size_t)b * cL + l) * 640;
    base[0 + t]   = f2bf(bnrelu(x0, cg[t],       cbb[t]));
    base[128 + t] = f2bf(bnrelu(y1, cg[128 + t], cbb[128 + t]));
    base[256 + t] = f2bf(bnrelu(y2, cg[256 + t], cbb[256 + t]));
    base[384 + t] = f2bf(bnrelu(y3, cg[384 + t], cbb[384 + t]));
    base[512 + t] = f2bf(bnrelu(y4, cg[512 + t], cbb[512 + t]));
}

// ------- weight prep: wb[o][k] bf16, k = tap*640+ch for conv, 5760+c for shortcut -------
__global__ void k_wprep(const float* __restrict__ cw, const float* __restrict__ scw,
                        u16* __restrict__ wb) {
    int idx = blockIdx.x * 256 + threadIdx.x;
    if (idx >= 64 * KTOT) return;
    int o = idx / KTOT, kx = idx % KTOT;
    float v;
    if (kx < 5760) { int tap = kx / 640, ch = kx % 640; v = cw[(o * 640 + ch) * 9 + tap]; }
    else v = scw[o * 64 + (kx - 5760)];
    wb[idx] = f2bf(v);
}

// ------- comp 3x3 conv (640->64) + shortcut via MFMA implicit-im2col GEMM -------
// block: 256 thr = 4 waves; wave w -> output rows [16w,16w+16); 64 pixels per block
__global__ void __launch_bounds__(256) k_comp(const u16* __restrict__ catbf,
                                              const u16* __restrict__ xbf,
                                              const u16* __restrict__ wb,
                                              float* __restrict__ p) {
    int t = threadIdx.x;
    int wv = t >> 6;
    int lane = t & 63;
    int ln = lane & 15;
    int q = lane >> 4;
    int pix0 = blockIdx.x * 64;
    int b = pix0 / cL;
    int lbase = pix0 - b * cL;
    const u16* wrow = wb + (size_t)(wv * 16 + ln) * KTOT + q * 8;
    const u16* cbase = catbf + (size_t)b * cL * 640;
    f32x4 acc[4] = {};
    int hj[4], wj[4];
#pragma unroll
    for (int j = 0; j < 4; j++) {
        int l = lbase + j * 16 + ln;
        hj[j] = l / cW; wj[j] = l % cW;
    }
    for (int tap = 0; tap < 9; tap++) {
        int kh = tap / 3 - 1, kw = tap % 3 - 1;
        const u16* bptr[4];
        bool ok[4];
#pragma unroll
        for (int j = 0; j < 4; j++) {
            int hh = hj[j] + kh, ww = wj[j] + kw;
            ok[j] = (hh >= 0) && (hh < cH) && (ww >= 0) && (ww < cW);
            bptr[j] = cbase + (size_t)(hh * cW + ww) * 640 + q * 8;
        }
        const u16* wtap = wrow + tap * 640;
#pragma unroll 4
        for (int cc = 0; cc < 20; cc++) {
            s16x8 av = *(const s16x8*)(wtap + cc * 32);
#pragma unroll
            for (int j = 0; j < 4; j++) {
                s16x8 bv;
                if (ok[j]) bv = *(const s16x8*)(bptr[j] + cc * 32);
                else bv = s16x8{0, 0, 0, 0, 0, 0, 0, 0};
                acc[j] = __builtin_amdgcn_mfma_f32_16x16x32_bf16(av, bv, acc[j], 0, 0, 0);
            }
        }
    }
    // shortcut (K = 64)
    {
        const u16* wsc = wrow + 5760;
#pragma unroll
        for (int cc = 0; cc < 2; cc++) {
            s16x8 av = *(const s16x8*)(wsc + cc * 32);
#pragma unroll
            for (int j = 0; j < 4; j++) {
                const u16* xp = xbf + ((size_t)pix0 + j * 16 + ln) * 64 + cc * 32 + q * 8;
                s16x8 bv = *(const s16x8*)xp;
                acc[j] = __builtin_amdgcn_mfma_f32_16x16x32_bf16(av, bv, acc[j], 0, 0, 0);
            }
        }
    }
#pragma unroll
    for (int j = 0; j < 4; j++) {
        int l = lbase + j * 16 + ln;
#pragma unroll
        for (int r = 0; r < 4; r++) {
            int o = wv * 16 + q * 4 + r;
            p[((size_t)b * 64 + o) * cL + l] = acc[j][r];
        }
    }
}

// ------- in_proj: xc -> channel-last (B,L,128), z -> (B,L,128) -------
__global__ void __launch_bounds__(256) k_inproj(const float* __restrict__ p, const float* __restrict__ wip,
                                                float* __restrict__ xc, float* __restrict__ z) {
    int pos = blockIdx.x;
    int b = pos / cL, l = pos % cL;
    __shared__ float v[64];
    int t = threadIdx.x;
    if (t < 64) v[t] = p[(b * 64 + t) * cL + l];
    __syncthreads();
    float acc = 0.f;
    const float* wr = wip + t * 64;
#pragma unroll 16
    for (int c = 0; c < 64; c++) acc += v[c] * wr[c];
    if (t < 128) xc[((size_t)b * cL + l) * 128 + t] = acc;
    else z[((size_t)b * cL + l) * 128 + (t - 128)] = acc;
}

// ------- depthwise 3x3 + bias + silu; channel-last in/out -------
__global__ void k_dw(const float* __restrict__ xc, const float* __restrict__ dww,
                     const float* __restrict__ dwb, float* __restrict__ xca) {
    int idx = blockIdx.x * 256 + threadIdx.x;
    if (idx >= cB * cL * cDI) return;
    int d = idx & 127;
    int rest = idx >> 7;
    int l = rest % cL, b = rest / cL;
    int h = l / cW, w = l % cW;
    const float* base = xc + (size_t)b * cL * 128 + d;
    float acc = dwb[d];
    const float* kw = dww + d * 9;
    for (int i = 0; i < 3; i++) {
        int hh = h + i - 1; if (hh < 0 || hh >= cH) continue;
        for (int j = 0; j < 3; j++) {
            int ww = w + j - 1; if (ww < 0 || ww >= cW) continue;
            acc += base[(size_t)(hh * cW + ww) * 128] * kw[i * 3 + j];
        }
    }
    xca[idx] = silu(acc);
}

// xs index mapping: offset into the (H*W) plane for direction k at scan pos l
__device__ __forceinline__ int xs_index(int k, int l) {
    int lp = (k & 2) ? (cL - 1 - l) : l;
    if (k & 1) { int w = lp / cH, h = lp % cH; return h * cW + w; }
    return lp;
}

// ------- x_dbl + softplus(delta) + xs snapshot; per (bk,l) block of 128 -------
__global__ void __launch_bounds__(128) k_xdbl2(const float* __restrict__ xca, const float* __restrict__ xpw,
                                               const float* __restrict__ dtw, const float* __restrict__ dtb,
                                               float* __restrict__ bc, float* __restrict__ delta,
                                               float* __restrict__ xsv) {
    int pos = blockIdx.x;  // bk*L + l
    int l = pos % cL;
    int bk = pos / cL;
    int k = bk % 4, b = bk / 4;
    __shared__ float v[128];
    __shared__ float dts[4];
    int t = threadIdx.x;
    int off = xs_index(k, l);
    v[t] = xca[((size_t)b * cL + off) * 128 + t];
    __syncthreads();
    if (t < 36) {
        const float* wr = xpw + (k * 36 + t) * 128;
        float acc = 0.f;
#pragma unroll 16
        for (int d = 0; d < 128; d++) acc += v[d] * wr[d];
        if (t < 4) dts[t] = acc;
        else bc[(size_t)pos * 32 + (t - 4)] = acc;
    }
    __syncthreads();
    const float* wd = dtw + (size_t)(k * 128 + t) * 4;
    float pre = dtb[k * 128 + t] + wd[0] * dts[0] + wd[1] * dts[1] + wd[2] * dts[2] + wd[3] * dts[3];
    float dl = pre > 20.f ? pre : log1pf(expf(pre));
    delta[(size_t)pos * 128 + t] = dl;
    xsv[(size_t)pos * 128 + t] = v[t];
}

// ------- scan pass 1: 256 thr = 16 d x 16 n; per-chunk local scan -------
__global__ void __launch_bounds__(256) k_scan1(const float* __restrict__ delta, const float* __restrict__ xsv,
                                               const float* __restrict__ bc, const float* __restrict__ Alogs,
                                               float* __restrict__ Pend, float* __restrict__ hend) {
    int blk = blockIdx.x;            // ((bk*8+dgq)*16 + c)
    int c = blk & 15;
    int g = blk >> 4;                // bk*8+dgq
    int dgq = g & 7, bk = g >> 3;
    int k = bk & 3;
    int t = threadIdx.x;
    int n = t & 15;
    int d = dgq * 16 + (t >> 4);
    float A = -expf(Alogs[(k * 128 + d) * 16 + n]);
    const float* dp = delta + (size_t)bk * cL * 128 + d;
    const float* xp = xsv + (size_t)bk * cL * 128 + d;
    const float* bp = bc + (size_t)bk * cL * 32 + n;
    int l0 = c * CHL, l1 = l0 + CHL;
    float P = 1.f, h = 0.f;
#pragma unroll 4
    for (int l = l0; l < l1; l++) {
        float dl = dp[(size_t)l * 128];
        float a = expf(dl * A);
        h = a * h + dl * xp[(size_t)l * 128] * bp[(size_t)l * 32];
        P *= a;
    }
    Pend[(size_t)blk * 256 + t] = P;
    hend[(size_t)blk * 256 + t] = h;
}

// ------- scan pass 2: sequential combine over chunks (tiny) -------
__global__ void __launch_bounds__(256) k_scan2(const float* __restrict__ Pend, const float* __restrict__ hend,
                                               float* __restrict__ hin) {
    int id = blockIdx.x * 256 + threadIdx.x;  // 16384 total
    int t = id & 255;
    int g = id >> 8;  // 0..63
    float h = 0.f;
    for (int c = 0; c < NCH; c++) {
        size_t idx = ((size_t)g * NCH + c) * 256 + t;
        hin[idx] = h;
        h = Pend[idx] * h + hend[idx];
    }
}

// ------- scan pass 3: re-scan with h_in; y channel-last [bk][l][128] -------
__global__ void __launch_bounds__(256) k_scan3(const float* __restrict__ delta, const float* __restrict__ xsv,
                                               const float* __restrict__ bc, const float* __restrict__ Alogs,
                                               const float* __restrict__ Dsv, const float* __restrict__ hin,
                                               float* __restrict__ y) {
    int blk = blockIdx.x;
    int c = blk & 15;
    int g = blk >> 4;
    int dgq = g & 7, bk = g >> 3;
    int k = bk & 3;
    int t = threadIdx.x;
    int n = t & 15;
    int d = dgq * 16 + (t >> 4);
    float A = -expf(Alogs[(k * 128 + d) * 16 + n]);
    float Dsd = Dsv[k * 128 + d];
    const float* dp = delta + (size_t)bk * cL * 128 + d;
    const float* xp = xsv + (size_t)bk * cL * 128 + d;
    const float* bp = bc + (size_t)bk * cL * 32 + n;
    const float* cp = bc + (size_t)bk * cL * 32 + 16 + n;
    float* yb = y + (size_t)bk * cL * 128 + d;
    int l0 = c * CHL, l1 = l0 + CHL;
    float h = hin[(size_t)blk * 256 + t];
#pragma unroll 2
    for (int l = l0; l < l1; l++) {
        float dl = dp[(size_t)l * 128];
        float xv = xp[(size_t)l * 128];
        float a = expf(dl * A);
        h = a * h + dl * xv * bp[(size_t)l * 32];
        float contrib = h * cp[(size_t)l * 32];
        contrib += __shfl_xor(contrib, 1);
        contrib += __shfl_xor(contrib, 2);
        contrib += __shfl_xor(contrib, 4);
        contrib += __shfl_xor(contrib, 8);
        if (n == 0) yb[(size_t)l * 128] = contrib + xv * Dsd;
    }
}

// ------- combine 4 dirs + layernorm + gate + out_proj -> x1 (B,64,L) -------
__global__ void __launch_bounds__(128) k_comb(const float* __restrict__ y, const float* __restrict__ z,
                                              const float* __restrict__ lng, const float* __restrict__ lnb,
                                              const float* __restrict__ opw, float* __restrict__ x1) {
    int pos = blockIdx.x;
    int b = pos / cL, l = pos % cL;
    int h = l / cW, w = l % cW;
    int lwh = w * cH + h;
    int t = threadIdx.x;  // d
    float v = y[((size_t)(b * 4 + 0) * cL + l) * 128 + t] +
              y[((size_t)(b * 4 + 2) * cL + (cL - 1 - l)) * 128 + t] +
              y[((size_t)(b * 4 + 1) * cL + lwh) * 128 + t] +
              y[((size_t)(b * 4 + 3) * cL + (cL - 1 - lwh)) * 128 + t];
    __shared__ float red[2];
    __shared__ float vv[128];
    float s = v;
    for (int m = 32; m > 0; m >>= 1) s += __shfl_down(s, m);
    if ((t & 63) == 0) red[t >> 6] = s;
    __syncthreads();
    float mu = (red[0] + red[1]) * (1.f / 128.f);
    float dv = v - mu;
    float s2 = dv * dv;
    for (int m = 32; m > 0; m >>= 1) s2 += __shfl_down(s2, m);
    __syncthreads();
    if ((t & 63) == 0) red[t >> 6] = s2;
    __syncthreads();
    float var = (red[0] + red[1]) * (1.f / 128.f);
    float yn = dv * rsqrtf(var + cEPS) * lng[t] + lnb[t];
    float zz = z[((size_t)b * cL + l) * 128 + t];
    vv[t] = yn * silu(zz);
    __syncthreads();
    if (t < 64) {
        const float* wr = opw + t * 128;
        float acc = 0.f;
#pragma unroll 16
        for (int d2 = 0; d2 < 128; d2++) acc += vv[d2] * wr[d2];
        x1[(b * 64 + t) * cL + l] = acc;
    }
}

// ------- final MLP: silu(fc1(x1)) -> fc2 + residual -------
__global__ void __launch_bounds__(128) k_final(const float* __restrict__ x1, const float* __restrict__ f1w,
                                               const float* __restrict__ f1b, const float* __restrict__ f2w,
                                               const float* __restrict__ f2b, float* __restrict__ out) {
    int pos = blockIdx.x;
    int b = pos / cL, l = pos % cL;
    int t = threadIdx.x;
    __shared__ float xv[64], h1[128];
    if (t < 64) xv[t] = x1[(b * 64 + t) * cL + l];
    __syncthreads();
    float acc = f1b[t];
    const float* wr = f1w + t * 64;
#pragma unroll 16
    for (int c = 0; c < 64; c++) acc += xv[c] * wr[c];
    h1[t] = silu(acc);
    __syncthreads();
    if (t < 64) {
        float acc2 = f2b[t];
        const float* w2 = f2w + t * 128;
#pragma unroll 16
        for (int j = 0; j < 128; j++) acc2 += h1[j] * w2[j];
        out[(b * 64 + t) * cL + l] = acc2 + xv[t];
    }
}

extern "C" void kernel_launch(void* const* d_in, const int* in_sizes, int n_in,
                              void* d_out, int out_size, void* d_ws, size_t ws_size,
                              hipStream_t stream) {
    (void)in_sizes; (void)n_in; (void)out_size; (void)ws_size;
    const float* x    = (const float*)d_in[0];
    const float* s0g  = (const float*)d_in[1];
    const float* s0b  = (const float*)d_in[2];
    const float* s0w  = (const float*)d_in[3];
    const float* s1g  = (const float*)d_in[4];
    const float* s1b  = (const float*)d_in[5];
    const float* s1w  = (const float*)d_in[6];
    const float* s2g  = (const float*)d_in[7];
    const float* s2b  = (const float*)d_in[8];
    const float* s2w  = (const float*)d_in[9];
    const float* s3g  = (const float*)d_in[10];
    const float* s3b  = (const float*)d_in[11];
    const float* s3w  = (const float*)d_in[12];
    const float* s4g  = (const float*)d_in[13];
    const float* s4b  = (const float*)d_in[14];
    const float* s4w  = (const float*)d_in[15];
    const float* cg   = (const float*)d_in[16];
    const float* cbb  = (const float*)d_in[17];
    const float* cw   = (const float*)d_in[18];
    const float* scg  = (const float*)d_in[19];
    const float* scb  = (const float*)d_in[20];
    const float* scw  = (const float*)d_in[21];
    const float* ipw  = (const float*)d_in[22];
    const float* dww  = (const float*)d_in[23];
    const float* dwb  = (const float*)d_in[24];
    const float* xpw  = (const float*)d_in[25];
    const float* dtw  = (const float*)d_in[26];
    const float* dtb  = (const float*)d_in[27];
    const float* Alog = (const float*)d_in[28];
    const float* Dsv  = (const float*)d_in[29];
    const float* lng  = (const float*)d_in[30];
    const float* lnb  = (const float*)d_in[31];
    const float* opw  = (const float*)d_in[32];
    const float* f1w  = (const float*)d_in[33];
    const float* f1b  = (const float*)d_in[34];
    const float* f2w  = (const float*)d_in[35];
    const float* f2b  = (const float*)d_in[36];
    float* out = (float*)d_out;

    float* ws = (float*)d_ws;
    size_t off = 0;
    // --- dead-before-scan region (delta/xsv overlay it) ---
    float* pool3  = ws + off; off += (size_t)cB * 64 * cL;        // 294912
    float* pool5  = ws + off; off += (size_t)cB * 64 * 576;       // 73728
    float* pool9  = ws + off; off += (size_t)cB * 64 * 144;       // 18432
    float* gmean  = ws + off; off += (size_t)cB * 64;             // 128
    float* c2     = ws + off; off += (size_t)cB * 128 * 576;      // 147456
    float* c3     = ws + off; off += (size_t)cB * 128 * 144;      // 36864
    float* c4     = ws + off; off += (size_t)cB * 128;            // 256
    u16*   catbf  = (u16*)(ws + off); off += (size_t)cB * cL * 640 / 2;  // 1474560 fl
    u16*   xbf    = (u16*)(ws + off); off += (size_t)cB * cL * 64 / 2;   // 147456 fl
    u16*   wb     = (u16*)(ws + off); off += (size_t)64 * KTOT / 2;      // 186368 fl
    float* pbuf   = ws + off; off += (size_t)cB * 64 * cL;        // 294912
    float* xc     = ws + off; off += (size_t)cB * cL * 128;       // 589824
    // pad dead region so delta+xsv (2*2359296) fit under it
    off = 4718592;
    // --- live buffers ---
    float* xca    = ws + off; off += (size_t)cB * cL * 128;       // 589824
    float* zbuf   = ws + off; off += (size_t)cB * cL * 128;       // 589824
    float* bcbuf  = ws + off; off += (size_t)cB * 4 * cL * 32;    // 589824
    float* Pend   = ws + off; off += (size_t)1024 * 256;          // 262144
    float* hend   = ws + off; off += (size_t)1024 * 256;          // 262144
    float* hin    = ws + off; off += (size_t)1024 * 256;          // 262144
    float* ybuf   = ws + off; off += (size_t)cB * 4 * cL * 128;   // 2359296
    float* x1     = ws + off; off += (size_t)cB * 64 * cL;        // 294912
    // overlays on dead region
    float* delta  = ws + 0;
    float* xsv    = ws + (size_t)cB * 4 * cL * 128;

    k_pool3<<<(cB * 64 * cL + 255) / 256, 256, 0, stream>>>(x, pool3);
    k_pool<5, 2, 2, 24><<<(cB * 64 * 576 + 255) / 256, 256, 0, stream>>>(x, pool5);
    k_pool<9, 4, 4, 12><<<(cB * 64 * 144 + 255) / 256, 256, 0, stream>>>(x, pool9);
    k_gmean<<<cB * 64, 256, 0, stream>>>(x, gmean);
    k_c1<<<cB * 576, 128, 0, stream>>>(pool5, s2g, s2b, s2w, c2, 576);
    k_c1<<<cB * 144, 128, 0, stream>>>(pool9, s3g, s3b, s3w, c3, 144);
    k_c1<<<cB, 128, 0, stream>>>(gmean, s4g, s4b, s4w, c4, 1);
    k_wprep<<<(64 * KTOT + 255) / 256, 256, 0, stream>>>(cw, scw, wb);
    k_cat<<<cB * cL, 128, 0, stream>>>(x, s0g, s0b, s0w, s1g, s1b, s1w, pool3, c2, c3, c4, cg, cbb, scg, scb, catbf, xbf);
    k_comp<<<cB * cL / 64, 256, 0, stream>>>(catbf, xbf, wb, pbuf);
    k_inproj<<<cB * cL, 256, 0, stream>>>(pbuf, ipw, xc, zbuf);
    k_dw<<<(cB * cL * 128 + 255) / 256, 256, 0, stream>>>(xc, dww, dwb, xca);
    k_xdbl2<<<cB * 4 * cL, 128, 0, stream>>>(xca, xpw, dtw, dtb, bcbuf, delta, xsv);
    k_scan1<<<1024, 256, 0, stream>>>(delta, xsv, bcbuf, Alog, Pend, hend);
    k_scan2<<<64, 256, 0, stream>>>(Pend, hend, hin);
    k_scan3<<<1024, 256, 0, stream>>>(delta, xsv, bcbuf, Alog, Dsv, hin, ybuf);
    k_comb<<<cB * cL, 128, 0, stream>>>(ybuf, zbuf, lng, lnb, opw, x1);
    k_final<<<cB * cL, 128, 0, stream>>>(x1, f1w, f1b, f2w, f2b, out);
}

// Round 4
// 488.532 us; speedup vs baseline: 5.6101x; 1.2448x over previous
//
#include <hip/hip_runtime.h>
#include <math.h>

constexpr int cB = 2, cC = 64, cH = 48, cW = 48, cL = 48 * 48;
constexpr int cBR = 128, cDI = 128, cNS = 16, cRK = 4, cK = 4;
constexpr float cEPS = 1e-5f;
constexpr int NCH = 16;          // scan chunks
constexpr int CHL = cL / NCH;    // 144 positions per chunk
constexpr int KTOT = 5824;       // 9*640 conv + 64 shortcut

typedef unsigned short u16;
typedef short s16x8 __attribute__((ext_vector_type(8)));
typedef float f32x4 __attribute__((ext_vector_type(4)));

__device__ __forceinline__ float bnrelu(float v, float g, float b) {
    float y = v * (g * rsqrtf(1.0f + cEPS)) + b;
    return y > 0.f ? y : 0.f;
}
__device__ __forceinline__ float silu(float v) {
    return v / (1.f + expf(-v));
}
__device__ __forceinline__ u16 f2bf(float f) {
    unsigned int u = __float_as_uint(f);
    u = (u + 0x7fffu + ((u >> 16) & 1u)) >> 16;
    return (u16)u;
}

// ---------------- pools ----------------
__global__ void k_pool3(const float* __restrict__ x, float* __restrict__ out) {
    int idx = blockIdx.x * 256 + threadIdx.x;
    if (idx >= cB * cC * cL) return;
    int w = idx % cW, h = (idx / cW) % cH, bc = idx / cL;
    const float* p = x + bc * cL;
    float s = 0.f;
    for (int dh = -1; dh <= 1; dh++) {
        int hh = h + dh; if (hh < 0 || hh >= cH) continue;
        for (int dw = -1; dw <= 1; dw++) {
            int ww = w + dw; if (ww < 0 || ww >= cW) continue;
            s += p[hh * cW + ww];
        }
    }
    out[idx] = s * (1.f / 9.f);
}

template <int KS, int ST, int PD, int OS>
__global__ void k_pool(const float* __restrict__ x, float* __restrict__ out) {
    int idx = blockIdx.x * 256 + threadIdx.x;
    if (idx >= cB * cC * OS * OS) return;
    int w = idx % OS, h = (idx / OS) % OS, bc = idx / (OS * OS);
    const float* p = x + bc * cL;
    float s = 0.f;
    for (int kh = 0; kh < KS; kh++) {
        int hh = h * ST - PD + kh; if (hh < 0 || hh >= cH) continue;
        for (int kw = 0; kw < KS; kw++) {
            int ww = w * ST - PD + kw; if (ww < 0 || ww >= cW) continue;
            s += p[hh * cW + ww];
        }
    }
    out[idx] = s * (1.f / (KS * KS));
}

__global__ void k_gmean(const float* __restrict__ x, float* __restrict__ out) {
    int bc = blockIdx.x;
    const float* p = x + bc * cL;
    float s = 0.f;
    for (int i = threadIdx.x; i < cL; i += 256) s += p[i];
    __shared__ float sm[4];
    for (int m = 32; m > 0; m >>= 1) s += __shfl_down(s, m);
    if ((threadIdx.x & 63) == 0) sm[threadIdx.x >> 6] = s;
    __syncthreads();
    if (threadIdx.x == 0) out[bc] = (sm[0] + sm[1] + sm[2] + sm[3]) * (1.f / cL);
}

// --------- bn_relu + 1x1 conv (64 -> 128) ---------
__global__ void __launch_bounds__(128) k_c1(const float* __restrict__ in, const float* __restrict__ g,
                                            const float* __restrict__ bb, const float* __restrict__ w,
                                            float* __restrict__ out, int HW) {
    int pos = blockIdx.x;
    int b = pos / HW, pp = pos % HW;
    __shared__ float v[64];
    int t = threadIdx.x;
    if (t < 64) v[t] = bnrelu(in[(b * 64 + t) * HW + pp], g[t], bb[t]);
    __syncthreads();
    float acc = 0.f;
    const float* wr = w + t * 64;
#pragma unroll 16
    for (int c = 0; c < 64; c++) acc += v[c] * wr[c];
    out[(b * 128 + t) * HW + pp] = acc;
}

// ---------------- bilinear (half-pixel, clamped) ----------------
__device__ __forceinline__ float bilin(const float* __restrict__ p, int S, float sy, float sx) {
    float fy = floorf(sy), fx = floorf(sx);
    int iy = (int)fy, ix = (int)fx;
    float ay = sy - fy, ax = sx - fx;
    int y0 = min(max(iy, 0), S - 1), y1 = min(max(iy + 1, 0), S - 1);
    int x0 = min(max(ix, 0), S - 1), x1 = min(max(ix + 1, 0), S - 1);
    float v00 = p[y0 * S + x0], v01 = p[y0 * S + x1];
    float v10 = p[y1 * S + x0], v11 = p[y1 * S + x1];
    float a = v00 + (v01 - v00) * ax;
    float b = v10 + (v11 - v10) * ax;
    return a + (b - a) * ay;
}

// ------- build cat (bn_relu'd, channel-last bf16) + shortcut-input snapshot -------
__global__ void __launch_bounds__(128) k_cat(
    const float* __restrict__ x, const float* __restrict__ s0g, const float* __restrict__ s0b,
    const float* __restrict__ s0w, const float* __restrict__ s1g, const float* __restrict__ s1b,
    const float* __restrict__ s1w, const float* __restrict__ pool3, const float* __restrict__ c2,
    const float* __restrict__ c3, const float* __restrict__ c4, const float* __restrict__ cg,
    const float* __restrict__ cbb, const float* __restrict__ scg, const float* __restrict__ scb,
    u16* __restrict__ catbf, u16* __restrict__ xbf) {
    int pos = blockIdx.x;
    int b = pos / cL, l = pos % cL;
    int h = l / cW, w = l % cW;
    __shared__ float xv[64], p3v[64];
    int t = threadIdx.x;
    if (t < 64) {
        float xraw = x[(b * 64 + t) * cL + l];
        xv[t] = bnrelu(xraw, s0g[t], s0b[t]);
        p3v[t] = bnrelu(pool3[(b * 64 + t) * cL + l], s1g[t], s1b[t]);
        xbf[((size_t)b * cL + l) * 64 + t] = f2bf(bnrelu(xraw, scg[t], scb[t]));
    }
    __syncthreads();
    float x0 = 0.f, y1 = 0.f;
    const float* w0 = s0w + t * 64;
    const float* w1 = s1w + t * 64;
#pragma unroll 8
    for (int c = 0; c < 64; c++) { x0 += xv[c] * w0[c]; y1 += p3v[c] * w1[c]; }
    y1 += x0;
    float y2 = x0 + bilin(c2 + (b * 128 + t) * 576, 24, h * 0.5f - 0.25f, w * 0.5f - 0.25f);
    float y3 = x0 + bilin(c3 + (b * 128 + t) * 144, 12, h * 0.25f - 0.375f, w * 0.25f - 0.375f);
    float y4 = x0 + c4[b * 128 + t];
    u16* base = catbf + ((size_t)b * cL + l) * 640;
    base[0 + t]   = f2bf(bnrelu(x0, cg[t],       cbb[t]));
    base[128 + t] = f2bf(bnrelu(y1, cg[128 + t], cbb[128 + t]));
    base[256 + t] = f2bf(bnrelu(y2, cg[256 + t], cbb[256 + t]));
    base[384 + t] = f2bf(bnrelu(y3, cg[384 + t], cbb[384 + t]));
    base[512 + t] = f2bf(bnrelu(y4, cg[512 + t], cbb[512 + t]));
}

// ------- weight prep: w8[(k/8)][o][k%8] bf16; k = tap*640+ch conv, 5760+c shortcut -------
__global__ void k_wprep(const float* __restrict__ cw, const float* __restrict__ scw,
                        u16* __restrict__ w8) {
    int idx = blockIdx.x * 256 + threadIdx.x;
    if (idx >= 64 * KTOT) return;
    int o = idx / KTOT, kx = idx % KTOT;
    float v;
    if (kx < 5760) { int tap = kx / 640, ch = kx % 640; v = cw[(o * 640 + ch) * 9 + tap]; }
    else v = scw[o * 64 + (kx - 5760)];
    w8[(((size_t)(kx >> 3) * 64) + o) * 8 + (kx & 7)] = f2bf(v);
}

// ------- comp 3x3 conv + shortcut: split-K MFMA GEMM -------
// grid = 288 px-tiles x 9 tap slices; 1 wave/block.
// A = activations (m=pixel), B = weights w8 (n=out, coalesced), D row=pixel col=out.
// slice 4 (center tap, always in bounds) also folds in the K=64 shortcut.
__global__ void __launch_bounds__(64) k_comp(const u16* __restrict__ catbf,
                                             const u16* __restrict__ xbf,
                                             const u16* __restrict__ w8,
                                             float* __restrict__ part) {
    int blk = blockIdx.x;
    int slice = blk % 9;
    int pxt = blk / 9;
    int pix0 = pxt * 16;
    int b = pix0 / cL;              // uniform per block (cL % 16 == 0)
    int lane = threadIdx.x;
    int ln = lane & 15, q = lane >> 4;
    int la = (pix0 + ln) - b * cL;  // pixel within image for A row
    int h = la / cW, w = la % cW;
    int kh = slice / 3 - 1, kw = slice % 3 - 1;
    int hh = h + kh, ww = w + kw;
    bool ok = (hh >= 0) && (hh < cH) && (ww >= 0) && (ww < cW);
    const u16* ap = catbf + ((size_t)b * cL + hh * cW + ww) * 640 + q * 8;
    f32x4 acc[4] = {};
    int kb = slice * 640;
#pragma unroll 4
    for (int cc = 0; cc < 20; cc++) {
        s16x8 av;
        if (ok) av = *(const s16x8*)(ap + cc * 32);
        else av = s16x8{0, 0, 0, 0, 0, 0, 0, 0};
        const u16* wrow = w8 + (((size_t)((kb + cc * 32) >> 3) + q) * 64) * 8;
#pragma unroll
        for (int j = 0; j < 4; j++) {
            s16x8 bv = *(const s16x8*)(wrow + (size_t)(j * 16 + ln) * 8);
            acc[j] = __builtin_amdgcn_mfma_f32_16x16x32_bf16(av, bv, acc[j], 0, 0, 0);
        }
    }
    if (slice == 4) {  // fold shortcut (K=64) into center-tap slice
        const u16* xp = xbf + (size_t)(pix0 + ln) * 64 + q * 8;
#pragma unroll
        for (int cc = 0; cc < 2; cc++) {
            s16x8 av = *(const s16x8*)(xp + cc * 32);
            const u16* wrow = w8 + (((size_t)((5760 + cc * 32) >> 3) + q) * 64) * 8;
#pragma unroll
            for (int j = 0; j < 4; j++) {
                s16x8 bv = *(const s16x8*)(wrow + (size_t)(j * 16 + ln) * 8);
                acc[j] = __builtin_amdgcn_mfma_f32_16x16x32_bf16(av, bv, acc[j], 0, 0, 0);
            }
        }
    }
    // D[row = q*4+r][col = ln]: pixel = pix0 + q*4 + r, out = j*16 + ln
    float* pb = part + ((size_t)slice * (cB * cL) + pix0) * 64;
#pragma unroll
    for (int j = 0; j < 4; j++) {
#pragma unroll
        for (int r = 0; r < 4; r++) {
            pb[(size_t)(q * 4 + r) * 64 + j * 16 + ln] = acc[j][r];
        }
    }
}

// ------- reduce 9 split-K partials -> pbuf channel-last (B,L,64) -------
__global__ void __launch_bounds__(256) k_red(const float* __restrict__ part, float* __restrict__ pbuf) {
    int id = blockIdx.x * 256 + threadIdx.x;
    if (id >= cB * cL * 64) return;
    float s = 0.f;
#pragma unroll
    for (int sl = 0; sl < 9; sl++) s += part[(size_t)sl * (cB * cL * 64) + id];
    pbuf[id] = s;
}

// ------- in_proj: xc -> channel-last (B,L,128), z -> (B,L,128) -------
__global__ void __launch_bounds__(256) k_inproj(const float* __restrict__ p, const float* __restrict__ wip,
                                                float* __restrict__ xc, float* __restrict__ z) {
    int pos = blockIdx.x;  // b*cL + l
    __shared__ float v[64];
    int t = threadIdx.x;
    if (t < 64) v[t] = p[(size_t)pos * 64 + t];
    __syncthreads();
    float acc = 0.f;
    const float* wr = wip + t * 64;
#pragma unroll 16
    for (int c = 0; c < 64; c++) acc += v[c] * wr[c];
    if (t < 128) xc[(size_t)pos * 128 + t] = acc;
    else z[(size_t)pos * 128 + (t - 128)] = acc;
}

// ------- depthwise 3x3 + bias + silu; channel-last in/out -------
__global__ void k_dw(const float* __restrict__ xc, const float* __restrict__ dww,
                     const float* __restrict__ dwb, float* __restrict__ xca) {
    int idx = blockIdx.x * 256 + threadIdx.x;
    if (idx >= cB * cL * cDI) return;
    int d = idx & 127;
    int rest = idx >> 7;
    int l = rest % cL, b = rest / cL;
    int h = l / cW, w = l % cW;
    const float* base = xc + (size_t)b * cL * 128 + d;
    float acc = dwb[d];
    const float* kw = dww + d * 9;
    for (int i = 0; i < 3; i++) {
        int hh = h + i - 1; if (hh < 0 || hh >= cH) continue;
        for (int j = 0; j < 3; j++) {
            int ww = w + j - 1; if (ww < 0 || ww >= cW) continue;
            acc += base[(size_t)(hh * cW + ww) * 128] * kw[i * 3 + j];
        }
    }
    xca[idx] = silu(acc);
}

// xs index mapping: offset into the (H*W) plane for direction k at scan pos l
__device__ __forceinline__ int xs_index(int k, int l) {
    int lp = (k & 2) ? (cL - 1 - l) : l;
    if (k & 1) { int w = lp / cH, h = lp % cH; return h * cW + w; }
    return lp;
}

// ------- x_dbl + softplus(delta) + xs snapshot; per (bk,l) block of 128 -------
__global__ void __launch_bounds__(128) k_xdbl2(const float* __restrict__ xca, const float* __restrict__ xpw,
                                               const float* __restrict__ dtw, const float* __restrict__ dtb,
                                               float* __restrict__ bc, float* __restrict__ delta,
                                               float* __restrict__ xsv) {
    int pos = blockIdx.x;  // bk*L + l
    int l = pos % cL;
    int bk = pos / cL;
    int k = bk % 4, b = bk / 4;
    __shared__ float v[128];
    __shared__ float dts[4];
    int t = threadIdx.x;
    int off = xs_index(k, l);
    v[t] = xca[((size_t)b * cL + off) * 128 + t];
    __syncthreads();
    if (t < 36) {
        const float* wr = xpw + (k * 36 + t) * 128;
        float acc = 0.f;
#pragma unroll 16
        for (int d = 0; d < 128; d++) acc += v[d] * wr[d];
        if (t < 4) dts[t] = acc;
        else bc[(size_t)pos * 32 + (t - 4)] = acc;
    }
    __syncthreads();
    const float* wd = dtw + (size_t)(k * 128 + t) * 4;
    float pre = dtb[k * 128 + t] + wd[0] * dts[0] + wd[1] * dts[1] + wd[2] * dts[2] + wd[3] * dts[3];
    float dl = pre > 20.f ? pre : log1pf(expf(pre));
    delta[(size_t)pos * 128 + t] = dl;
    xsv[(size_t)pos * 128 + t] = v[t];
}

// ------- scan pass 1: 256 thr = 16 d x 16 n; per-chunk local scan -------
__global__ void __launch_bounds__(256) k_scan1(const float* __restrict__ delta, const float* __restrict__ xsv,
                                               const float* __restrict__ bc, const float* __restrict__ Alogs,
                                               float* __restrict__ Pend, float* __restrict__ hend) {
    int blk = blockIdx.x;            // ((bk*8+dgq)*16 + c)
    int c = blk & 15;
    int g = blk >> 4;                // bk*8+dgq
    int dgq = g & 7, bk = g >> 3;
    int k = bk & 3;
    int t = threadIdx.x;
    int n = t & 15;
    int d = dgq * 16 + (t >> 4);
    float A = -expf(Alogs[(k * 128 + d) * 16 + n]);
    const float* dp = delta + (size_t)bk * cL * 128 + d;
    const float* xp = xsv + (size_t)bk * cL * 128 + d;
    const float* bp = bc + (size_t)bk * cL * 32 + n;
    int l0 = c * CHL, l1 = l0 + CHL;
    float P = 1.f, h = 0.f;
#pragma unroll 4
    for (int l = l0; l < l1; l++) {
        float dl = dp[(size_t)l * 128];
        float a = expf(dl * A);
        h = a * h + dl * xp[(size_t)l * 128] * bp[(size_t)l * 32];
        P *= a;
    }
    Pend[(size_t)blk * 256 + t] = P;
    hend[(size_t)blk * 256 + t] = h;
}

// ------- scan pass 2: sequential combine over chunks (tiny) -------
__global__ void __launch_bounds__(256) k_scan2(const float* __restrict__ Pend, const float* __restrict__ hend,
                                               float* __restrict__ hin) {
    int id = blockIdx.x * 256 + threadIdx.x;  // 16384 total
    int t = id & 255;
    int g = id >> 8;  // 0..63
    float h = 0.f;
    for (int c = 0; c < NCH; c++) {
        size_t idx = ((size_t)g * NCH + c) * 256 + t;
        hin[idx] = h;
        h = Pend[idx] * h + hend[idx];
    }
}

// ------- scan pass 3: re-scan with h_in; y channel-last [bk][l][128] -------
__global__ void __launch_bounds__(256) k_scan3(const float* __restrict__ delta, const float* __restrict__ xsv,
                                               const float* __restrict__ bc, const float* __restrict__ Alogs,
                                               const float* __restrict__ Dsv, const float* __restrict__ hin,
                                               float* __restrict__ y) {
    int blk = blockIdx.x;
    int c = blk & 15;
    int g = blk >> 4;
    int dgq = g & 7, bk = g >> 3;
    int k = bk & 3;
    int t = threadIdx.x;
    int n = t & 15;
    int d = dgq * 16 + (t >> 4);
    float A = -expf(Alogs[(k * 128 + d) * 16 + n]);
    float Dsd = Dsv[k * 128 + d];
    const float* dp = delta + (size_t)bk * cL * 128 + d;
    const float* xp = xsv + (size_t)bk * cL * 128 + d;
    const float* bp = bc + (size_t)bk * cL * 32 + n;
    const float* cp = bc + (size_t)bk * cL * 32 + 16 + n;
    float* yb = y + (size_t)bk * cL * 128 + d;
    int l0 = c * CHL, l1 = l0 + CHL;
    float h = hin[(size_t)blk * 256 + t];
#pragma unroll 2
    for (int l = l0; l < l1; l++) {
        float dl = dp[(size_t)l * 128];
        float xv = xp[(size_t)l * 128];
        float a = expf(dl * A);
        h = a * h + dl * xv * bp[(size_t)l * 32];
        float contrib = h * cp[(size_t)l * 32];
        contrib += __shfl_xor(contrib, 1);
        contrib += __shfl_xor(contrib, 2);
        contrib += __shfl_xor(contrib, 4);
        contrib += __shfl_xor(contrib, 8);
        if (n == 0) yb[(size_t)l * 128] = contrib + xv * Dsd;
    }
}

// ------- combine 4 dirs + layernorm + gate + out_proj -> x1 (B,64,L) -------
__global__ void __launch_bounds__(128) k_comb(const float* __restrict__ y, const float* __restrict__ z,
                                              const float* __restrict__ lng, const float* __restrict__ lnb,
                                              const float* __restrict__ opw, float* __restrict__ x1) {
    int pos = blockIdx.x;
    int b = pos / cL, l = pos % cL;
    int h = l / cW, w = l % cW;
    int lwh = w * cH + h;
    int t = threadIdx.x;  // d
    float v = y[((size_t)(b * 4 + 0) * cL + l) * 128 + t] +
              y[((size_t)(b * 4 + 2) * cL + (cL - 1 - l)) * 128 + t] +
              y[((size_t)(b * 4 + 1) * cL + lwh) * 128 + t] +
              y[((size_t)(b * 4 + 3) * cL + (cL - 1 - lwh)) * 128 + t];
    __shared__ float red[2];
    __shared__ float vv[128];
    float s = v;
    for (int m = 32; m > 0; m >>= 1) s += __shfl_down(s, m);
    if ((t & 63) == 0) red[t >> 6] = s;
    __syncthreads();
    float mu = (red[0] + red[1]) * (1.f / 128.f);
    float dv = v - mu;
    float s2 = dv * dv;
    for (int m = 32; m > 0; m >>= 1) s2 += __shfl_down(s2, m);
    __syncthreads();
    if ((t & 63) == 0) red[t >> 6] = s2;
    __syncthreads();
    float var = (red[0] + red[1]) * (1.f / 128.f);
    float yn = dv * rsqrtf(var + cEPS) * lng[t] + lnb[t];
    float zz = z[((size_t)b * cL + l) * 128 + t];
    vv[t] = yn * silu(zz);
    __syncthreads();
    if (t < 64) {
        const float* wr = opw + t * 128;
        float acc = 0.f;
#pragma unroll 16
        for (int d2 = 0; d2 < 128; d2++) acc += vv[d2] * wr[d2];
        x1[(b * 64 + t) * cL + l] = acc;
    }
}

// ------- final MLP: silu(fc1(x1)) -> fc2 + residual -------
__global__ void __launch_bounds__(128) k_final(const float* __restrict__ x1, const float* __restrict__ f1w,
                                               const float* __restrict__ f1b, const float* __restrict__ f2w,
                                               const float* __restrict__ f2b, float* __restrict__ out) {
    int pos = blockIdx.x;
    int b = pos / cL, l = pos % cL;
    int t = threadIdx.x;
    __shared__ float xv[64], h1[128];
    if (t < 64) xv[t] = x1[(b * 64 + t) * cL + l];
    __syncthreads();
    float acc = f1b[t];
    const float* wr = f1w + t * 64;
#pragma unroll 16
    for (int c = 0; c < 64; c++) acc += xv[c] * wr[c];
    h1[t] = silu(acc);
    __syncthreads();
    if (t < 64) {
        float acc2 = f2b[t];
        const float* w2 = f2w + t * 128;
#pragma unroll 16
        for (int j = 0; j < 128; j++) acc2 += h1[j] * w2[j];
        out[(b * 64 + t) * cL + l] = acc2 + xv[t];
    }
}

extern "C" void kernel_launch(void* const* d_in, const int* in_sizes, int n_in,
                              void* d_out, int out_size, void* d_ws, size_t ws_size,
                              hipStream_t stream) {
    (void)in_sizes; (void)n_in; (void)out_size; (void)ws_size;
    const float* x    = (const float*)d_in[0];
    const float* s0g  = (const float*)d_in[1];
    const float* s0b  = (const float*)d_in[2];
    const float* s0w  = (const float*)d_in[3];
    const float* s1g  = (const float*)d_in[4];
    const float* s1b  = (const float*)d_in[5];
    const float* s1w  = (const float*)d_in[6];
    const float* s2g  = (const float*)d_in[7];
    const float* s2b  = (const float*)d_in[8];
    const float* s2w  = (const float*)d_in[9];
    const float* s3g  = (const float*)d_in[10];
    const float* s3b  = (const float*)d_in[11];
    const float* s3w  = (const float*)d_in[12];
    const float* s4g  = (const float*)d_in[13];
    const float* s4b  = (const float*)d_in[14];
    const float* s4w  = (const float*)d_in[15];
    const float* cg   = (const float*)d_in[16];
    const float* cbb  = (const float*)d_in[17];
    const float* cw   = (const float*)d_in[18];
    const float* scg  = (const float*)d_in[19];
    const float* scb  = (const float*)d_in[20];
    const float* scw  = (const float*)d_in[21];
    const float* ipw  = (const float*)d_in[22];
    const float* dww  = (const float*)d_in[23];
    const float* dwb  = (const float*)d_in[24];
    const float* xpw  = (const float*)d_in[25];
    const float* dtw  = (const float*)d_in[26];
    const float* dtb  = (const float*)d_in[27];
    const float* Alog = (const float*)d_in[28];
    const float* Dsv  = (const float*)d_in[29];
    const float* lng  = (const float*)d_in[30];
    const float* lnb  = (const float*)d_in[31];
    const float* opw  = (const float*)d_in[32];
    const float* f1w  = (const float*)d_in[33];
    const float* f1b  = (const float*)d_in[34];
    const float* f2w  = (const float*)d_in[35];
    const float* f2b  = (const float*)d_in[36];
    float* out = (float*)d_out;

    float* ws = (float*)d_ws;
    size_t off = 0;
    // --- dead-before-scan region (delta/xsv overlay it) ---
    float* pool3  = ws + off; off += (size_t)cB * 64 * cL;        // 294912
    float* pool5  = ws + off; off += (size_t)cB * 64 * 576;       // 73728
    float* pool9  = ws + off; off += (size_t)cB * 64 * 144;       // 18432
    float* gmean  = ws + off; off += (size_t)cB * 64;             // 128
    float* c2     = ws + off; off += (size_t)cB * 128 * 576;      // 147456
    float* c3     = ws + off; off += (size_t)cB * 128 * 144;      // 36864
    float* c4     = ws + off; off += (size_t)cB * 128;            // 256
    u16*   catbf  = (u16*)(ws + off); off += (size_t)cB * cL * 640 / 2;  // 1474560 fl
    u16*   xbf    = (u16*)(ws + off); off += (size_t)cB * cL * 64 / 2;   // 147456 fl
    u16*   w8     = (u16*)(ws + off); off += (size_t)64 * KTOT / 2;      // 186368 fl
    float* pbuf   = ws + off; off += (size_t)cB * cL * 64;        // 294912 (channel-last)
    float* xc     = ws + off; off += (size_t)cB * cL * 128;       // 589824
    // pad dead region so delta+xsv (2*2359296) fit under it
    off = 4718592;
    // --- live buffers ---
    float* xca    = ws + off; off += (size_t)cB * cL * 128;       // 589824
    float* zbuf   = ws + off; off += (size_t)cB * cL * 128;       // 589824
    float* bcbuf  = ws + off; off += (size_t)cB * 4 * cL * 32;    // 589824
    float* Pend   = ws + off; off += (size_t)1024 * 256;          // 262144
    float* hend   = ws + off; off += (size_t)1024 * 256;          // 262144
    float* hin    = ws + off; off += (size_t)1024 * 256;          // 262144
    float* ybuf   = ws + off; off += (size_t)cB * 4 * cL * 128;   // 2359296
    float* x1     = ws + off; off += (size_t)cB * 64 * cL;        // 294912
    // overlays on dead region
    float* delta  = ws + 0;
    float* xsv    = ws + (size_t)cB * 4 * cL * 128;
    // split-K partials overlay ybuf+x1 (9*294912 = 2654208 = 2359296+294912), dead at k_comp time
    float* part   = ybuf;

    k_pool3<<<(cB * 64 * cL + 255) / 256, 256, 0, stream>>>(x, pool3);
    k_pool<5, 2, 2, 24><<<(cB * 64 * 576 + 255) / 256, 256, 0, stream>>>(x, pool5);
    k_pool<9, 4, 4, 12><<<(cB * 64 * 144 + 255) / 256, 256, 0, stream>>>(x, pool9);
    k_gmean<<<cB * 64, 256, 0, stream>>>(x, gmean);
    k_c1<<<cB * 576, 128, 0, stream>>>(pool5, s2g, s2b, s2w, c2, 576);
    k_c1<<<cB * 144, 128, 0, stream>>>(pool9, s3g, s3b, s3w, c3, 144);
    k_c1<<<cB, 128, 0, stream>>>(gmean, s4g, s4b, s4w, c4, 1);
    k_wprep<<<(64 * KTOT + 255) / 256, 256, 0, stream>>>(cw, scw, w8);
    k_cat<<<cB * cL, 128, 0, stream>>>(x, s0g, s0b, s0w, s1g, s1b, s1w, pool3, c2, c3, c4, cg, cbb, scg, scb, catbf, xbf);
    k_comp<<<(cB * cL / 16) * 9, 64, 0, stream>>>(catbf, xbf, w8, part);
    k_red<<<(cB * cL * 64 + 255) / 256, 256, 0, stream>>>(part, pbuf);
    k_inproj<<<cB * cL, 256, 0, stream>>>(pbuf, ipw, xc, zbuf);
    k_dw<<<(cB * cL * 128 + 255) / 256, 256, 0, stream>>>(xc, dww, dwb, xca);
    k_xdbl2<<<cB * 4 * cL, 128, 0, stream>>>(xca, xpw, dtw, dtb, bcbuf, delta, xsv);
    k_scan1<<<1024, 256, 0, stream>>>(delta, xsv, bcbuf, Alog, Pend, hend);
    k_scan2<<<64, 256, 0, stream>>>(Pend, hend, hin);
    k_scan3<<<1024, 256, 0, stream>>>(delta, xsv, bcbuf, Alog, Dsv, hin, ybuf);
    k_comb<<<cB * cL, 128, 0, stream>>>(ybuf, zbuf, lng, lnb, opw, x1);
    k_final<<<cB * cL, 128, 0, stream>>>(x1, f1w, f1b, f2w, f2b, out);
}

// Round 5
// 457.739 us; speedup vs baseline: 5.9875x; 1.0673x over previous
//
#include <hip/hip_runtime.h>
#include <math.h>

constexpr int cB = 2, cC = 64, cH = 48, cW = 48, cL = 48 * 48;
constexpr int cBR = 128, cDI = 128, cNS = 16, cRK = 4, cK = 4;
constexpr float cEPS = 1e-5f;
constexpr int NCH = 32;          // scan chunks
constexpr int CHL = cL / NCH;    // 72 positions per chunk
constexpr int KTOT = 5824;       // 9*640 conv + 64 shortcut

typedef unsigned short u16;
typedef short s16x8 __attribute__((ext_vector_type(8)));
typedef float f32x4 __attribute__((ext_vector_type(4)));

__device__ __forceinline__ float bnrelu(float v, float g, float b) {
    float y = v * (g * rsqrtf(1.0f + cEPS)) + b;
    return y > 0.f ? y : 0.f;
}
__device__ __forceinline__ float silu(float v) {
    return v / (1.f + expf(-v));
}
__device__ __forceinline__ u16 f2bf(float f) {
    unsigned int u = __float_as_uint(f);
    u = (u + 0x7fffu + ((u >> 16) & 1u)) >> 16;
    return (u16)u;
}
// sum over each aligned 16-lane row via DPP (full-rate VALU, no DS pipe)
__device__ __forceinline__ float row_sum16(float v) {
    v += __int_as_float(__builtin_amdgcn_update_dpp(0, __float_as_int(v), 0xB1, 0xF, 0xF, true));  // quad xor1
    v += __int_as_float(__builtin_amdgcn_update_dpp(0, __float_as_int(v), 0x4E, 0xF, 0xF, true));  // quad xor2
    v += __int_as_float(__builtin_amdgcn_update_dpp(0, __float_as_int(v), 0x124, 0xF, 0xF, true)); // row_ror:4
    v += __int_as_float(__builtin_amdgcn_update_dpp(0, __float_as_int(v), 0x128, 0xF, 0xF, true)); // row_ror:8
    return v;
}

// ---------------- pools ----------------
__global__ void k_pool3(const float* __restrict__ x, float* __restrict__ out) {
    int idx = blockIdx.x * 256 + threadIdx.x;
    if (idx >= cB * cC * cL) return;
    int w = idx % cW, h = (idx / cW) % cH, bc = idx / cL;
    const float* p = x + bc * cL;
    float s = 0.f;
    for (int dh = -1; dh <= 1; dh++) {
        int hh = h + dh; if (hh < 0 || hh >= cH) continue;
        for (int dw = -1; dw <= 1; dw++) {
            int ww = w + dw; if (ww < 0 || ww >= cW) continue;
            s += p[hh * cW + ww];
        }
    }
    out[idx] = s * (1.f / 9.f);
}

template <int KS, int ST, int PD, int OS>
__global__ void k_pool(const float* __restrict__ x, float* __restrict__ out) {
    int idx = blockIdx.x * 256 + threadIdx.x;
    if (idx >= cB * cC * OS * OS) return;
    int w = idx % OS, h = (idx / OS) % OS, bc = idx / (OS * OS);
    const float* p = x + bc * cL;
    float s = 0.f;
    for (int kh = 0; kh < KS; kh++) {
        int hh = h * ST - PD + kh; if (hh < 0 || hh >= cH) continue;
        for (int kw = 0; kw < KS; kw++) {
            int ww = w * ST - PD + kw; if (ww < 0 || ww >= cW) continue;
            s += p[hh * cW + ww];
        }
    }
    out[idx] = s * (1.f / (KS * KS));
}

__global__ void k_gmean(const float* __restrict__ x, float* __restrict__ out) {
    int bc = blockIdx.x;
    const float* p = x + bc * cL;
    float s = 0.f;
    for (int i = threadIdx.x; i < cL; i += 256) s += p[i];
    __shared__ float sm[4];
    for (int m = 32; m > 0; m >>= 1) s += __shfl_down(s, m);
    if ((threadIdx.x & 63) == 0) sm[threadIdx.x >> 6] = s;
    __syncthreads();
    if (threadIdx.x == 0) out[bc] = (sm[0] + sm[1] + sm[2] + sm[3]) * (1.f / cL);
}

// --------- bn_relu + 1x1 conv (64 -> 128) ---------
__global__ void __launch_bounds__(128) k_c1(const float* __restrict__ in, const float* __restrict__ g,
                                            const float* __restrict__ bb, const float* __restrict__ w,
                                            float* __restrict__ out, int HW) {
    int pos = blockIdx.x;
    int b = pos / HW, pp = pos % HW;
    __shared__ float v[64];
    int t = threadIdx.x;
    if (t < 64) v[t] = bnrelu(in[(b * 64 + t) * HW + pp], g[t], bb[t]);
    __syncthreads();
    float acc = 0.f;
    const float* wr = w + t * 64;
#pragma unroll 16
    for (int c = 0; c < 64; c++) acc += v[c] * wr[c];
    out[(b * 128 + t) * HW + pp] = acc;
}

// ---------------- bilinear (half-pixel, clamped) ----------------
__device__ __forceinline__ float bilin(const float* __restrict__ p, int S, float sy, float sx) {
    float fy = floorf(sy), fx = floorf(sx);
    int iy = (int)fy, ix = (int)fx;
    float ay = sy - fy, ax = sx - fx;
    int y0 = min(max(iy, 0), S - 1), y1 = min(max(iy + 1, 0), S - 1);
    int x0 = min(max(ix, 0), S - 1), x1 = min(max(ix + 1, 0), S - 1);
    float v00 = p[y0 * S + x0], v01 = p[y0 * S + x1];
    float v10 = p[y1 * S + x0], v11 = p[y1 * S + x1];
    float a = v00 + (v01 - v00) * ax;
    float b = v10 + (v11 - v10) * ax;
    return a + (b - a) * ay;
}

// ------- build cat (bn_relu'd, channel-last bf16) + shortcut-input snapshot -------
__global__ void __launch_bounds__(128) k_cat(
    const float* __restrict__ x, const float* __restrict__ s0g, const float* __restrict__ s0b,
    const float* __restrict__ s0w, const float* __restrict__ s1g, const float* __restrict__ s1b,
    const float* __restrict__ s1w, const float* __restrict__ pool3, const float* __restrict__ c2,
    const float* __restrict__ c3, const float* __restrict__ c4, const float* __restrict__ cg,
    const float* __restrict__ cbb, const float* __restrict__ scg, const float* __restrict__ scb,
    u16* __restrict__ catbf, u16* __restrict__ xbf) {
    int pos = blockIdx.x;
    int b = pos / cL, l = pos % cL;
    int h = l / cW, w = l % cW;
    __shared__ float xv[64], p3v[64];
    int t = threadIdx.x;
    if (t < 64) {
        float xraw = x[(b * 64 + t) * cL + l];
        xv[t] = bnrelu(xraw, s0g[t], s0b[t]);
        p3v[t] = bnrelu(pool3[(b * 64 + t) * cL + l], s1g[t], s1b[t]);
        xbf[((size_t)b * cL + l) * 64 + t] = f2bf(bnrelu(xraw, scg[t], scb[t]));
    }
    __syncthreads();
    float x0 = 0.f, y1 = 0.f;
    const float* w0 = s0w + t * 64;
    const float* w1 = s1w + t * 64;
#pragma unroll 8
    for (int c = 0; c < 64; c++) { x0 += xv[c] * w0[c]; y1 += p3v[c] * w1[c]; }
    y1 += x0;
    float y2 = x0 + bilin(c2 + (b * 128 + t) * 576, 24, h * 0.5f - 0.25f, w * 0.5f - 0.25f);
    float y3 = x0 + bilin(c3 + (b * 128 + t) * 144, 12, h * 0.25f - 0.375f, w * 0.25f - 0.375f);
    float y4 = x0 + c4[b * 128 + t];
    u16* base = catbf + ((size_t)b * cL + l) * 640;
    base[0 + t]   = f2bf(bnrelu(x0, cg[t],       cbb[t]));
    base[128 + t] = f2bf(bnrelu(y1, cg[128 + t], cbb[128 + t]));
    base[256 + t] = f2bf(bnrelu(y2, cg[256 + t], cbb[256 + t]));
    base[384 + t] = f2bf(bnrelu(y3, cg[384 + t], cbb[384 + t]));
    base[512 + t] = f2bf(bnrelu(y4, cg[512 + t], cbb[512 + t]));
}

// ------- weight prep: w8[(k/8)][o][k%8] bf16; k = tap*640+ch conv, 5760+c shortcut -------
__global__ void k_wprep(const float* __restrict__ cw, const float* __restrict__ scw,
                        u16* __restrict__ w8) {
    int idx = blockIdx.x * 256 + threadIdx.x;
    if (idx >= 64 * KTOT) return;
    int o = idx / KTOT, kx = idx % KTOT;
    float v;
    if (kx < 5760) { int tap = kx / 640, ch = kx % 640; v = cw[(o * 640 + ch) * 9 + tap]; }
    else v = scw[o * 64 + (kx - 5760)];
    w8[(((size_t)(kx >> 3) * 64) + o) * 8 + (kx & 7)] = f2bf(v);
}

// ------- comp 3x3 conv + shortcut: split-K MFMA GEMM -------
__global__ void __launch_bounds__(64) k_comp(const u16* __restrict__ catbf,
                                             const u16* __restrict__ xbf,
                                             const u16* __restrict__ w8,
                                             float* __restrict__ part) {
    int blk = blockIdx.x;
    int slice = blk % 9;
    int pxt = blk / 9;
    int pix0 = pxt * 16;
    int b = pix0 / cL;
    int lane = threadIdx.x;
    int ln = lane & 15, q = lane >> 4;
    int la = (pix0 + ln) - b * cL;
    int h = la / cW, w = la % cW;
    int kh = slice / 3 - 1, kw = slice % 3 - 1;
    int hh = h + kh, ww = w + kw;
    bool ok = (hh >= 0) && (hh < cH) && (ww >= 0) && (ww < cW);
    const u16* ap = catbf + ((size_t)b * cL + hh * cW + ww) * 640 + q * 8;
    f32x4 acc[4] = {};
    int kb = slice * 640;
#pragma unroll 4
    for (int cc = 0; cc < 20; cc++) {
        s16x8 av;
        if (ok) av = *(const s16x8*)(ap + cc * 32);
        else av = s16x8{0, 0, 0, 0, 0, 0, 0, 0};
        const u16* wrow = w8 + (((size_t)((kb + cc * 32) >> 3) + q) * 64) * 8;
#pragma unroll
        for (int j = 0; j < 4; j++) {
            s16x8 bv = *(const s16x8*)(wrow + (size_t)(j * 16 + ln) * 8);
            acc[j] = __builtin_amdgcn_mfma_f32_16x16x32_bf16(av, bv, acc[j], 0, 0, 0);
        }
    }
    if (slice == 4) {
        const u16* xp = xbf + (size_t)(pix0 + ln) * 64 + q * 8;
#pragma unroll
        for (int cc = 0; cc < 2; cc++) {
            s16x8 av = *(const s16x8*)(xp + cc * 32);
            const u16* wrow = w8 + (((size_t)((5760 + cc * 32) >> 3) + q) * 64) * 8;
#pragma unroll
            for (int j = 0; j < 4; j++) {
                s16x8 bv = *(const s16x8*)(wrow + (size_t)(j * 16 + ln) * 8);
                acc[j] = __builtin_amdgcn_mfma_f32_16x16x32_bf16(av, bv, acc[j], 0, 0, 0);
            }
        }
    }
    float* pb = part + ((size_t)slice * (cB * cL) + pix0) * 64;
#pragma unroll
    for (int j = 0; j < 4; j++) {
#pragma unroll
        for (int r = 0; r < 4; r++) {
            pb[(size_t)(q * 4 + r) * 64 + j * 16 + ln] = acc[j][r];
        }
    }
}

// ------- reduce 9 split-K partials -> pbuf channel-last (B,L,64) -------
__global__ void __launch_bounds__(256) k_red(const float* __restrict__ part, float* __restrict__ pbuf) {
    int id = blockIdx.x * 256 + threadIdx.x;
    if (id >= cB * cL * 64) return;
    float s = 0.f;
#pragma unroll
    for (int sl = 0; sl < 9; sl++) s += part[(size_t)sl * (cB * cL * 64) + id];
    pbuf[id] = s;
}

// ------- in_proj: xc -> channel-last (B,L,128), z -> (B,L,128) -------
__global__ void __launch_bounds__(256) k_inproj(const float* __restrict__ p, const float* __restrict__ wip,
                                                float* __restrict__ xc, float* __restrict__ z) {
    int pos = blockIdx.x;  // b*cL + l
    __shared__ float v[64];
    int t = threadIdx.x;
    if (t < 64) v[t] = p[(size_t)pos * 64 + t];
    __syncthreads();
    float acc = 0.f;
    const float* wr = wip + t * 64;
#pragma unroll 16
    for (int c = 0; c < 64; c++) acc += v[c] * wr[c];
    if (t < 128) xc[(size_t)pos * 128 + t] = acc;
    else z[(size_t)pos * 128 + (t - 128)] = acc;
}

// ------- depthwise 3x3 + bias + silu; channel-last in/out -------
__global__ void k_dw(const float* __restrict__ xc, const float* __restrict__ dww,
                     const float* __restrict__ dwb, float* __restrict__ xca) {
    int idx = blockIdx.x * 256 + threadIdx.x;
    if (idx >= cB * cL * cDI) return;
    int d = idx & 127;
    int rest = idx >> 7;
    int l = rest % cL, b = rest / cL;
    int h = l / cW, w = l % cW;
    const float* base = xc + (size_t)b * cL * 128 + d;
    float acc = dwb[d];
    const float* kw = dww + d * 9;
    for (int i = 0; i < 3; i++) {
        int hh = h + i - 1; if (hh < 0 || hh >= cH) continue;
        for (int j = 0; j < 3; j++) {
            int ww = w + j - 1; if (ww < 0 || ww >= cW) continue;
            acc += base[(size_t)(hh * cW + ww) * 128] * kw[i * 3 + j];
        }
    }
    xca[idx] = silu(acc);
}

// xs index mapping: offset into the (H*W) plane for direction k at scan pos l
__device__ __forceinline__ int xs_index(int k, int l) {
    int lp = (k & 2) ? (cL - 1 - l) : l;
    if (k & 1) { int w = lp / cH, h = lp % cH; return h * cW + w; }
    return lp;
}

// ------- x_dbl + softplus(delta) + xs snapshot; per (bk,l) block of 128 -------
__global__ void __launch_bounds__(128) k_xdbl2(const float* __restrict__ xca, const float* __restrict__ xpw,
                                               const float* __restrict__ dtw, const float* __restrict__ dtb,
                                               float* __restrict__ bc, float* __restrict__ delta,
                                               float* __restrict__ xsv) {
    int pos = blockIdx.x;  // bk*L + l
    int l = pos % cL;
    int bk = pos / cL;
    int k = bk % 4, b = bk / 4;
    __shared__ float v[128];
    __shared__ float dts[4];
    int t = threadIdx.x;
    int off = xs_index(k, l);
    v[t] = xca[((size_t)b * cL + off) * 128 + t];
    __syncthreads();
    if (t < 36) {
        const float* wr = xpw + (k * 36 + t) * 128;
        float acc = 0.f;
#pragma unroll 16
        for (int d = 0; d < 128; d++) acc += v[d] * wr[d];
        if (t < 4) dts[t] = acc;
        else bc[(size_t)pos * 32 + (t - 4)] = acc;
    }
    __syncthreads();
    const float* wd = dtw + (size_t)(k * 128 + t) * 4;
    float pre = dtb[k * 128 + t] + wd[0] * dts[0] + wd[1] * dts[1] + wd[2] * dts[2] + wd[3] * dts[3];
    float dl = pre > 20.f ? pre : log1pf(expf(pre));
    delta[(size_t)pos * 128 + t] = dl;
    xsv[(size_t)pos * 128 + t] = v[t];
}

// ------- scan pass 1: 256 thr = 16 d x 16 n; per-chunk local scan -------
__global__ void __launch_bounds__(256) k_scan1(const float* __restrict__ delta, const float* __restrict__ xsv,
                                               const float* __restrict__ bc, const float* __restrict__ Alogs,
                                               float* __restrict__ Pend, float* __restrict__ hend) {
    int blk = blockIdx.x;            // ((bk*8+dgq)*NCH + c)
    int c = blk & 31;
    if (c == NCH - 1) return;        // last chunk's P/h never consumed
    int g = blk >> 5;                // bk*8+dgq
    int dgq = g & 7, bk = g >> 3;
    int k = bk & 3;
    int t = threadIdx.x;
    int n = t & 15;
    int d = dgq * 16 + (t >> 4);
    float A = -expf(Alogs[(k * 128 + d) * 16 + n]);
    const float* dp = delta + (size_t)bk * cL * 128 + d;
    const float* xp = xsv + (size_t)bk * cL * 128 + d;
    const float* bp = bc + (size_t)bk * cL * 32 + n;
    int l0 = c * CHL, l1 = l0 + CHL;
    float P = 1.f, h = 0.f;
#pragma unroll 4
    for (int l = l0; l < l1; l++) {
        float dl = dp[(size_t)l * 128];
        float a = expf(dl * A);
        h = a * h + dl * xp[(size_t)l * 128] * bp[(size_t)l * 32];
        P *= a;
    }
    Pend[(size_t)blk * 256 + t] = P;
    hend[(size_t)blk * 256 + t] = h;
}

// ------- scan pass 2: sequential combine; writes h_in in-place into hend -------
__global__ void __launch_bounds__(256) k_scan2(const float* __restrict__ Pend, float* __restrict__ hend) {
    int id = blockIdx.x * 256 + threadIdx.x;  // 16384 total
    int t = id & 255;
    int g = id >> 8;  // 0..63
    float h = 0.f;
    for (int c = 0; c < NCH; c++) {
        size_t idx = ((size_t)g * NCH + c) * 256 + t;
        float tmp = hend[idx];
        float Pv = Pend[idx];
        hend[idx] = h;               // h_in for chunk c
        h = Pv * h + tmp;
    }
}

// ------- scan pass 3: re-scan with h_in (from hend); y channel-last [bk][l][128] -------
__global__ void __launch_bounds__(256) k_scan3(const float* __restrict__ delta, const float* __restrict__ xsv,
                                               const float* __restrict__ bc, const float* __restrict__ Alogs,
                                               const float* __restrict__ Dsv, const float* __restrict__ hinb,
                                               float* __restrict__ y) {
    int blk = blockIdx.x;
    int c = blk & 31;
    int g = blk >> 5;
    int dgq = g & 7, bk = g >> 3;
    int k = bk & 3;
    int t = threadIdx.x;
    int n = t & 15;
    int d = dgq * 16 + (t >> 4);
    float A = -expf(Alogs[(k * 128 + d) * 16 + n]);
    float Dsd = Dsv[k * 128 + d];
    const float* dp = delta + (size_t)bk * cL * 128 + d;
    const float* xp = xsv + (size_t)bk * cL * 128 + d;
    const float* bp = bc + (size_t)bk * cL * 32 + n;
    const float* cp = bc + (size_t)bk * cL * 32 + 16 + n;
    float* yb = y + (size_t)bk * cL * 128 + d;
    int l0 = c * CHL, l1 = l0 + CHL;
    float h = hinb[(size_t)blk * 256 + t];
#pragma unroll 2
    for (int l = l0; l < l1; l++) {
        float dl = dp[(size_t)l * 128];
        float xv = xp[(size_t)l * 128];
        float a = expf(dl * A);
        h = a * h + dl * xv * bp[(size_t)l * 32];
        float contrib = row_sum16(h * cp[(size_t)l * 32]);
        if (n == 0) yb[(size_t)l * 128] = contrib + xv * Dsd;
    }
}

// ------- combine 4 dirs + layernorm + gate + out_proj -> x1 (B,64,L) -------
__global__ void __launch_bounds__(128) k_comb(const float* __restrict__ y, const float* __restrict__ z,
                                              const float* __restrict__ lng, const float* __restrict__ lnb,
                                              const float* __restrict__ opw, float* __restrict__ x1) {
    int pos = blockIdx.x;
    int b = pos / cL, l = pos % cL;
    int h = l / cW, w = l % cW;
    int lwh = w * cH + h;
    int t = threadIdx.x;  // d
    float v = y[((size_t)(b * 4 + 0) * cL + l) * 128 + t] +
              y[((size_t)(b * 4 + 2) * cL + (cL - 1 - l)) * 128 + t] +
              y[((size_t)(b * 4 + 1) * cL + lwh) * 128 + t] +
              y[((size_t)(b * 4 + 3) * cL + (cL - 1 - lwh)) * 128 + t];
    __shared__ float red[2];
    __shared__ float vv[128];
    float s = v;
    for (int m = 32; m > 0; m >>= 1) s += __shfl_down(s, m);
    if ((t & 63) == 0) red[t >> 6] = s;
    __syncthreads();
    float mu = (red[0] + red[1]) * (1.f / 128.f);
    float dv = v - mu;
    float s2 = dv * dv;
    for (int m = 32; m > 0; m >>= 1) s2 += __shfl_down(s2, m);
    __syncthreads();
    if ((t & 63) == 0) red[t >> 6] = s2;
    __syncthreads();
    float var = (red[0] + red[1]) * (1.f / 128.f);
    float yn = dv * rsqrtf(var + cEPS) * lng[t] + lnb[t];
    float zz = z[((size_t)b * cL + l) * 128 + t];
    vv[t] = yn * silu(zz);
    __syncthreads();
    if (t < 64) {
        const float* wr = opw + t * 128;
        float acc = 0.f;
#pragma unroll 16
        for (int d2 = 0; d2 < 128; d2++) acc += vv[d2] * wr[d2];
        x1[(b * 64 + t) * cL + l] = acc;
    }
}

// ------- final MLP: silu(fc1(x1)) -> fc2 + residual -------
__global__ void __launch_bounds__(128) k_final(const float* __restrict__ x1, const float* __restrict__ f1w,
                                               const float* __restrict__ f1b, const float* __restrict__ f2w,
                                               const float* __restrict__ f2b, float* __restrict__ out) {
    int pos = blockIdx.x;
    int b = pos / cL, l = pos % cL;
    int t = threadIdx.x;
    __shared__ float xv[64], h1[128];
    if (t < 64) xv[t] = x1[(b * 64 + t) * cL + l];
    __syncthreads();
    float acc = f1b[t];
    const float* wr = f1w + t * 64;
#pragma unroll 16
    for (int c = 0; c < 64; c++) acc += xv[c] * wr[c];
    h1[t] = silu(acc);
    __syncthreads();
    if (t < 64) {
        float acc2 = f2b[t];
        const float* w2 = f2w + t * 128;
#pragma unroll 16
        for (int j = 0; j < 128; j++) acc2 += h1[j] * w2[j];
        out[(b * 64 + t) * cL + l] = acc2 + xv[t];
    }
}

extern "C" void kernel_launch(void* const* d_in, const int* in_sizes, int n_in,
                              void* d_out, int out_size, void* d_ws, size_t ws_size,
                              hipStream_t stream) {
    (void)in_sizes; (void)n_in; (void)out_size; (void)ws_size;
    const float* x    = (const float*)d_in[0];
    const float* s0g  = (const float*)d_in[1];
    const float* s0b  = (const float*)d_in[2];
    const float* s0w  = (const float*)d_in[3];
    const float* s1g  = (const float*)d_in[4];
    const float* s1b  = (const float*)d_in[5];
    const float* s1w  = (const float*)d_in[6];
    const float* s2g  = (const float*)d_in[7];
    const float* s2b  = (const float*)d_in[8];
    const float* s2w  = (const float*)d_in[9];
    const float* s3g  = (const float*)d_in[10];
    const float* s3b  = (const float*)d_in[11];
    const float* s3w  = (const float*)d_in[12];
    const float* s4g  = (const float*)d_in[13];
    const float* s4b  = (const float*)d_in[14];
    const float* s4w  = (const float*)d_in[15];
    const float* cg   = (const float*)d_in[16];
    const float* cbb  = (const float*)d_in[17];
    const float* cw   = (const float*)d_in[18];
    const float* scg  = (const float*)d_in[19];
    const float* scb  = (const float*)d_in[20];
    const float* scw  = (const float*)d_in[21];
    const float* ipw  = (const float*)d_in[22];
    const float* dww  = (const float*)d_in[23];
    const float* dwb  = (const float*)d_in[24];
    const float* xpw  = (const float*)d_in[25];
    const float* dtw  = (const float*)d_in[26];
    const float* dtb  = (const float*)d_in[27];
    const float* Alog = (const float*)d_in[28];
    const float* Dsv  = (const float*)d_in[29];
    const float* lng  = (const float*)d_in[30];
    const float* lnb  = (const float*)d_in[31];
    const float* opw  = (const float*)d_in[32];
    const float* f1w  = (const float*)d_in[33];
    const float* f1b  = (const float*)d_in[34];
    const float* f2w  = (const float*)d_in[35];
    const float* f2b  = (const float*)d_in[36];
    float* out = (float*)d_out;

    float* ws = (float*)d_ws;
    size_t off = 0;
    // --- dead-before-scan region (delta/xsv overlay it) ---
    float* pool3  = ws + off; off += (size_t)cB * 64 * cL;        // 294912
    float* pool5  = ws + off; off += (size_t)cB * 64 * 576;       // 73728
    float* pool9  = ws + off; off += (size_t)cB * 64 * 144;       // 18432
    float* gmean  = ws + off; off += (size_t)cB * 64;             // 128
    float* c2     = ws + off; off += (size_t)cB * 128 * 576;      // 147456
    float* c3     = ws + off; off += (size_t)cB * 128 * 144;      // 36864
    float* c4     = ws + off; off += (size_t)cB * 128;            // 256
    u16*   catbf  = (u16*)(ws + off); off += (size_t)cB * cL * 640 / 2;  // 1474560 fl
    u16*   xbf    = (u16*)(ws + off); off += (size_t)cB * cL * 64 / 2;   // 147456 fl
    u16*   w8     = (u16*)(ws + off); off += (size_t)64 * KTOT / 2;      // 186368 fl
    float* pbuf   = ws + off; off += (size_t)cB * cL * 64;        // 294912 (channel-last)
    float* xc     = ws + off; off += (size_t)cB * cL * 128;       // 589824
    // pad dead region so delta+xsv (2*2359296) fit under it
    off = 4718592;
    // --- live buffers ---
    float* xca    = ws + off; off += (size_t)cB * cL * 128;       // 589824; dead after k_xdbl2 -> hend overlay
    float* zbuf   = ws + off; off += (size_t)cB * cL * 128;       // 589824
    float* bcbuf  = ws + off; off += (size_t)cB * 4 * cL * 32;    // 589824
    float* Pend   = ws + off; off += (size_t)2048 * 256;          // 524288 (old Pend+hend slots)
    off += 262144;                                                // old hin slot, spare
    float* ybuf   = ws + off; off += (size_t)cB * 4 * cL * 128;   // 2359296
    float* x1     = ws + off; off += (size_t)cB * 64 * cL;        // 294912
    // overlays
    float* delta  = ws + 0;
    float* xsv    = ws + (size_t)cB * 4 * cL * 128;
    float* hend   = xca;          // 524288 <= 589824, xca dead after k_xdbl2
    float* part   = ybuf;         // 9*294912 = 2654208 <= ybuf+x1, dead at k_comp time

    k_pool3<<<(cB * 64 * cL + 255) / 256, 256, 0, stream>>>(x, pool3);
    k_pool<5, 2, 2, 24><<<(cB * 64 * 576 + 255) / 256, 256, 0, stream>>>(x, pool5);
    k_pool<9, 4, 4, 12><<<(cB * 64 * 144 + 255) / 256, 256, 0, stream>>>(x, pool9);
    k_gmean<<<cB * 64, 256, 0, stream>>>(x, gmean);
    k_c1<<<cB * 576, 128, 0, stream>>>(pool5, s2g, s2b, s2w, c2, 576);
    k_c1<<<cB * 144, 128, 0, stream>>>(pool9, s3g, s3b, s3w, c3, 144);
    k_c1<<<cB, 128, 0, stream>>>(gmean, s4g, s4b, s4w, c4, 1);
    k_wprep<<<(64 * KTOT + 255) / 256, 256, 0, stream>>>(cw, scw, w8);
    k_cat<<<cB * cL, 128, 0, stream>>>(x, s0g, s0b, s0w, s1g, s1b, s1w, pool3, c2, c3, c4, cg, cbb, scg, scb, catbf, xbf);
    k_comp<<<(cB * cL / 16) * 9, 64, 0, stream>>>(catbf, xbf, w8, part);
    k_red<<<(cB * cL * 64 + 255) / 256, 256, 0, stream>>>(part, pbuf);
    k_inproj<<<cB * cL, 256, 0, stream>>>(pbuf, ipw, xc, zbuf);
    k_dw<<<(cB * cL * 128 + 255) / 256, 256, 0, stream>>>(xc, dww, dwb, xca);
    k_xdbl2<<<cB * 4 * cL, 128, 0, stream>>>(xca, xpw, dtw, dtb, bcbuf, delta, xsv);
    k_scan1<<<64 * NCH, 256, 0, stream>>>(delta, xsv, bcbuf, Alog, Pend, hend);
    k_scan2<<<64, 256, 0, stream>>>(Pend, hend);
    k_scan3<<<64 * NCH, 256, 0, stream>>>(delta, xsv, bcbuf, Alog, Dsv, hend, ybuf);
    k_comb<<<cB * cL, 128, 0, stream>>>(ybuf, zbuf, lng, lnb, opw, x1);
    k_final<<<cB * cL, 128, 0, stream>>>(x1, f1w, f1b, f2w, f2b, out);
}

// Round 6
// 394.207 us; speedup vs baseline: 6.9524x; 1.1612x over previous
//
#include <hip/hip_runtime.h>
#include <math.h>

constexpr int cB = 2, cC = 64, cH = 48, cW = 48, cL = 48 * 48;
constexpr int cBR = 128, cDI = 128, cNS = 16, cRK = 4, cK = 4;
constexpr float cEPS = 1e-5f;
constexpr int NCH = 32;          // scan chunks
constexpr int CHL = cL / NCH;    // 72 positions per chunk
constexpr int KTOT = 5824;       // 9*640 conv + 64 shortcut

typedef unsigned short u16;
typedef unsigned int u32;
typedef short s16x8 __attribute__((ext_vector_type(8)));
typedef float f32x4 __attribute__((ext_vector_type(4)));

__device__ __forceinline__ float bnrelu(float v, float g, float b) {
    float y = v * (g * rsqrtf(1.0f + cEPS)) + b;
    return y > 0.f ? y : 0.f;
}
__device__ __forceinline__ float silu(float v) {
    return v / (1.f + expf(-v));
}
__device__ __forceinline__ u16 f2bf(float f) {
    u32 u = __float_as_uint(f);
    u = (u + 0x7fffu + ((u >> 16) & 1u)) >> 16;
    return (u16)u;
}
__device__ __forceinline__ float bf2f(u16 v) {
    return __uint_as_float(((u32)v) << 16);
}
__device__ __forceinline__ s16x8 cvt8(const float* p) {
    s16x8 r;
#pragma unroll
    for (int i = 0; i < 8; i++) r[i] = (short)f2bf(p[i]);
    return r;
}
// sum over each aligned 16-lane row via DPP (full-rate VALU, no DS pipe)
__device__ __forceinline__ float row_sum16(float v) {
    v += __int_as_float(__builtin_amdgcn_update_dpp(0, __float_as_int(v), 0xB1, 0xF, 0xF, true));  // quad xor1
    v += __int_as_float(__builtin_amdgcn_update_dpp(0, __float_as_int(v), 0x4E, 0xF, 0xF, true));  // quad xor2
    v += __int_as_float(__builtin_amdgcn_update_dpp(0, __float_as_int(v), 0x124, 0xF, 0xF, true)); // row_ror:4
    v += __int_as_float(__builtin_amdgcn_update_dpp(0, __float_as_int(v), 0x128, 0xF, 0xF, true)); // row_ror:8
    return v;
}

// ---------------- pools ----------------
__global__ void k_pool3(const float* __restrict__ x, float* __restrict__ out) {
    int idx = blockIdx.x * 256 + threadIdx.x;
    if (idx >= cB * cC * cL) return;
    int w = idx % cW, h = (idx / cW) % cH, bc = idx / cL;
    const float* p = x + bc * cL;
    float s = 0.f;
    for (int dh = -1; dh <= 1; dh++) {
        int hh = h + dh; if (hh < 0 || hh >= cH) continue;
        for (int dw = -1; dw <= 1; dw++) {
            int ww = w + dw; if (ww < 0 || ww >= cW) continue;
            s += p[hh * cW + ww];
        }
    }
    out[idx] = s * (1.f / 9.f);
}

template <int KS, int ST, int PD, int OS>
__global__ void k_pool(const float* __restrict__ x, float* __restrict__ out) {
    int idx = blockIdx.x * 256 + threadIdx.x;
    if (idx >= cB * cC * OS * OS) return;
    int w = idx % OS, h = (idx / OS) % OS, bc = idx / (OS * OS);
    const float* p = x + bc * cL;
    float s = 0.f;
    for (int kh = 0; kh < KS; kh++) {
        int hh = h * ST - PD + kh; if (hh < 0 || hh >= cH) continue;
        for (int kw = 0; kw < KS; kw++) {
            int ww = w * ST - PD + kw; if (ww < 0 || ww >= cW) continue;
            s += p[hh * cW + ww];
        }
    }
    out[idx] = s * (1.f / (KS * KS));
}

__global__ void k_gmean(const float* __restrict__ x, float* __restrict__ out) {
    int bc = blockIdx.x;
    const float* p = x + bc * cL;
    float s = 0.f;
    for (int i = threadIdx.x; i < cL; i += 256) s += p[i];
    __shared__ float sm[4];
    for (int m = 32; m > 0; m >>= 1) s += __shfl_down(s, m);
    if ((threadIdx.x & 63) == 0) sm[threadIdx.x >> 6] = s;
    __syncthreads();
    if (threadIdx.x == 0) out[bc] = (sm[0] + sm[1] + sm[2] + sm[3]) * (1.f / cL);
}

// --------- bn_relu + 1x1 conv (64 -> 128) ---------
__global__ void __launch_bounds__(128) k_c1(const float* __restrict__ in, const float* __restrict__ g,
                                            const float* __restrict__ bb, const float* __restrict__ w,
                                            float* __restrict__ out, int HW) {
    int pos = blockIdx.x;
    int b = pos / HW, pp = pos % HW;
    __shared__ float v[64];
    int t = threadIdx.x;
    if (t < 64) v[t] = bnrelu(in[(b * 64 + t) * HW + pp], g[t], bb[t]);
    __syncthreads();
    float acc = 0.f;
    const float* wr = w + t * 64;
#pragma unroll 16
    for (int c = 0; c < 64; c++) acc += v[c] * wr[c];
    out[(b * 128 + t) * HW + pp] = acc;
}

// ---------------- bilinear (half-pixel, clamped) ----------------
__device__ __forceinline__ float bilin(const float* __restrict__ p, int S, float sy, float sx) {
    float fy = floorf(sy), fx = floorf(sx);
    int iy = (int)fy, ix = (int)fx;
    float ay = sy - fy, ax = sx - fx;
    int y0 = min(max(iy, 0), S - 1), y1 = min(max(iy + 1, 0), S - 1);
    int x0 = min(max(ix, 0), S - 1), x1 = min(max(ix + 1, 0), S - 1);
    float v00 = p[y0 * S + x0], v01 = p[y0 * S + x1];
    float v10 = p[y1 * S + x0], v11 = p[y1 * S + x1];
    float a = v00 + (v01 - v00) * ax;
    float b = v10 + (v11 - v10) * ax;
    return a + (b - a) * ay;
}

// ------- upsample c2 (24x24) and c3 (12x12) to 48x48, channel-last bf16 -------
__global__ void k_up(const float* __restrict__ c2, const float* __restrict__ c3,
                     u16* __restrict__ u2, u16* __restrict__ u3) {
    int idx = blockIdx.x * 256 + threadIdx.x;
    int N = cB * cL * 128;
    if (idx >= 2 * N) return;
    bool second = idx >= N;
    int id = second ? idx - N : idx;
    int ch = id & 127;
    int rest = id >> 7;
    int px = rest % cL, b = rest / cL;
    int h = px / cW, w = px % cW;
    float v;
    if (second) v = bilin(c3 + (size_t)(b * 128 + ch) * 144, 12, h * 0.25f - 0.375f, w * 0.25f - 0.375f);
    else        v = bilin(c2 + (size_t)(b * 128 + ch) * 576, 24, h * 0.5f - 0.25f, w * 0.5f - 0.25f);
    (second ? u3 : u2)[id] = f2bf(v);
}

// ------- pack s0w|s1w into MFMA B-frag layout: [g][kt][q][nt][ln][j] -------
__global__ void k_wcat(const float* __restrict__ s0w, const float* __restrict__ s1w,
                       u16* __restrict__ wcat) {
    int idx = blockIdx.x * 256 + threadIdx.x;
    if (idx >= 2 * 128 * 64) return;
    int g = idx >> 13;
    int r = idx & 8191;
    int o = r >> 6, c = r & 63;
    float v = (g ? s1w : s0w)[r];
    int kt = c >> 5, q = (c >> 3) & 3, j = c & 7, nt = o >> 4, ln = o & 15;
    wcat[(size_t)((((g * 2 + kt) * 4 + q) * 8 + nt) * 16 + ln) * 8 + j] = f2bf(v);
}

// ------- pack in_proj weights (256x64) into B-frag layout: [kt][q][nt][ln][j] -------
__global__ void k_ipw(const float* __restrict__ ipw, u16* __restrict__ ipk) {
    int idx = blockIdx.x * 256 + threadIdx.x;
    if (idx >= 256 * 64) return;
    int o = idx >> 6, c = idx & 63;
    int kt = c >> 5, q = (c >> 3) & 3, j = c & 7, nt = o >> 4, ln = o & 15;
    ipk[(size_t)(((kt * 4 + q) * 16 + nt) * 16 + ln) * 8 + j] = f2bf(ipw[idx]);
}

// ------- cat build: staged coalesced loads + MFMA 1x1 convs + fused epilogue -------
// 288 blocks (16 px each), 256 thr = 4 waves; wave wv covers out-ch ntiles {2wv, 2wv+1}
__global__ void __launch_bounds__(256) k_cat2(
    const float* __restrict__ x, const float* __restrict__ pool3, const float* __restrict__ c4,
    const float* __restrict__ s0g, const float* __restrict__ s0b,
    const float* __restrict__ s1g, const float* __restrict__ s1b,
    const float* __restrict__ scg, const float* __restrict__ scb,
    const float* __restrict__ cg, const float* __restrict__ cbb,
    const u16* __restrict__ wcat, const u16* __restrict__ u2, const u16* __restrict__ u3,
    u16* __restrict__ catbf, u16* __restrict__ xbf) {
    int blk = blockIdx.x;
    int b = blk / 144;
    int l0 = (blk % 144) * 16;
    int t = threadIdx.x;
    __shared__ float axv[16][68];
    __shared__ float ap3[16][68];
    __shared__ u16 axc[16][66];
    int pc = t >> 4, p = t & 15;
#pragma unroll
    for (int i = 0; i < 4; i++) {
        int c = i * 16 + pc;
        float xraw = x[(size_t)(b * 64 + c) * cL + l0 + p];
        float p3raw = pool3[(size_t)(b * 64 + c) * cL + l0 + p];
        axv[p][c] = bnrelu(xraw, s0g[c], s0b[c]);
        ap3[p][c] = bnrelu(p3raw, s1g[c], s1b[c]);
        axc[p][c] = f2bf(bnrelu(xraw, scg[c], scb[c]));
    }
    __syncthreads();
    // write xbf coalesced
#pragma unroll
    for (int i = 0; i < 4; i++) {
        int idx = i * 256 + t;
        int pp = idx >> 6, cc = idx & 63;
        xbf[((size_t)b * cL + l0 + pp) * 64 + cc] = axc[pp][cc];
    }
    int wv = t >> 6, lane = t & 63, ln = lane & 15, q = lane >> 4;
    f32x4 ax[2] = {};
    f32x4 ay[2] = {};
#pragma unroll
    for (int kt = 0; kt < 2; kt++) {
        s16x8 a0 = cvt8(&axv[ln][kt * 32 + q * 8]);
        s16x8 a1 = cvt8(&ap3[ln][kt * 32 + q * 8]);
#pragma unroll
        for (int jj = 0; jj < 2; jj++) {
            int nt = wv * 2 + jj;
            s16x8 b0 = *(const s16x8*)(wcat + (size_t)((((0 * 2 + kt) * 4 + q) * 8 + nt) * 16 + ln) * 8);
            s16x8 b1 = *(const s16x8*)(wcat + (size_t)((((1 * 2 + kt) * 4 + q) * 8 + nt) * 16 + ln) * 8);
            ax[jj] = __builtin_amdgcn_mfma_f32_16x16x32_bf16(a0, b0, ax[jj], 0, 0, 0);
            ay[jj] = __builtin_amdgcn_mfma_f32_16x16x32_bf16(a1, b1, ay[jj], 0, 0, 0);
        }
    }
    const u16* u2b = u2 + ((size_t)b * cL + l0) * 128;
    const u16* u3b = u3 + ((size_t)b * cL + l0) * 128;
#pragma unroll
    for (int jj = 0; jj < 2; jj++) {
        int ch = (wv * 2 + jj) * 16 + ln;
        float g0 = cg[ch], g1 = cg[128 + ch], g2 = cg[256 + ch], g3 = cg[384 + ch], g4 = cg[512 + ch];
        float b0 = cbb[ch], b1 = cbb[128 + ch], b2 = cbb[256 + ch], b3 = cbb[384 + ch], b4 = cbb[512 + ch];
        float c4v = c4[b * 128 + ch];
#pragma unroll
        for (int r = 0; r < 4; r++) {
            int pp = q * 4 + r;
            float x0 = ax[jj][r];
            float y1 = ay[jj][r] + x0;
            float y2 = x0 + bf2f(u2b[(size_t)pp * 128 + ch]);
            float y3 = x0 + bf2f(u3b[(size_t)pp * 128 + ch]);
            float y4 = x0 + c4v;
            u16* base = catbf + ((size_t)b * cL + l0 + pp) * 640;
            base[ch]       = f2bf(bnrelu(x0, g0, b0));
            base[128 + ch] = f2bf(bnrelu(y1, g1, b1));
            base[256 + ch] = f2bf(bnrelu(y2, g2, b2));
            base[384 + ch] = f2bf(bnrelu(y3, g3, b3));
            base[512 + ch] = f2bf(bnrelu(y4, g4, b4));
        }
    }
}

// ------- weight prep: w8[(k/8)][o][k%8] bf16; k = tap*640+ch conv, 5760+c shortcut -------
__global__ void k_wprep(const float* __restrict__ cw, const float* __restrict__ scw,
                        u16* __restrict__ w8) {
    int idx = blockIdx.x * 256 + threadIdx.x;
    if (idx >= 64 * KTOT) return;
    int o = idx / KTOT, kx = idx % KTOT;
    float v;
    if (kx < 5760) { int tap = kx / 640, ch = kx % 640; v = cw[(o * 640 + ch) * 9 + tap]; }
    else v = scw[o * 64 + (kx - 5760)];
    w8[(((size_t)(kx >> 3) * 64) + o) * 8 + (kx & 7)] = f2bf(v);
}

// ------- comp 3x3 conv + shortcut: split-K MFMA GEMM -------
__global__ void __launch_bounds__(64) k_comp(const u16* __restrict__ catbf,
                                             const u16* __restrict__ xbf,
                                             const u16* __restrict__ w8,
                                             float* __restrict__ part) {
    int blk = blockIdx.x;
    int slice = blk % 9;
    int pxt = blk / 9;
    int pix0 = pxt * 16;
    int b = pix0 / cL;
    int lane = threadIdx.x;
    int ln = lane & 15, q = lane >> 4;
    int la = (pix0 + ln) - b * cL;
    int h = la / cW, w = la % cW;
    int kh = slice / 3 - 1, kw = slice % 3 - 1;
    int hh = h + kh, ww = w + kw;
    bool ok = (hh >= 0) && (hh < cH) && (ww >= 0) && (ww < cW);
    const u16* ap = catbf + ((size_t)b * cL + hh * cW + ww) * 640 + q * 8;
    f32x4 acc[4] = {};
    int kb = slice * 640;
#pragma unroll 4
    for (int cc = 0; cc < 20; cc++) {
        s16x8 av;
        if (ok) av = *(const s16x8*)(ap + cc * 32);
        else av = s16x8{0, 0, 0, 0, 0, 0, 0, 0};
        const u16* wrow = w8 + (((size_t)((kb + cc * 32) >> 3) + q) * 64) * 8;
#pragma unroll
        for (int j = 0; j < 4; j++) {
            s16x8 bv = *(const s16x8*)(wrow + (size_t)(j * 16 + ln) * 8);
            acc[j] = __builtin_amdgcn_mfma_f32_16x16x32_bf16(av, bv, acc[j], 0, 0, 0);
        }
    }
    if (slice == 4) {
        const u16* xp = xbf + (size_t)(pix0 + ln) * 64 + q * 8;
#pragma unroll
        for (int cc = 0; cc < 2; cc++) {
            s16x8 av = *(const s16x8*)(xp + cc * 32);
            const u16* wrow = w8 + (((size_t)((5760 + cc * 32) >> 3) + q) * 64) * 8;
#pragma unroll
            for (int j = 0; j < 4; j++) {
                s16x8 bv = *(const s16x8*)(wrow + (size_t)(j * 16 + ln) * 8);
                acc[j] = __builtin_amdgcn_mfma_f32_16x16x32_bf16(av, bv, acc[j], 0, 0, 0);
            }
        }
    }
    float* pb = part + ((size_t)slice * (cB * cL) + pix0) * 64;
#pragma unroll
    for (int j = 0; j < 4; j++) {
#pragma unroll
        for (int r = 0; r < 4; r++) {
            pb[(size_t)(q * 4 + r) * 64 + j * 16 + ln] = acc[j][r];
        }
    }
}

// ------- fused split-K reduce + in_proj MFMA: part -> xc (B,L,128), z (B,L,128) -------
// 288 blocks (16 px), 256 thr = 4 waves; wave wv covers ntiles {4wv..4wv+3} of 16
__global__ void __launch_bounds__(256) k_ip(const float* __restrict__ part, const u16* __restrict__ ipk,
                                            float* __restrict__ xc, float* __restrict__ z) {
    int px0 = blockIdx.x * 16;  // global pixel (b folded in)
    int t = threadIdx.x;
    __shared__ float pv[16][68];
#pragma unroll
    for (int i = 0; i < 4; i++) {
        int idx = i * 256 + t;
        int p = idx >> 6, c = idx & 63;
        float s = 0.f;
#pragma unroll
        for (int sl = 0; sl < 9; sl++)
            s += part[((size_t)sl * (cB * cL) + px0 + p) * 64 + c];
        pv[p][c] = s;
    }
    __syncthreads();
    int wv = t >> 6, lane = t & 63, ln = lane & 15, q = lane >> 4;
    f32x4 acc[4] = {};
#pragma unroll
    for (int kt = 0; kt < 2; kt++) {
        s16x8 a = cvt8(&pv[ln][kt * 32 + q * 8]);
#pragma unroll
        for (int jn = 0; jn < 4; jn++) {
            int nt = wv * 4 + jn;
            s16x8 bfr = *(const s16x8*)(ipk + (size_t)(((kt * 4 + q) * 16 + nt) * 16 + ln) * 8);
            acc[jn] = __builtin_amdgcn_mfma_f32_16x16x32_bf16(a, bfr, acc[jn], 0, 0, 0);
        }
    }
#pragma unroll
    for (int jn = 0; jn < 4; jn++) {
        int o = (wv * 4 + jn) * 16 + ln;
#pragma unroll
        for (int r = 0; r < 4; r++) {
            int p = q * 4 + r;
            if (o < 128) xc[((size_t)px0 + p) * 128 + o] = acc[jn][r];
            else         z[((size_t)px0 + p) * 128 + (o - 128)] = acc[jn][r];
        }
    }
}

// ------- depthwise 3x3 + bias + silu; channel-last in/out -------
__global__ void k_dw(const float* __restrict__ xc, const float* __restrict__ dww,
                     const float* __restrict__ dwb, float* __restrict__ xca) {
    int idx = blockIdx.x * 256 + threadIdx.x;
    if (idx >= cB * cL * cDI) return;
    int d = idx & 127;
    int rest = idx >> 7;
    int l = rest % cL, b = rest / cL;
    int h = l / cW, w = l % cW;
    const float* base = xc + (size_t)b * cL * 128 + d;
    float acc = dwb[d];
    const float* kw = dww + d * 9;
    for (int i = 0; i < 3; i++) {
        int hh = h + i - 1; if (hh < 0 || hh >= cH) continue;
        for (int j = 0; j < 3; j++) {
            int ww = w + j - 1; if (ww < 0 || ww >= cW) continue;
            acc += base[(size_t)(hh * cW + ww) * 128] * kw[i * 3 + j];
        }
    }
    xca[idx] = silu(acc);
}

// xs index mapping: offset into the (H*W) plane for direction k at scan pos l
__device__ __forceinline__ int xs_index(int k, int l) {
    int lp = (k & 2) ? (cL - 1 - l) : l;
    if (k & 1) { int w = lp / cH, h = lp % cH; return h * cW + w; }
    return lp;
}

// ------- x_dbl + softplus(delta) + xs snapshot; 4 positions per 256-thr block -------
__global__ void __launch_bounds__(256) k_xdbl3(const float* __restrict__ xca, const float* __restrict__ xpw,
                                               const float* __restrict__ dtw, const float* __restrict__ dtb,
                                               float* __restrict__ bc, float* __restrict__ delta,
                                               float* __restrict__ xsv) {
    int pos = blockIdx.x;  // bk*576 + lt
    int lt = pos % 576;
    int bk = pos / 576;
    int l0 = lt * 4;
    int k = bk & 3, b = bk >> 2;
    int t = threadIdx.x;
    __shared__ float v[4][132];
    __shared__ float xd[4][36];
#pragma unroll
    for (int i = 0; i < 2; i++) {
        int idx = i * 256 + t;
        int p = idx >> 7, d = idx & 127;
        int off = xs_index(k, l0 + p);
        v[p][d] = xca[((size_t)b * cL + off) * 128 + d];
    }
    __syncthreads();
    if (t < 144) {
        int p = t / 36, c = t % 36;
        const float* wr = xpw + (size_t)(k * 36 + c) * 128;
        float acc = 0.f;
#pragma unroll 16
        for (int d = 0; d < 128; d++) acc += v[p][d] * wr[d];
        xd[p][c] = acc;
        if (c >= 4) bc[((size_t)bk * cL + l0 + p) * 32 + (c - 4)] = acc;
    }
    __syncthreads();
#pragma unroll
    for (int i = 0; i < 2; i++) {
        int idx = i * 256 + t;
        int p = idx >> 7, d = idx & 127;
        const float* wd = dtw + (size_t)(k * 128 + d) * 4;
        float pre = dtb[k * 128 + d] + wd[0] * xd[p][0] + wd[1] * xd[p][1] + wd[2] * xd[p][2] + wd[3] * xd[p][3];
        float dl = pre > 20.f ? pre : log1pf(expf(pre));
        size_t o = ((size_t)bk * cL + l0 + p) * 128 + d;
        delta[o] = dl;
        xsv[o] = v[p][d];
    }
}

// ------- scan pass 1: 256 thr = 16 d x 16 n; per-chunk local scan -------
__global__ void __launch_bounds__(256) k_scan1(const float* __restrict__ delta, const float* __restrict__ xsv,
                                               const float* __restrict__ bc, const float* __restrict__ Alogs,
                                               float* __restrict__ Pend, float* __restrict__ hend) {
    int blk = blockIdx.x;            // ((bk*8+dgq)*NCH + c)
    int c = blk & 31;
    if (c == NCH - 1) return;        // last chunk's P/h never consumed
    int g = blk >> 5;                // bk*8+dgq
    int dgq = g & 7, bk = g >> 3;
    int k = bk & 3;
    int t = threadIdx.x;
    int n = t & 15;
    int d = dgq * 16 + (t >> 4);
    float A = -expf(Alogs[(k * 128 + d) * 16 + n]);
    const float* dp = delta + (size_t)bk * cL * 128 + d;
    const float* xp = xsv + (size_t)bk * cL * 128 + d;
    const float* bp = bc + (size_t)bk * cL * 32 + n;
    int l0 = c * CHL, l1 = l0 + CHL;
    float P = 1.f, h = 0.f;
#pragma unroll 4
    for (int l = l0; l < l1; l++) {
        float dl = dp[(size_t)l * 128];
        float a = expf(dl * A);
        h = a * h + dl * xp[(size_t)l * 128] * bp[(size_t)l * 32];
        P *= a;
    }
    Pend[(size_t)blk * 256 + t] = P;
    hend[(size_t)blk * 256 + t] = h;
}

// ------- scan pass 2: sequential combine; writes h_in in-place into hend -------
__global__ void __launch_bounds__(256) k_scan2(const float* __restrict__ Pend, float* __restrict__ hend) {
    int id = blockIdx.x * 256 + threadIdx.x;  // 16384 total
    int t = id & 255;
    int g = id >> 8;  // 0..63
    float h = 0.f;
    for (int c = 0; c < NCH; c++) {
        size_t idx = ((size_t)g * NCH + c) * 256 + t;
        float tmp = hend[idx];
        float Pv = Pend[idx];
        hend[idx] = h;               // h_in for chunk c
        h = Pv * h + tmp;
    }
}

// ------- scan pass 3: re-scan with h_in (from hend); y channel-last [bk][l][128] -------
__global__ void __launch_bounds__(256) k_scan3(const float* __restrict__ delta, const float* __restrict__ xsv,
                                               const float* __restrict__ bc, const float* __restrict__ Alogs,
                                               const float* __restrict__ Dsv, const float* __restrict__ hinb,
                                               float* __restrict__ y) {
    int blk = blockIdx.x;
    int c = blk & 31;
    int g = blk >> 5;
    int dgq = g & 7, bk = g >> 3;
    int k = bk & 3;
    int t = threadIdx.x;
    int n = t & 15;
    int d = dgq * 16 + (t >> 4);
    float A = -expf(Alogs[(k * 128 + d) * 16 + n]);
    float Dsd = Dsv[k * 128 + d];
    const float* dp = delta + (size_t)bk * cL * 128 + d;
    const float* xp = xsv + (size_t)bk * cL * 128 + d;
    const float* bp = bc + (size_t)bk * cL * 32 + n;
    const float* cp = bc + (size_t)bk * cL * 32 + 16 + n;
    float* yb = y + (size_t)bk * cL * 128 + d;
    int l0 = c * CHL, l1 = l0 + CHL;
    float h = hinb[(size_t)blk * 256 + t];
#pragma unroll 2
    for (int l = l0; l < l1; l++) {
        float dl = dp[(size_t)l * 128];
        float xv = xp[(size_t)l * 128];
        float a = expf(dl * A);
        h = a * h + dl * xv * bp[(size_t)l * 32];
        float contrib = row_sum16(h * cp[(size_t)l * 32]);
        if (n == 0) yb[(size_t)l * 128] = contrib + xv * Dsd;
    }
}

// ------- combine 4 dirs + layernorm + gate + out_proj -> x1 (B,64,L) -------
__global__ void __launch_bounds__(128) k_comb(const float* __restrict__ y, const float* __restrict__ z,
                                              const float* __restrict__ lng, const float* __restrict__ lnb,
                                              const float* __restrict__ opw, float* __restrict__ x1) {
    int pos = blockIdx.x;
    int b = pos / cL, l = pos % cL;
    int h = l / cW, w = l % cW;
    int lwh = w * cH + h;
    int t = threadIdx.x;  // d
    float v = y[((size_t)(b * 4 + 0) * cL + l) * 128 + t] +
              y[((size_t)(b * 4 + 2) * cL + (cL - 1 - l)) * 128 + t] +
              y[((size_t)(b * 4 + 1) * cL + lwh) * 128 + t] +
              y[((size_t)(b * 4 + 3) * cL + (cL - 1 - lwh)) * 128 + t];
    __shared__ float red[2];
    __shared__ float vv[128];
    float s = v;
    for (int m = 32; m > 0; m >>= 1) s += __shfl_down(s, m);
    if ((t & 63) == 0) red[t >> 6] = s;
    __syncthreads();
    float mu = (red[0] + red[1]) * (1.f / 128.f);
    float dv = v - mu;
    float s2 = dv * dv;
    for (int m = 32; m > 0; m >>= 1) s2 += __shfl_down(s2, m);
    __syncthreads();
    if ((t & 63) == 0) red[t >> 6] = s2;
    __syncthreads();
    float var = (red[0] + red[1]) * (1.f / 128.f);
    float yn = dv * rsqrtf(var + cEPS) * lng[t] + lnb[t];
    float zz = z[((size_t)b * cL + l) * 128 + t];
    vv[t] = yn * silu(zz);
    __syncthreads();
    if (t < 64) {
        const float* wr = opw + t * 128;
        float acc = 0.f;
#pragma unroll 16
        for (int d2 = 0; d2 < 128; d2++) acc += vv[d2] * wr[d2];
        x1[(b * 64 + t) * cL + l] = acc;
    }
}

// ------- final MLP: silu(fc1(x1)) -> fc2 + residual -------
__global__ void __launch_bounds__(128) k_final(const float* __restrict__ x1, const float* __restrict__ f1w,
                                               const float* __restrict__ f1b, const float* __restrict__ f2w,
                                               const float* __restrict__ f2b, float* __restrict__ out) {
    int pos = blockIdx.x;
    int b = pos / cL, l = pos % cL;
    int t = threadIdx.x;
    __shared__ float xv[64], h1[128];
    if (t < 64) xv[t] = x1[(b * 64 + t) * cL + l];
    __syncthreads();
    float acc = f1b[t];
    const float* wr = f1w + t * 64;
#pragma unroll 16
    for (int c = 0; c < 64; c++) acc += xv[c] * wr[c];
    h1[t] = silu(acc);
    __syncthreads();
    if (t < 64) {
        float acc2 = f2b[t];
        const float* w2 = f2w + t * 128;
#pragma unroll 16
        for (int j = 0; j < 128; j++) acc2 += h1[j] * w2[j];
        out[(b * 64 + t) * cL + l] = acc2 + xv[t];
    }
}

extern "C" void kernel_launch(void* const* d_in, const int* in_sizes, int n_in,
                              void* d_out, int out_size, void* d_ws, size_t ws_size,
                              hipStream_t stream) {
    (void)in_sizes; (void)n_in; (void)out_size; (void)ws_size;
    const float* x    = (const float*)d_in[0];
    const float* s0g  = (const float*)d_in[1];
    const float* s0b  = (const float*)d_in[2];
    const float* s0w  = (const float*)d_in[3];
    const float* s1g  = (const float*)d_in[4];
    const float* s1b  = (const float*)d_in[5];
    const float* s1w  = (const float*)d_in[6];
    const float* s2g  = (const float*)d_in[7];
    const float* s2b  = (const float*)d_in[8];
    const float* s2w  = (const float*)d_in[9];
    const float* s3g  = (const float*)d_in[10];
    const float* s3b  = (const float*)d_in[11];
    const float* s3w  = (const float*)d_in[12];
    const float* s4g  = (const float*)d_in[13];
    const float* s4b  = (const float*)d_in[14];
    const float* s4w  = (const float*)d_in[15];
    const float* cg   = (const float*)d_in[16];
    const float* cbb  = (const float*)d_in[17];
    const float* cw   = (const float*)d_in[18];
    const float* scg  = (const float*)d_in[19];
    const float* scb  = (const float*)d_in[20];
    const float* scw  = (const float*)d_in[21];
    const float* ipw  = (const float*)d_in[22];
    const float* dww  = (const float*)d_in[23];
    const float* dwb  = (const float*)d_in[24];
    const float* xpw  = (const float*)d_in[25];
    const float* dtw  = (const float*)d_in[26];
    const float* dtb  = (const float*)d_in[27];
    const float* Alog = (const float*)d_in[28];
    const float* Dsv  = (const float*)d_in[29];
    const float* lng  = (const float*)d_in[30];
    const float* lnb  = (const float*)d_in[31];
    const float* opw  = (const float*)d_in[32];
    const float* f1w  = (const float*)d_in[33];
    const float* f1b  = (const float*)d_in[34];
    const float* f2w  = (const float*)d_in[35];
    const float* f2b  = (const float*)d_in[36];
    float* out = (float*)d_out;

    float* ws = (float*)d_ws;
    size_t off = 0;
    // --- dead-before-scan region (delta/xsv overlay it; everything here dies before k_xdbl3) ---
    float* pool3  = ws + off; off += (size_t)cB * 64 * cL;        // 294912
    float* pool5  = ws + off; off += (size_t)cB * 64 * 576;       // 73728
    float* pool9  = ws + off; off += (size_t)cB * 64 * 144;       // 18432
    float* gmean  = ws + off; off += (size_t)cB * 64;             // 128
    float* c2     = ws + off; off += (size_t)cB * 128 * 576;      // 147456
    float* c3     = ws + off; off += (size_t)cB * 128 * 144;      // 36864
    float* c4     = ws + off; off += (size_t)cB * 128;            // 256
    u16*   catbf  = (u16*)(ws + off); off += (size_t)cB * cL * 640 / 2;  // 737280 fl
    u16*   xbf    = (u16*)(ws + off); off += (size_t)cB * cL * 64 / 2;   // 73728 fl
    u16*   w8     = (u16*)(ws + off); off += (size_t)64 * KTOT / 2;      // 186368 fl
    float* xc     = ws + off; off += (size_t)cB * cL * 128;       // 589824
    u16*   u2     = (u16*)(ws + off); off += (size_t)cB * cL * 128 / 2;  // 294912 fl
    u16*   u3     = (u16*)(ws + off); off += (size_t)cB * cL * 128 / 2;  // 294912 fl
    u16*   wcat   = (u16*)(ws + off); off += (size_t)2 * 128 * 64 / 2;   // 8192 fl
    u16*   ipk    = (u16*)(ws + off); off += (size_t)256 * 64 / 2;       // 8192 fl
    // pad dead region so delta+xsv (2*2359296) fit under it
    off = 4718592;
    // --- live buffers ---
    float* xca    = ws + off; off += (size_t)cB * cL * 128;       // 589824; dead after k_xdbl3 -> hend overlay
    float* zbuf   = ws + off; off += (size_t)cB * cL * 128;       // 589824
    float* bcbuf  = ws + off; off += (size_t)cB * 4 * cL * 32;    // 589824
    float* Pend   = ws + off; off += (size_t)2048 * 256;          // 524288
    off += 262144;                                                // spare
    float* ybuf   = ws + off; off += (size_t)cB * 4 * cL * 128;   // 2359296
    float* x1     = ws + off; off += (size_t)cB * 64 * cL;        // 294912
    // overlays
    float* delta  = ws + 0;
    float* xsv    = ws + (size_t)cB * 4 * cL * 128;
    float* hend   = xca;          // 524288 <= 589824, xca dead after k_xdbl3
    float* part   = ybuf;         // 9*294912 = 2654208 <= ybuf+x1, dead at k_comp/k_ip time

    k_pool3<<<(cB * 64 * cL + 255) / 256, 256, 0, stream>>>(x, pool3);
    k_pool<5, 2, 2, 24><<<(cB * 64 * 576 + 255) / 256, 256, 0, stream>>>(x, pool5);
    k_pool<9, 4, 4, 12><<<(cB * 64 * 144 + 255) / 256, 256, 0, stream>>>(x, pool9);
    k_gmean<<<cB * 64, 256, 0, stream>>>(x, gmean);
    k_c1<<<cB * 576, 128, 0, stream>>>(pool5, s2g, s2b, s2w, c2, 576);
    k_c1<<<cB * 144, 128, 0, stream>>>(pool9, s3g, s3b, s3w, c3, 144);
    k_c1<<<cB, 128, 0, stream>>>(gmean, s4g, s4b, s4w, c4, 1);
    k_wprep<<<(64 * KTOT + 255) / 256, 256, 0, stream>>>(cw, scw, w8);
    k_wcat<<<(2 * 128 * 64 + 255) / 256, 256, 0, stream>>>(s0w, s1w, wcat);
    k_ipw<<<(256 * 64 + 255) / 256, 256, 0, stream>>>(ipw, ipk);
    k_up<<<(2 * cB * cL * 128 + 255) / 256, 256, 0, stream>>>(c2, c3, u2, u3);
    k_cat2<<<cB * 144, 256, 0, stream>>>(x, pool3, c4, s0g, s0b, s1g, s1b, scg, scb, cg, cbb, wcat, u2, u3, catbf, xbf);
    k_comp<<<(cB * cL / 16) * 9, 64, 0, stream>>>(catbf, xbf, w8, part);
    k_ip<<<cB * cL / 16, 256, 0, stream>>>(part, ipk, xc, zbuf);
    k_dw<<<(cB * cL * 128 + 255) / 256, 256, 0, stream>>>(xc, dww, dwb, xca);
    k_xdbl3<<<cB * 4 * 576, 256, 0, stream>>>(xca, xpw, dtw, dtb, bcbuf, delta, xsv);
    k_scan1<<<64 * NCH, 256, 0, stream>>>(delta, xsv, bcbuf, Alog, Pend, hend);
    k_scan2<<<64, 256, 0, stream>>>(Pend, hend);
    k_scan3<<<64 * NCH, 256, 0, stream>>>(delta, xsv, bcbuf, Alog, Dsv, hend, ybuf);
    k_comb<<<cB * cL, 128, 0, stream>>>(ybuf, zbuf, lng, lnb, opw, x1);
    k_final<<<cB * cL, 128, 0, stream>>>(x1, f1w, f1b, f2w, f2b, out);
}

// Round 7
// 338.563 us; speedup vs baseline: 8.0951x; 1.1644x over previous
//
#include <hip/hip_runtime.h>
#include <math.h>

constexpr int cB = 2, cC = 64, cH = 48, cW = 48, cL = 48 * 48;
constexpr int cBR = 128, cDI = 128, cNS = 16, cRK = 4, cK = 4;
constexpr float cEPS = 1e-5f;
constexpr int NCH = 32;          // scan chunks
constexpr int CHL = cL / NCH;    // 72 positions per chunk
constexpr int KTOT = 5824;       // 9*640 conv + 64 shortcut

typedef unsigned short u16;
typedef unsigned int u32;
typedef short s16x8 __attribute__((ext_vector_type(8)));
typedef float f32x4 __attribute__((ext_vector_type(4)));

__device__ __forceinline__ float bnrelu(float v, float g, float b) {
    float y = v * (g * rsqrtf(1.0f + cEPS)) + b;
    return y > 0.f ? y : 0.f;
}
__device__ __forceinline__ float silu(float v) {
    return v / (1.f + expf(-v));
}
__device__ __forceinline__ u16 f2bf(float f) {
    u32 u = __float_as_uint(f);
    u = (u + 0x7fffu + ((u >> 16) & 1u)) >> 16;
    return (u16)u;
}
__device__ __forceinline__ float bf2f(u16 v) {
    return __uint_as_float(((u32)v) << 16);
}
__device__ __forceinline__ s16x8 cvt8(const float* p) {
    s16x8 r;
#pragma unroll
    for (int i = 0; i < 8; i++) r[i] = (short)f2bf(p[i]);
    return r;
}
// sum over each aligned 16-lane row via DPP (full-rate VALU, no DS pipe)
__device__ __forceinline__ float row_sum16(float v) {
    v += __int_as_float(__builtin_amdgcn_update_dpp(0, __float_as_int(v), 0xB1, 0xF, 0xF, true));  // quad xor1
    v += __int_as_float(__builtin_amdgcn_update_dpp(0, __float_as_int(v), 0x4E, 0xF, 0xF, true));  // quad xor2
    v += __int_as_float(__builtin_amdgcn_update_dpp(0, __float_as_int(v), 0x124, 0xF, 0xF, true)); // row_ror:4
    v += __int_as_float(__builtin_amdgcn_update_dpp(0, __float_as_int(v), 0x128, 0xF, 0xF, true)); // row_ror:8
    return v;
}

// ---------------- pools ----------------
__global__ void k_pool3(const float* __restrict__ x, float* __restrict__ out) {
    int idx = blockIdx.x * 256 + threadIdx.x;
    if (idx >= cB * cC * cL) return;
    int w = idx % cW, h = (idx / cW) % cH, bc = idx / cL;
    const float* p = x + bc * cL;
    float s = 0.f;
    for (int dh = -1; dh <= 1; dh++) {
        int hh = h + dh; if (hh < 0 || hh >= cH) continue;
        for (int dw = -1; dw <= 1; dw++) {
            int ww = w + dw; if (ww < 0 || ww >= cW) continue;
            s += p[hh * cW + ww];
        }
    }
    out[idx] = s * (1.f / 9.f);
}

template <int KS, int ST, int PD, int OS>
__global__ void k_pool(const float* __restrict__ x, float* __restrict__ out) {
    int idx = blockIdx.x * 256 + threadIdx.x;
    if (idx >= cB * cC * OS * OS) return;
    int w = idx % OS, h = (idx / OS) % OS, bc = idx / (OS * OS);
    const float* p = x + bc * cL;
    float s = 0.f;
    for (int kh = 0; kh < KS; kh++) {
        int hh = h * ST - PD + kh; if (hh < 0 || hh >= cH) continue;
        for (int kw = 0; kw < KS; kw++) {
            int ww = w * ST - PD + kw; if (ww < 0 || ww >= cW) continue;
            s += p[hh * cW + ww];
        }
    }
    out[idx] = s * (1.f / (KS * KS));
}

__global__ void k_gmean(const float* __restrict__ x, float* __restrict__ out) {
    int bc = blockIdx.x;
    const float* p = x + bc * cL;
    float s = 0.f;
    for (int i = threadIdx.x; i < cL; i += 256) s += p[i];
    __shared__ float sm[4];
    for (int m = 32; m > 0; m >>= 1) s += __shfl_down(s, m);
    if ((threadIdx.x & 63) == 0) sm[threadIdx.x >> 6] = s;
    __syncthreads();
    if (threadIdx.x == 0) out[bc] = (sm[0] + sm[1] + sm[2] + sm[3]) * (1.f / cL);
}

// --------- bn_relu + 1x1 conv (64 -> 128) ---------
__global__ void __launch_bounds__(128) k_c1(const float* __restrict__ in, const float* __restrict__ g,
                                            const float* __restrict__ bb, const float* __restrict__ w,
                                            float* __restrict__ out, int HW) {
    int pos = blockIdx.x;
    int b = pos / HW, pp = pos % HW;
    __shared__ float v[64];
    int t = threadIdx.x;
    if (t < 64) v[t] = bnrelu(in[(b * 64 + t) * HW + pp], g[t], bb[t]);
    __syncthreads();
    float acc = 0.f;
    const float* wr = w + t * 64;
#pragma unroll 16
    for (int c = 0; c < 64; c++) acc += v[c] * wr[c];
    out[(b * 128 + t) * HW + pp] = acc;
}

// ---------------- bilinear (half-pixel, clamped) ----------------
__device__ __forceinline__ float bilin(const float* __restrict__ p, int S, float sy, float sx) {
    float fy = floorf(sy), fx = floorf(sx);
    int iy = (int)fy, ix = (int)fx;
    float ay = sy - fy, ax = sx - fx;
    int y0 = min(max(iy, 0), S - 1), y1 = min(max(iy + 1, 0), S - 1);
    int x0 = min(max(ix, 0), S - 1), x1 = min(max(ix + 1, 0), S - 1);
    float v00 = p[y0 * S + x0], v01 = p[y0 * S + x1];
    float v10 = p[y1 * S + x0], v11 = p[y1 * S + x1];
    float a = v00 + (v01 - v00) * ax;
    float b = v10 + (v11 - v10) * ax;
    return a + (b - a) * ay;
}

// ------- upsample c2 (24x24) and c3 (12x12) to 48x48, channel-last bf16 -------
__global__ void k_up(const float* __restrict__ c2, const float* __restrict__ c3,
                     u16* __restrict__ u2, u16* __restrict__ u3) {
    int idx = blockIdx.x * 256 + threadIdx.x;
    int N = cB * cL * 128;
    if (idx >= 2 * N) return;
    bool second = idx >= N;
    int id = second ? idx - N : idx;
    int ch = id & 127;
    int rest = id >> 7;
    int px = rest % cL, b = rest / cL;
    int h = px / cW, w = px % cW;
    float v;
    if (second) v = bilin(c3 + (size_t)(b * 128 + ch) * 144, 12, h * 0.25f - 0.375f, w * 0.25f - 0.375f);
    else        v = bilin(c2 + (size_t)(b * 128 + ch) * 576, 24, h * 0.5f - 0.25f, w * 0.5f - 0.25f);
    (second ? u3 : u2)[id] = f2bf(v);
}

// ------- pack s0w|s1w into MFMA B-frag layout: [g][kt][q][nt][ln][j] -------
__global__ void k_wcat(const float* __restrict__ s0w, const float* __restrict__ s1w,
                       u16* __restrict__ wcat) {
    int idx = blockIdx.x * 256 + threadIdx.x;
    if (idx >= 2 * 128 * 64) return;
    int g = idx >> 13;
    int r = idx & 8191;
    int o = r >> 6, c = r & 63;
    float v = (g ? s1w : s0w)[r];
    int kt = c >> 5, q = (c >> 3) & 3, j = c & 7, nt = o >> 4, ln = o & 15;
    wcat[(size_t)((((g * 2 + kt) * 4 + q) * 8 + nt) * 16 + ln) * 8 + j] = f2bf(v);
}

// ------- pack in_proj weights (256x64) into B-frag layout: [kt][q][nt][ln][j] -------
__global__ void k_ipw(const float* __restrict__ ipw, u16* __restrict__ ipk) {
    int idx = blockIdx.x * 256 + threadIdx.x;
    if (idx >= 256 * 64) return;
    int o = idx >> 6, c = idx & 63;
    int kt = c >> 5, q = (c >> 3) & 3, j = c & 7, nt = o >> 4, ln = o & 15;
    ipk[(size_t)(((kt * 4 + q) * 16 + nt) * 16 + ln) * 8 + j] = f2bf(ipw[idx]);
}

// ------- pack x_proj_w (144 x 128) into B-frag layout: [kt][q][nt(9)][ln][j] -------
__global__ void k_xpw(const float* __restrict__ xpw, u16* __restrict__ xpk) {
    int idx = blockIdx.x * 256 + threadIdx.x;
    if (idx >= 144 * 128) return;
    int o = idx >> 7, d = idx & 127;
    int kt = d >> 5, q = (d >> 3) & 3, j = d & 7, nt = o >> 4, ln = o & 15;
    xpk[(size_t)(((kt * 4 + q) * 9 + nt) * 16 + ln) * 8 + j] = f2bf(xpw[idx]);
}

// ------- cat build: staged coalesced loads + MFMA 1x1 convs + fused epilogue -------
__global__ void __launch_bounds__(256) k_cat2(
    const float* __restrict__ x, const float* __restrict__ pool3, const float* __restrict__ c4,
    const float* __restrict__ s0g, const float* __restrict__ s0b,
    const float* __restrict__ s1g, const float* __restrict__ s1b,
    const float* __restrict__ scg, const float* __restrict__ scb,
    const float* __restrict__ cg, const float* __restrict__ cbb,
    const u16* __restrict__ wcat, const u16* __restrict__ u2, const u16* __restrict__ u3,
    u16* __restrict__ catbf, u16* __restrict__ xbf) {
    int blk = blockIdx.x;
    int b = blk / 144;
    int l0 = (blk % 144) * 16;
    int t = threadIdx.x;
    __shared__ float axv[16][68];
    __shared__ float ap3[16][68];
    __shared__ u16 axc[16][66];
    int pc = t >> 4, p = t & 15;
#pragma unroll
    for (int i = 0; i < 4; i++) {
        int c = i * 16 + pc;
        float xraw = x[(size_t)(b * 64 + c) * cL + l0 + p];
        float p3raw = pool3[(size_t)(b * 64 + c) * cL + l0 + p];
        axv[p][c] = bnrelu(xraw, s0g[c], s0b[c]);
        ap3[p][c] = bnrelu(p3raw, s1g[c], s1b[c]);
        axc[p][c] = f2bf(bnrelu(xraw, scg[c], scb[c]));
    }
    __syncthreads();
#pragma unroll
    for (int i = 0; i < 4; i++) {
        int idx = i * 256 + t;
        int pp = idx >> 6, cc = idx & 63;
        xbf[((size_t)b * cL + l0 + pp) * 64 + cc] = axc[pp][cc];
    }
    int wv = t >> 6, lane = t & 63, ln = lane & 15, q = lane >> 4;
    f32x4 ax[2] = {};
    f32x4 ay[2] = {};
#pragma unroll
    for (int kt = 0; kt < 2; kt++) {
        s16x8 a0 = cvt8(&axv[ln][kt * 32 + q * 8]);
        s16x8 a1 = cvt8(&ap3[ln][kt * 32 + q * 8]);
#pragma unroll
        for (int jj = 0; jj < 2; jj++) {
            int nt = wv * 2 + jj;
            s16x8 b0 = *(const s16x8*)(wcat + (size_t)((((0 * 2 + kt) * 4 + q) * 8 + nt) * 16 + ln) * 8);
            s16x8 b1 = *(const s16x8*)(wcat + (size_t)((((1 * 2 + kt) * 4 + q) * 8 + nt) * 16 + ln) * 8);
            ax[jj] = __builtin_amdgcn_mfma_f32_16x16x32_bf16(a0, b0, ax[jj], 0, 0, 0);
            ay[jj] = __builtin_amdgcn_mfma_f32_16x16x32_bf16(a1, b1, ay[jj], 0, 0, 0);
        }
    }
    const u16* u2b = u2 + ((size_t)b * cL + l0) * 128;
    const u16* u3b = u3 + ((size_t)b * cL + l0) * 128;
#pragma unroll
    for (int jj = 0; jj < 2; jj++) {
        int ch = (wv * 2 + jj) * 16 + ln;
        float g0 = cg[ch], g1 = cg[128 + ch], g2 = cg[256 + ch], g3 = cg[384 + ch], g4 = cg[512 + ch];
        float b0 = cbb[ch], b1 = cbb[128 + ch], b2 = cbb[256 + ch], b3 = cbb[384 + ch], b4 = cbb[512 + ch];
        float c4v = c4[b * 128 + ch];
#pragma unroll
        for (int r = 0; r < 4; r++) {
            int pp = q * 4 + r;
            float x0 = ax[jj][r];
            float y1 = ay[jj][r] + x0;
            float y2 = x0 + bf2f(u2b[(size_t)pp * 128 + ch]);
            float y3 = x0 + bf2f(u3b[(size_t)pp * 128 + ch]);
            float y4 = x0 + c4v;
            u16* base = catbf + ((size_t)b * cL + l0 + pp) * 640;
            base[ch]       = f2bf(bnrelu(x0, g0, b0));
            base[128 + ch] = f2bf(bnrelu(y1, g1, b1));
            base[256 + ch] = f2bf(bnrelu(y2, g2, b2));
            base[384 + ch] = f2bf(bnrelu(y3, g3, b3));
            base[512 + ch] = f2bf(bnrelu(y4, g4, b4));
        }
    }
}

// ------- weight prep: w8[(k/8)][o][k%8] bf16; k = tap*640+ch conv, 5760+c shortcut -------
__global__ void k_wprep(const float* __restrict__ cw, const float* __restrict__ scw,
                        u16* __restrict__ w8) {
    int idx = blockIdx.x * 256 + threadIdx.x;
    if (idx >= 64 * KTOT) return;
    int o = idx / KTOT, kx = idx % KTOT;
    float v;
    if (kx < 5760) { int tap = kx / 640, ch = kx % 640; v = cw[(o * 640 + ch) * 9 + tap]; }
    else v = scw[o * 64 + (kx - 5760)];
    w8[(((size_t)(kx >> 3) * 64) + o) * 8 + (kx & 7)] = f2bf(v);
}

// ------- comp 3x3 conv + shortcut: split-K MFMA GEMM -------
__global__ void __launch_bounds__(64) k_comp(const u16* __restrict__ catbf,
                                             const u16* __restrict__ xbf,
                                             const u16* __restrict__ w8,
                                             float* __restrict__ part) {
    int blk = blockIdx.x;
    int slice = blk % 9;
    int pxt = blk / 9;
    int pix0 = pxt * 16;
    int b = pix0 / cL;
    int lane = threadIdx.x;
    int ln = lane & 15, q = lane >> 4;
    int la = (pix0 + ln) - b * cL;
    int h = la / cW, w = la % cW;
    int kh = slice / 3 - 1, kw = slice % 3 - 1;
    int hh = h + kh, ww = w + kw;
    bool ok = (hh >= 0) && (hh < cH) && (ww >= 0) && (ww < cW);
    const u16* ap = catbf + ((size_t)b * cL + hh * cW + ww) * 640 + q * 8;
    f32x4 acc[4] = {};
    int kb = slice * 640;
#pragma unroll 4
    for (int cc = 0; cc < 20; cc++) {
        s16x8 av;
        if (ok) av = *(const s16x8*)(ap + cc * 32);
        else av = s16x8{0, 0, 0, 0, 0, 0, 0, 0};
        const u16* wrow = w8 + (((size_t)((kb + cc * 32) >> 3) + q) * 64) * 8;
#pragma unroll
        for (int j = 0; j < 4; j++) {
            s16x8 bv = *(const s16x8*)(wrow + (size_t)(j * 16 + ln) * 8);
            acc[j] = __builtin_amdgcn_mfma_f32_16x16x32_bf16(av, bv, acc[j], 0, 0, 0);
        }
    }
    if (slice == 4) {
        const u16* xp = xbf + (size_t)(pix0 + ln) * 64 + q * 8;
#pragma unroll
        for (int cc = 0; cc < 2; cc++) {
            s16x8 av = *(const s16x8*)(xp + cc * 32);
            const u16* wrow = w8 + (((size_t)((5760 + cc * 32) >> 3) + q) * 64) * 8;
#pragma unroll
            for (int j = 0; j < 4; j++) {
                s16x8 bv = *(const s16x8*)(wrow + (size_t)(j * 16 + ln) * 8);
                acc[j] = __builtin_amdgcn_mfma_f32_16x16x32_bf16(av, bv, acc[j], 0, 0, 0);
            }
        }
    }
    float* pb = part + ((size_t)slice * (cB * cL) + pix0) * 64;
#pragma unroll
    for (int j = 0; j < 4; j++) {
#pragma unroll
        for (int r = 0; r < 4; r++) {
            pb[(size_t)(q * 4 + r) * 64 + j * 16 + ln] = acc[j][r];
        }
    }
}

// ------- fused split-K reduce + in_proj MFMA: part -> xc (B,L,128), z (B,L,128) -------
__global__ void __launch_bounds__(256) k_ip(const float* __restrict__ part, const u16* __restrict__ ipk,
                                            float* __restrict__ xc, float* __restrict__ z) {
    int px0 = blockIdx.x * 16;
    int t = threadIdx.x;
    __shared__ float pv[16][68];
#pragma unroll
    for (int i = 0; i < 4; i++) {
        int idx = i * 256 + t;
        int p = idx >> 6, c = idx & 63;
        float s = 0.f;
#pragma unroll
        for (int sl = 0; sl < 9; sl++)
            s += part[((size_t)sl * (cB * cL) + px0 + p) * 64 + c];
        pv[p][c] = s;
    }
    __syncthreads();
    int wv = t >> 6, lane = t & 63, ln = lane & 15, q = lane >> 4;
    f32x4 acc[4] = {};
#pragma unroll
    for (int kt = 0; kt < 2; kt++) {
        s16x8 a = cvt8(&pv[ln][kt * 32 + q * 8]);
#pragma unroll
        for (int jn = 0; jn < 4; jn++) {
            int nt = wv * 4 + jn;
            s16x8 bfr = *(const s16x8*)(ipk + (size_t)(((kt * 4 + q) * 16 + nt) * 16 + ln) * 8);
            acc[jn] = __builtin_amdgcn_mfma_f32_16x16x32_bf16(a, bfr, acc[jn], 0, 0, 0);
        }
    }
#pragma unroll
    for (int jn = 0; jn < 4; jn++) {
        int o = (wv * 4 + jn) * 16 + ln;
#pragma unroll
        for (int r = 0; r < 4; r++) {
            int p = q * 4 + r;
            if (o < 128) xc[((size_t)px0 + p) * 128 + o] = acc[jn][r];
            else         z[((size_t)px0 + p) * 128 + (o - 128)] = acc[jn][r];
        }
    }
}

// ------- depthwise 3x3 + bias + silu; channel-last in/out -------
__global__ void k_dw(const float* __restrict__ xc, const float* __restrict__ dww,
                     const float* __restrict__ dwb, float* __restrict__ xca) {
    int idx = blockIdx.x * 256 + threadIdx.x;
    if (idx >= cB * cL * cDI) return;
    int d = idx & 127;
    int rest = idx >> 7;
    int l = rest % cL, b = rest / cL;
    int h = l / cW, w = l % cW;
    const float* base = xc + (size_t)b * cL * 128 + d;
    float acc = dwb[d];
    const float* kw = dww + d * 9;
    for (int i = 0; i < 3; i++) {
        int hh = h + i - 1; if (hh < 0 || hh >= cH) continue;
        for (int j = 0; j < 3; j++) {
            int ww = w + j - 1; if (ww < 0 || ww >= cW) continue;
            acc += base[(size_t)(hh * cW + ww) * 128] * kw[i * 3 + j];
        }
    }
    xca[idx] = silu(acc);
}

// xs index mapping: offset into the (H*W) plane for direction k at scan pos l
__device__ __forceinline__ int xs_index(int k, int l) {
    int lp = (k & 2) ? (cL - 1 - l) : l;
    if (k & 1) { int w = lp / cH, h = lp % cH; return h * cW + w; }
    return lp;
}

// ------- spatial x_dbl via MFMA + fused softplus; outputs in SPATIAL order -------
// 288 blocks (16 px), 256 thr = 4 waves; N=144 (4k x 36) split as ntiles {wv, wv+4, [8 for wv0]}
__global__ void __launch_bounds__(256) k_xdbl4(const float* __restrict__ xca, const u16* __restrict__ xpk,
                                               const float* __restrict__ dtw, const float* __restrict__ dtb,
                                               float* __restrict__ bc, float* __restrict__ delta) {
    int blk = blockIdx.x;
    int b = blk / 144;
    int l0 = (blk % 144) * 16;
    int t = threadIdx.x;
    __shared__ float av[16][132];
    __shared__ float Dt[16][148];
#pragma unroll
    for (int i = 0; i < 8; i++) {
        int id = i * 256 + t;
        int d = id & 127, p = id >> 7;
        av[p][d] = xca[((size_t)b * cL + l0 + p) * 128 + d];
    }
    __syncthreads();
    int wv = t >> 6, lane = t & 63, ln = lane & 15, q = lane >> 4;
    int nmax = (wv == 0) ? 3 : 2;
    f32x4 acc[3] = {};
#pragma unroll
    for (int kt = 0; kt < 4; kt++) {
        s16x8 a = cvt8(&av[ln][kt * 32 + q * 8]);
        for (int i = 0; i < nmax; i++) {
            int nt = (i == 2) ? 8 : wv + i * 4;
            s16x8 bfr = *(const s16x8*)(xpk + (size_t)(((kt * 4 + q) * 9 + nt) * 16 + ln) * 8);
            acc[i] = __builtin_amdgcn_mfma_f32_16x16x32_bf16(a, bfr, acc[i], 0, 0, 0);
        }
    }
    for (int i = 0; i < nmax; i++) {
        int nt = (i == 2) ? 8 : wv + i * 4;
#pragma unroll
        for (int r = 0; r < 4; r++)
            Dt[q * 4 + r][nt * 16 + ln] = acc[i][r];
    }
    __syncthreads();
    // bc out: (bk, p_spatial, 32), coalesced
#pragma unroll
    for (int i = 0; i < 8; i++) {
        int id = i * 256 + t;
        int cc = id & 31, kk = (id >> 5) & 3, p = id >> 7;
        bc[((size_t)(b * 4 + kk) * cL + l0 + p) * 32 + cc] = Dt[p][kk * 36 + 4 + cc];
    }
    // delta = softplus(dtb + dts . dtw): (bk, p_spatial, 128), coalesced
    for (int i = 0; i < 32; i++) {
        int id = i * 256 + t;
        int d = id & 127, kk = (id >> 7) & 3, p = id >> 9;
        const float* wd = dtw + (size_t)(kk * 128 + d) * 4;
        float pre = dtb[kk * 128 + d] + wd[0] * Dt[p][kk * 36] + wd[1] * Dt[p][kk * 36 + 1]
                  + wd[2] * Dt[p][kk * 36 + 2] + wd[3] * Dt[p][kk * 36 + 3];
        float dl = pre > 20.f ? pre : log1pf(expf(pre));
        delta[((size_t)(b * 4 + kk) * cL + l0 + p) * 128 + d] = dl;
    }
}

// ------- scan pass 1: spatial-order inputs, incremental permuted offset -------
__global__ void __launch_bounds__(256) k_scan1(const float* __restrict__ delta, const float* __restrict__ xca,
                                               const float* __restrict__ bc, const float* __restrict__ Alogs,
                                               float* __restrict__ Pend, float* __restrict__ hend) {
    int blk = blockIdx.x;            // ((bk*8+dgq)*NCH + c)
    int c = blk & 31;
    if (c == NCH - 1) return;        // last chunk's P/h never consumed
    int g = blk >> 5;
    int dgq = g & 7, bk = g >> 3;
    int k = bk & 3, b = bk >> 2;
    int t = threadIdx.x;
    int n = t & 15;
    int d = dgq * 16 + (t >> 4);
    float A = -expf(Alogs[(k * 128 + d) * 16 + n]);
    const float* dp = delta + (size_t)bk * cL * 128 + d;
    const float* xp = xca + (size_t)b * cL * 128 + d;
    const float* bp = bc + (size_t)bk * cL * 32 + n;
    int off = xs_index(k, c * CHL);
    int step = (k == 0) ? 1 : (k == 1) ? cW : (k == 2) ? -1 : -cW;
    float P = 1.f, h = 0.f;
#pragma unroll 4
    for (int i = 0; i < CHL; i++) {
        float dl = dp[(size_t)off * 128];
        float a = expf(dl * A);
        h = a * h + dl * xp[(size_t)off * 128] * bp[(size_t)off * 32];
        P *= a;
        off += step;
        if (off >= cL) off -= (cL - 1);
        else if (off < 0) off += (cL - 1);
    }
    Pend[(size_t)blk * 256 + t] = P;
    hend[(size_t)blk * 256 + t] = h;
}

// ------- scan pass 2: sequential combine; writes h_in in-place into hend -------
__global__ void __launch_bounds__(256) k_scan2(const float* __restrict__ Pend, float* __restrict__ hend) {
    int id = blockIdx.x * 256 + threadIdx.x;  // 16384 total
    int t = id & 255;
    int g = id >> 8;
    float h = 0.f;
    for (int c = 0; c < NCH; c++) {
        size_t idx = ((size_t)g * NCH + c) * 256 + t;
        float tmp = hend[idx];
        float Pv = Pend[idx];
        hend[idx] = h;
        h = Pv * h + tmp;
    }
}

// ------- scan pass 3: re-scan; y written in SPATIAL order (bk, p, 128) -------
__global__ void __launch_bounds__(256) k_scan3(const float* __restrict__ delta, const float* __restrict__ xca,
                                               const float* __restrict__ bc, const float* __restrict__ Alogs,
                                               const float* __restrict__ Dsv, const float* __restrict__ hinb,
                                               float* __restrict__ y) {
    int blk = blockIdx.x;
    int c = blk & 31;
    int g = blk >> 5;
    int dgq = g & 7, bk = g >> 3;
    int k = bk & 3, b = bk >> 2;
    int t = threadIdx.x;
    int n = t & 15;
    int d = dgq * 16 + (t >> 4);
    float A = -expf(Alogs[(k * 128 + d) * 16 + n]);
    float Dsd = Dsv[k * 128 + d];
    const float* dp = delta + (size_t)bk * cL * 128 + d;
    const float* xp = xca + (size_t)b * cL * 128 + d;
    const float* bp = bc + (size_t)bk * cL * 32 + n;
    const float* cp = bc + (size_t)bk * cL * 32 + 16 + n;
    float* yb = y + (size_t)bk * cL * 128 + d;
    int off = xs_index(k, c * CHL);
    int step = (k == 0) ? 1 : (k == 1) ? cW : (k == 2) ? -1 : -cW;
    float h = hinb[(size_t)blk * 256 + t];
#pragma unroll 2
    for (int i = 0; i < CHL; i++) {
        float dl = dp[(size_t)off * 128];
        float xv = xp[(size_t)off * 128];
        float a = expf(dl * A);
        h = a * h + dl * xv * bp[(size_t)off * 32];
        float contrib = row_sum16(h * cp[(size_t)off * 32]);
        if (n == 0) yb[(size_t)off * 128] = contrib + xv * Dsd;
        off += step;
        if (off >= cL) off -= (cL - 1);
        else if (off < 0) off += (cL - 1);
    }
}

// ------- fused tail: 4-dir sum + LN + gate + out_proj + MLP + residual -------
// 288 blocks (16 px), 256 thr
__global__ void __launch_bounds__(256) k_tail(const float* __restrict__ y, const float* __restrict__ z,
                                              const float* __restrict__ lng, const float* __restrict__ lnb,
                                              const float* __restrict__ opw,
                                              const float* __restrict__ f1w, const float* __restrict__ f1b,
                                              const float* __restrict__ f2w, const float* __restrict__ f2b,
                                              float* __restrict__ out) {
    int blk = blockIdx.x;
    int b = blk / 144;
    int l0 = (blk % 144) * 16;
    int t = threadIdx.x;
    __shared__ float v[16][132];
    __shared__ float x1s[16][68];
    __shared__ float h1s[16][132];
    __shared__ float mus[16], rss[16];
    const float* yb = y + (size_t)b * 4 * cL * 128;
#pragma unroll
    for (int i = 0; i < 8; i++) {
        int id = i * 256 + t;
        int d = id & 127, p = id >> 7;
        size_t base = (size_t)(l0 + p) * 128 + d;
        v[p][d] = yb[base] + yb[(size_t)cL * 128 + base] + yb[(size_t)2 * cL * 128 + base] + yb[(size_t)3 * cL * 128 + base];
    }
    __syncthreads();
    {
        int p = t >> 4, c8 = (t & 15) * 8;
        float s = 0.f;
#pragma unroll
        for (int j = 0; j < 8; j++) s += v[p][c8 + j];
        s = row_sum16(s);
        float mu = s * (1.f / 128.f);
        float s2 = 0.f;
#pragma unroll
        for (int j = 0; j < 8; j++) { float dv = v[p][c8 + j] - mu; s2 += dv * dv; }
        s2 = row_sum16(s2);
        if ((t & 15) == 0) { mus[p] = mu; rss[p] = rsqrtf(s2 * (1.f / 128.f) + cEPS); }
    }
    __syncthreads();
#pragma unroll
    for (int i = 0; i < 8; i++) {
        int id = i * 256 + t;
        int d = id & 127, p = id >> 7;
        float zz = z[((size_t)b * cL + l0 + p) * 128 + d];
        v[p][d] = ((v[p][d] - mus[p]) * rss[p] * lng[d] + lnb[d]) * silu(zz);
    }
    __syncthreads();
#pragma unroll
    for (int i = 0; i < 4; i++) {
        int id = i * 256 + t;
        int p = id & 15, o = id >> 4;
        const float* wr = opw + o * 128;
        float acc = 0.f;
#pragma unroll 16
        for (int d2 = 0; d2 < 128; d2++) acc += v[p][d2] * wr[d2];
        x1s[p][o] = acc;
    }
    __syncthreads();
#pragma unroll
    for (int i = 0; i < 8; i++) {
        int id = i * 256 + t;
        int p = id & 15, j = id >> 4;
        const float* wr = f1w + j * 64;
        float acc = f1b[j];
#pragma unroll 16
        for (int c = 0; c < 64; c++) acc += x1s[p][c] * wr[c];
        h1s[p][j] = silu(acc);
    }
    __syncthreads();
#pragma unroll
    for (int i = 0; i < 4; i++) {
        int id = i * 256 + t;
        int p = id & 15, o = id >> 4;
        const float* wr = f2w + o * 128;
        float acc = f2b[o];
#pragma unroll 16
        for (int j = 0; j < 128; j++) acc += h1s[p][j] * wr[j];
        out[((size_t)b * 64 + o) * cL + l0 + p] = acc + x1s[p][o];
    }
}

extern "C" void kernel_launch(void* const* d_in, const int* in_sizes, int n_in,
                              void* d_out, int out_size, void* d_ws, size_t ws_size,
                              hipStream_t stream) {
    (void)in_sizes; (void)n_in; (void)out_size; (void)ws_size;
    const float* x    = (const float*)d_in[0];
    const float* s0g  = (const float*)d_in[1];
    const float* s0b  = (const float*)d_in[2];
    const float* s0w  = (const float*)d_in[3];
    const float* s1g  = (const float*)d_in[4];
    const float* s1b  = (const float*)d_in[5];
    const float* s1w  = (const float*)d_in[6];
    const float* s2g  = (const float*)d_in[7];
    const float* s2b  = (const float*)d_in[8];
    const float* s2w  = (const float*)d_in[9];
    const float* s3g  = (const float*)d_in[10];
    const float* s3b  = (const float*)d_in[11];
    const float* s3w  = (const float*)d_in[12];
    const float* s4g  = (const float*)d_in[13];
    const float* s4b  = (const float*)d_in[14];
    const float* s4w  = (const float*)d_in[15];
    const float* cg   = (const float*)d_in[16];
    const float* cbb  = (const float*)d_in[17];
    const float* cw   = (const float*)d_in[18];
    const float* scg  = (const float*)d_in[19];
    const float* scb  = (const float*)d_in[20];
    const float* scw  = (const float*)d_in[21];
    const float* ipw  = (const float*)d_in[22];
    const float* dww  = (const float*)d_in[23];
    const float* dwb  = (const float*)d_in[24];
    const float* xpw  = (const float*)d_in[25];
    const float* dtw  = (const float*)d_in[26];
    const float* dtb  = (const float*)d_in[27];
    const float* Alog = (const float*)d_in[28];
    const float* Dsv  = (const float*)d_in[29];
    const float* lng  = (const float*)d_in[30];
    const float* lnb  = (const float*)d_in[31];
    const float* opw  = (const float*)d_in[32];
    const float* f1w  = (const float*)d_in[33];
    const float* f1b  = (const float*)d_in[34];
    const float* f2w  = (const float*)d_in[35];
    const float* f2b  = (const float*)d_in[36];
    float* out = (float*)d_out;

    float* ws = (float*)d_ws;
    size_t off = 0;
    // --- dead-before-scan region (delta overlays [0, 2359296); hend at [2359296, 2883584)) ---
    float* pool3  = ws + off; off += (size_t)cB * 64 * cL;        // 294912
    float* pool5  = ws + off; off += (size_t)cB * 64 * 576;       // 73728
    float* pool9  = ws + off; off += (size_t)cB * 64 * 144;       // 18432
    float* gmean  = ws + off; off += (size_t)cB * 64;             // 128
    float* c2     = ws + off; off += (size_t)cB * 128 * 576;      // 147456
    float* c3     = ws + off; off += (size_t)cB * 128 * 144;      // 36864
    float* c4     = ws + off; off += (size_t)cB * 128;            // 256
    u16*   catbf  = (u16*)(ws + off); off += (size_t)cB * cL * 640 / 2;  // 737280 fl
    u16*   xbf    = (u16*)(ws + off); off += (size_t)cB * cL * 64 / 2;   // 73728 fl
    u16*   w8     = (u16*)(ws + off); off += (size_t)64 * KTOT / 2;      // 186368 fl
    float* xc     = ws + off; off += (size_t)cB * cL * 128;       // 589824 (ends 2158976)
    u16*   u2     = (u16*)(ws + off); off += (size_t)cB * cL * 128 / 2;  // 147456... (u16 count/2 fl)
    u16*   u3     = (u16*)(ws + off); off += (size_t)cB * cL * 128 / 2;
    u16*   wcat   = (u16*)(ws + off); off += (size_t)2 * 128 * 64 / 2;
    u16*   ipk    = (u16*)(ws + off); off += (size_t)256 * 64 / 2;
    u16*   xpk    = (u16*)(ws + off); off += (size_t)144 * 128 / 2 + 64;
    off = 4718592;  // pad dead region: delta(2359296) + hend(524288) fit beneath
    // --- live buffers ---
    float* xca    = ws + off; off += (size_t)cB * cL * 128;       // live through scan3 (scan reads xs from it)
    float* zbuf   = ws + off; off += (size_t)cB * cL * 128;
    float* bcbuf  = ws + off; off += (size_t)cB * 4 * cL * 32;    // spatial (bk,p,32)
    float* Pend   = ws + off; off += (size_t)2048 * 256;
    off += 262144;                                                // spare
    float* ybuf   = ws + off; off += (size_t)cB * 4 * cL * 128;   // spatial (bk,p,128)
    float* x1pad  = ws + off; off += (size_t)cB * 64 * cL;        // keeps part overlay sized
    (void)x1pad;
    // overlays on dead region
    float* delta  = ws + 0;                          // (bk, p_spatial, 128)
    float* hend   = ws + (size_t)cB * 4 * cL * 128;  // [2359296, 2883584): u2/u3/wcat/ipk/xpk dead by scan1
    float* part   = ybuf;                            // 9*294912 <= ybuf+x1pad, dead at k_comp/k_ip time

    k_pool3<<<(cB * 64 * cL + 255) / 256, 256, 0, stream>>>(x, pool3);
    k_pool<5, 2, 2, 24><<<(cB * 64 * 576 + 255) / 256, 256, 0, stream>>>(x, pool5);
    k_pool<9, 4, 4, 12><<<(cB * 64 * 144 + 255) / 256, 256, 0, stream>>>(x, pool9);
    k_gmean<<<cB * 64, 256, 0, stream>>>(x, gmean);
    k_c1<<<cB * 576, 128, 0, stream>>>(pool5, s2g, s2b, s2w, c2, 576);
    k_c1<<<cB * 144, 128, 0, stream>>>(pool9, s3g, s3b, s3w, c3, 144);
    k_c1<<<cB, 128, 0, stream>>>(gmean, s4g, s4b, s4w, c4, 1);
    k_wprep<<<(64 * KTOT + 255) / 256, 256, 0, stream>>>(cw, scw, w8);
    k_wcat<<<(2 * 128 * 64 + 255) / 256, 256, 0, stream>>>(s0w, s1w, wcat);
    k_ipw<<<(256 * 64 + 255) / 256, 256, 0, stream>>>(ipw, ipk);
    k_xpw<<<(144 * 128 + 255) / 256, 256, 0, stream>>>(xpw, xpk);
    k_up<<<(2 * cB * cL * 128 + 255) / 256, 256, 0, stream>>>(c2, c3, u2, u3);
    k_cat2<<<cB * 144, 256, 0, stream>>>(x, pool3, c4, s0g, s0b, s1g, s1b, scg, scb, cg, cbb, wcat, u2, u3, catbf, xbf);
    k_comp<<<(cB * cL / 16) * 9, 64, 0, stream>>>(catbf, xbf, w8, part);
    k_ip<<<cB * cL / 16, 256, 0, stream>>>(part, ipk, xc, zbuf);
    k_dw<<<(cB * cL * 128 + 255) / 256, 256, 0, stream>>>(xc, dww, dwb, xca);
    k_xdbl4<<<cB * 144, 256, 0, stream>>>(xca, xpk, dtw, dtb, bcbuf, delta);
    k_scan1<<<64 * NCH, 256, 0, stream>>>(delta, xca, bcbuf, Alog, Pend, hend);
    k_scan2<<<64, 256, 0, stream>>>(Pend, hend);
    k_scan3<<<64 * NCH, 256, 0, stream>>>(delta, xca, bcbuf, Alog, Dsv, hend, ybuf);
    k_tail<<<cB * 144, 256, 0, stream>>>(ybuf, zbuf, lng, lnb, opw, f1w, f1b, f2w, f2b, out);
}

// Round 9
// 321.853 us; speedup vs baseline: 8.5154x; 1.0519x over previous
//
#include <hip/hip_runtime.h>
#include <math.h>

constexpr int cB = 2, cC = 64, cH = 48, cW = 48, cL = 48 * 48;
constexpr int cBR = 128, cDI = 128, cNS = 16, cRK = 4, cK = 4;
constexpr float cEPS = 1e-5f;
constexpr int NCH = 32;          // scan chunks
constexpr int CHL = cL / NCH;    // 72 positions per chunk
constexpr int KTOT = 5824;       // 9*640 conv + 64 shortcut

typedef unsigned short u16;
typedef unsigned int u32;
typedef short s16x8 __attribute__((ext_vector_type(8)));
typedef float f32x4 __attribute__((ext_vector_type(4)));

__device__ __forceinline__ float bnrelu(float v, float g, float b) {
    float y = v * (g * rsqrtf(1.0f + cEPS)) + b;
    return y > 0.f ? y : 0.f;
}
__device__ __forceinline__ float silu(float v) {
    return v / (1.f + expf(-v));
}
__device__ __forceinline__ u16 f2bf(float f) {
    u32 u = __float_as_uint(f);
    u = (u + 0x7fffu + ((u >> 16) & 1u)) >> 16;
    return (u16)u;
}
__device__ __forceinline__ s16x8 cvt8(const float* p) {
    s16x8 r;
#pragma unroll
    for (int i = 0; i < 8; i++) r[i] = (short)f2bf(p[i]);
    return r;
}
// sum over each aligned 16-lane row via DPP (full-rate VALU, no DS pipe)
__device__ __forceinline__ float row_sum16(float v) {
    v += __int_as_float(__builtin_amdgcn_update_dpp(0, __float_as_int(v), 0xB1, 0xF, 0xF, true));  // quad xor1
    v += __int_as_float(__builtin_amdgcn_update_dpp(0, __float_as_int(v), 0x4E, 0xF, 0xF, true));  // quad xor2
    v += __int_as_float(__builtin_amdgcn_update_dpp(0, __float_as_int(v), 0x124, 0xF, 0xF, true)); // row_ror:4
    v += __int_as_float(__builtin_amdgcn_update_dpp(0, __float_as_int(v), 0x128, 0xF, 0xF, true)); // row_ror:8
    return v;
}

// ------- fused pools: pool3 (1152 blk) | pool5 (288) | pool9 (72) | gmean (128) -------
__global__ void __launch_bounds__(256) k_pools(const float* __restrict__ x, float* __restrict__ pool3,
                                               float* __restrict__ pool5, float* __restrict__ pool9,
                                               float* __restrict__ gmean) {
    __shared__ float sm[4];
    int blk = blockIdx.x;
    int t = threadIdx.x;
    if (blk < 1152) {
        int idx = blk * 256 + t;
        int w = idx % cW, h = (idx / cW) % cH, bc = idx / cL;
        const float* p = x + bc * cL;
        float s = 0.f;
        for (int dh = -1; dh <= 1; dh++) {
            int hh = h + dh; if (hh < 0 || hh >= cH) continue;
            for (int dw = -1; dw <= 1; dw++) {
                int ww = w + dw; if (ww < 0 || ww >= cW) continue;
                s += p[hh * cW + ww];
            }
        }
        pool3[idx] = s * (1.f / 9.f);
    } else if (blk < 1440) {
        int idx = (blk - 1152) * 256 + t;   // 5x5 s2 p2 -> 24x24
        int w = idx % 24, h = (idx / 24) % 24, bc = idx / 576;
        const float* p = x + bc * cL;
        float s = 0.f;
        for (int kh = 0; kh < 5; kh++) {
            int hh = h * 2 - 2 + kh; if (hh < 0 || hh >= cH) continue;
            for (int kw = 0; kw < 5; kw++) {
                int ww = w * 2 - 2 + kw; if (ww < 0 || ww >= cW) continue;
                s += p[hh * cW + ww];
            }
        }
        pool5[idx] = s * (1.f / 25.f);
    } else if (blk < 1512) {
        int idx = (blk - 1440) * 256 + t;   // 9x9 s4 p4 -> 12x12
        int w = idx % 12, h = (idx / 12) % 12, bc = idx / 144;
        const float* p = x + bc * cL;
        float s = 0.f;
        for (int kh = 0; kh < 9; kh++) {
            int hh = h * 4 - 4 + kh; if (hh < 0 || hh >= cH) continue;
            for (int kw = 0; kw < 9; kw++) {
                int ww = w * 4 - 4 + kw; if (ww < 0 || ww >= cW) continue;
                s += p[hh * cW + ww];
            }
        }
        pool9[idx] = s * (1.f / 81.f);
    } else {
        int bc = blk - 1512;
        const float* p = x + bc * cL;
        float s = 0.f;
        for (int i = t; i < cL; i += 256) s += p[i];
        for (int m = 32; m > 0; m >>= 1) s += __shfl_down(s, m);
        if ((t & 63) == 0) sm[t >> 6] = s;
        __syncthreads();
        if (t == 0) gmean[bc] = (sm[0] + sm[1] + sm[2] + sm[3]) * (1.f / cL);
    }
}

// ------- fused weight prep: w8 (1456 blk) | wcat (64) | ipk (64) | xpk (72) -------
__global__ void __launch_bounds__(256) k_prep(const float* __restrict__ cw, const float* __restrict__ scw,
                                              const float* __restrict__ s0w, const float* __restrict__ s1w,
                                              const float* __restrict__ ipw, const float* __restrict__ xpw,
                                              u16* __restrict__ w8, u16* __restrict__ wcat,
                                              u16* __restrict__ ipk, u16* __restrict__ xpk) {
    int blk = blockIdx.x, t = threadIdx.x;
    if (blk < 1456) {
        int idx = blk * 256 + t;  // < 64*KTOT exactly
        int o = idx / KTOT, kx = idx % KTOT;
        float v;
        if (kx < 5760) { int tap = kx / 640, ch = kx % 640; v = cw[(o * 640 + ch) * 9 + tap]; }
        else v = scw[o * 64 + (kx - 5760)];
        w8[(((size_t)(kx >> 3) * 64) + o) * 8 + (kx & 7)] = f2bf(v);
    } else if (blk < 1520) {
        int idx = (blk - 1456) * 256 + t;
        int g = idx >> 13, r = idx & 8191;
        int o = r >> 6, c = r & 63;
        float v = (g ? s1w : s0w)[r];
        int kt = c >> 5, q = (c >> 3) & 3, j = c & 7, nt = o >> 4, ln = o & 15;
        wcat[(size_t)((((g * 2 + kt) * 4 + q) * 8 + nt) * 16 + ln) * 8 + j] = f2bf(v);
    } else if (blk < 1584) {
        int idx = (blk - 1520) * 256 + t;
        int o = idx >> 6, c = idx & 63;
        int kt = c >> 5, q = (c >> 3) & 3, j = c & 7, nt = o >> 4, ln = o & 15;
        ipk[(size_t)(((kt * 4 + q) * 16 + nt) * 16 + ln) * 8 + j] = f2bf(ipw[idx]);
    } else {
        int idx = (blk - 1584) * 256 + t;
        int o = idx >> 7, d = idx & 127;
        int kt = d >> 5, q = (d >> 3) & 3, j = d & 7, nt = o >> 4, ln = o & 15;
        xpk[(size_t)(((kt * 4 + q) * 9 + nt) * 16 + ln) * 8 + j] = f2bf(xpw[idx]);
    }
}

// ------- fused bn_relu + 1x1 conv (64->128), channel-LAST outputs -------
__global__ void __launch_bounds__(128) k_c1all(const float* __restrict__ pool5, const float* __restrict__ pool9,
                                               const float* __restrict__ gm,
                                               const float* __restrict__ s2g, const float* __restrict__ s2b,
                                               const float* __restrict__ s2w,
                                               const float* __restrict__ s3g, const float* __restrict__ s3b,
                                               const float* __restrict__ s3w,
                                               const float* __restrict__ s4g, const float* __restrict__ s4b,
                                               const float* __restrict__ s4w,
                                               float* __restrict__ c2cl, float* __restrict__ c3cl,
                                               float* __restrict__ c4) {
    int pos = blockIdx.x;
    const float *in, *g, *bb, *w;
    float* outp;
    int HW, b, pp;
    if (pos < cB * 576) { b = pos / 576; pp = pos % 576; in = pool5; g = s2g; bb = s2b; w = s2w; HW = 576; outp = c2cl + ((size_t)b * 576 + pp) * 128; }
    else if (pos < cB * 576 + cB * 144) { int r = pos - cB * 576; b = r / 144; pp = r % 144; in = pool9; g = s3g; bb = s3b; w = s3w; HW = 144; outp = c3cl + ((size_t)b * 144 + pp) * 128; }
    else { b = pos - cB * 576 - cB * 144; pp = 0; in = gm; g = s4g; bb = s4b; w = s4w; HW = 1; outp = c4 + (size_t)b * 128; }
    __shared__ float v[64];
    int t = threadIdx.x;
    if (t < 64) v[t] = bnrelu(in[(b * 64 + t) * HW + pp], g[t], bb[t]);
    __syncthreads();
    float acc = 0.f;
    const float* wr = w + t * 64;
#pragma unroll 16
    for (int c = 0; c < 64; c++) acc += v[c] * wr[c];
    outp[t] = acc;
}

// ------- cat build: staged loads + MFMA 1x1 convs + INLINE bilinear + fused epilogue -------
__global__ void __launch_bounds__(256) k_cat2(
    const float* __restrict__ x, const float* __restrict__ pool3, const float* __restrict__ c4,
    const float* __restrict__ s0g, const float* __restrict__ s0b,
    const float* __restrict__ s1g, const float* __restrict__ s1b,
    const float* __restrict__ scg, const float* __restrict__ scb,
    const float* __restrict__ cg, const float* __restrict__ cbb,
    const u16* __restrict__ wcat, const float* __restrict__ c2cl, const float* __restrict__ c3cl,
    u16* __restrict__ catbf, u16* __restrict__ xbf) {
    int blk = blockIdx.x;
    int b = blk / 144;
    int l0 = (blk % 144) * 16;
    int t = threadIdx.x;
    __shared__ float axv[16][68];
    __shared__ float ap3[16][68];
    __shared__ u16 axc[16][66];
    int pc = t >> 4, p = t & 15;
#pragma unroll
    for (int i = 0; i < 4; i++) {
        int c = i * 16 + pc;
        float xraw = x[(size_t)(b * 64 + c) * cL + l0 + p];
        float p3raw = pool3[(size_t)(b * 64 + c) * cL + l0 + p];
        axv[p][c] = bnrelu(xraw, s0g[c], s0b[c]);
        ap3[p][c] = bnrelu(p3raw, s1g[c], s1b[c]);
        axc[p][c] = f2bf(bnrelu(xraw, scg[c], scb[c]));
    }
    __syncthreads();
#pragma unroll
    for (int i = 0; i < 4; i++) {
        int idx = i * 256 + t;
        int pp = idx >> 6, cc = idx & 63;
        xbf[((size_t)b * cL + l0 + pp) * 64 + cc] = axc[pp][cc];
    }
    int wv = t >> 6, lane = t & 63, ln = lane & 15, q = lane >> 4;
    f32x4 ax[2] = {};
    f32x4 ay[2] = {};
#pragma unroll
    for (int kt = 0; kt < 2; kt++) {
        s16x8 a0 = cvt8(&axv[ln][kt * 32 + q * 8]);
        s16x8 a1 = cvt8(&ap3[ln][kt * 32 + q * 8]);
#pragma unroll
        for (int jj = 0; jj < 2; jj++) {
            int nt = wv * 2 + jj;
            s16x8 b0 = *(const s16x8*)(wcat + (size_t)((((0 * 2 + kt) * 4 + q) * 8 + nt) * 16 + ln) * 8);
            s16x8 b1 = *(const s16x8*)(wcat + (size_t)((((1 * 2 + kt) * 4 + q) * 8 + nt) * 16 + ln) * 8);
            ax[jj] = __builtin_amdgcn_mfma_f32_16x16x32_bf16(a0, b0, ax[jj], 0, 0, 0);
            ay[jj] = __builtin_amdgcn_mfma_f32_16x16x32_bf16(a1, b1, ay[jj], 0, 0, 0);
        }
    }
    // bilinear setup (row uniform per block)
    int hrow = l0 / cW, w0g = l0 % cW;
    float sy2 = hrow * 0.5f - 0.25f;
    float fy2 = floorf(sy2); int iy2 = (int)fy2; float ay2 = sy2 - fy2;
    int y20 = min(max(iy2, 0), 23), y21 = min(max(iy2 + 1, 0), 23);
    float sy3 = hrow * 0.25f - 0.375f;
    float fy3 = floorf(sy3); int iy3 = (int)fy3; float ay3 = sy3 - fy3;
    int y30 = min(max(iy3, 0), 11), y31 = min(max(iy3 + 1, 0), 11);
    const float* c2b = c2cl + (size_t)b * 576 * 128;
    const float* c3b = c3cl + (size_t)b * 144 * 128;
#pragma unroll
    for (int r = 0; r < 4; r++) {
        int pp = q * 4 + r;
        int wq = w0g + pp;
        float sx2 = wq * 0.5f - 0.25f;
        float fx2 = floorf(sx2); int ix2 = (int)fx2; float ax2 = sx2 - fx2;
        int x20 = min(max(ix2, 0), 23), x21 = min(max(ix2 + 1, 0), 23);
        float sx3 = wq * 0.25f - 0.375f;
        float fx3 = floorf(sx3); int ix3 = (int)fx3; float ax3 = sx3 - fx3;
        int x30 = min(max(ix3, 0), 11), x31 = min(max(ix3 + 1, 0), 11);
#pragma unroll
        for (int jj = 0; jj < 2; jj++) {
            int ch = (wv * 2 + jj) * 16 + ln;
            float v00 = c2b[(y20 * 24 + x20) * 128 + ch], v01 = c2b[(y20 * 24 + x21) * 128 + ch];
            float v10 = c2b[(y21 * 24 + x20) * 128 + ch], v11 = c2b[(y21 * 24 + x21) * 128 + ch];
            float t0 = v00 + (v01 - v00) * ax2, t1 = v10 + (v11 - v10) * ax2;
            float u2v = t0 + (t1 - t0) * ay2;
            float w00 = c3b[(y30 * 12 + x30) * 128 + ch], w01 = c3b[(y30 * 12 + x31) * 128 + ch];
            float w10 = c3b[(y31 * 12 + x30) * 128 + ch], w11 = c3b[(y31 * 12 + x31) * 128 + ch];
            float s0_ = w00 + (w01 - w00) * ax3, s1_ = w10 + (w11 - w10) * ax3;
            float u3v = s0_ + (s1_ - s0_) * ay3;
            float x0 = ax[jj][r];
            float y1 = ay[jj][r] + x0;
            float y2 = x0 + u2v;
            float y3 = x0 + u3v;
            float y4 = x0 + c4[b * 128 + ch];
            u16* base = catbf + ((size_t)b * cL + l0 + pp) * 640;
            base[ch]       = f2bf(bnrelu(x0, cg[ch],       cbb[ch]));
            base[128 + ch] = f2bf(bnrelu(y1, cg[128 + ch], cbb[128 + ch]));
            base[256 + ch] = f2bf(bnrelu(y2, cg[256 + ch], cbb[256 + ch]));
            base[384 + ch] = f2bf(bnrelu(y3, cg[384 + ch], cbb[384 + ch]));
            base[512 + ch] = f2bf(bnrelu(y4, cg[512 + ch], cbb[512 + ch]));
        }
    }
}

// ------- comp 3x3 conv + shortcut: split-K MFMA GEMM -------
__global__ void __launch_bounds__(64) k_comp(const u16* __restrict__ catbf,
                                             const u16* __restrict__ xbf,
                                             const u16* __restrict__ w8,
                                             float* __restrict__ part) {
    int blk = blockIdx.x;
    int slice = blk % 9;
    int pxt = blk / 9;
    int pix0 = pxt * 16;
    int b = pix0 / cL;
    int lane = threadIdx.x;
    int ln = lane & 15, q = lane >> 4;
    int la = (pix0 + ln) - b * cL;
    int h = la / cW, w = la % cW;
    int kh = slice / 3 - 1, kw = slice % 3 - 1;
    int hh = h + kh, ww = w + kw;
    bool ok = (hh >= 0) && (hh < cH) && (ww >= 0) && (ww < cW);
    const u16* ap = catbf + ((size_t)b * cL + hh * cW + ww) * 640 + q * 8;
    f32x4 acc[4] = {};
    int kb = slice * 640;
#pragma unroll 4
    for (int cc = 0; cc < 20; cc++) {
        s16x8 av;
        if (ok) av = *(const s16x8*)(ap + cc * 32);
        else av = s16x8{0, 0, 0, 0, 0, 0, 0, 0};
        const u16* wrow = w8 + (((size_t)((kb + cc * 32) >> 3) + q) * 64) * 8;
#pragma unroll
        for (int j = 0; j < 4; j++) {
            s16x8 bv = *(const s16x8*)(wrow + (size_t)(j * 16 + ln) * 8);
            acc[j] = __builtin_amdgcn_mfma_f32_16x16x32_bf16(av, bv, acc[j], 0, 0, 0);
        }
    }
    if (slice == 4) {
        const u16* xp = xbf + (size_t)(pix0 + ln) * 64 + q * 8;
#pragma unroll
        for (int cc = 0; cc < 2; cc++) {
            s16x8 av = *(const s16x8*)(xp + cc * 32);
            const u16* wrow = w8 + (((size_t)((5760 + cc * 32) >> 3) + q) * 64) * 8;
#pragma unroll
            for (int j = 0; j < 4; j++) {
                s16x8 bv = *(const s16x8*)(wrow + (size_t)(j * 16 + ln) * 8);
                acc[j] = __builtin_amdgcn_mfma_f32_16x16x32_bf16(av, bv, acc[j], 0, 0, 0);
            }
        }
    }
    float* pb = part + ((size_t)slice * (cB * cL) + pix0) * 64;
#pragma unroll
    for (int j = 0; j < 4; j++) {
#pragma unroll
        for (int r = 0; r < 4; r++) {
            pb[(size_t)(q * 4 + r) * 64 + j * 16 + ln] = acc[j][r];
        }
    }
}

// ------- fused split-K reduce + in_proj MFMA: part -> xc (B,L,128), z (B,L,128) -------
__global__ void __launch_bounds__(256) k_ip(const float* __restrict__ part, const u16* __restrict__ ipk,
                                            float* __restrict__ xc, float* __restrict__ z) {
    int px0 = blockIdx.x * 16;
    int t = threadIdx.x;
    __shared__ float pv[16][68];
#pragma unroll
    for (int i = 0; i < 4; i++) {
        int idx = i * 256 + t;
        int p = idx >> 6, c = idx & 63;
        float s = 0.f;
#pragma unroll
        for (int sl = 0; sl < 9; sl++)
            s += part[((size_t)sl * (cB * cL) + px0 + p) * 64 + c];
        pv[p][c] = s;
    }
    __syncthreads();
    int wv = t >> 6, lane = t & 63, ln = lane & 15, q = lane >> 4;
    f32x4 acc[4] = {};
#pragma unroll
    for (int kt = 0; kt < 2; kt++) {
        s16x8 a = cvt8(&pv[ln][kt * 32 + q * 8]);
#pragma unroll
        for (int jn = 0; jn < 4; jn++) {
            int nt = wv * 4 + jn;
            s16x8 bfr = *(const s16x8*)(ipk + (size_t)(((kt * 4 + q) * 16 + nt) * 16 + ln) * 8);
            acc[jn] = __builtin_amdgcn_mfma_f32_16x16x32_bf16(a, bfr, acc[jn], 0, 0, 0);
        }
    }
#pragma unroll
    for (int jn = 0; jn < 4; jn++) {
        int o = (wv * 4 + jn) * 16 + ln;
#pragma unroll
        for (int r = 0; r < 4; r++) {
            int p = q * 4 + r;
            if (o < 128) xc[((size_t)px0 + p) * 128 + o] = acc[jn][r];
            else         z[((size_t)px0 + p) * 128 + (o - 128)] = acc[jn][r];
        }
    }
}

// ------- fused depthwise 3x3 + silu + x_dbl MFMA + softplus(delta); spatial order -------
__global__ void __launch_bounds__(256) k_dwx(const float* __restrict__ xc, const float* __restrict__ dww,
                                             const float* __restrict__ dwb, const u16* __restrict__ xpk,
                                             const float* __restrict__ dtw, const float* __restrict__ dtb,
                                             float* __restrict__ xca, float* __restrict__ bc,
                                             float* __restrict__ delta) {
    int blk = blockIdx.x;
    int b = blk / 144;
    int l0 = (blk % 144) * 16;
    int h = l0 / cW, w0 = l0 % cW;
    int t = threadIdx.x;
    __shared__ float hal[3][18][128];
    __shared__ float av[16][132];
    __shared__ float Dt[16][148];
    // coalesced halo load (3 rows x 18 cols x 128 ch)
#pragma unroll
    for (int i = 0; i < 27; i++) {
        int id = i * 256 + t;
        int d = id & 127;
        int rc = id >> 7;         // 0..53
        int c18 = rc % 18, r3 = rc / 18;
        int hh = h + r3 - 1, wc = w0 + c18 - 1;
        float v = 0.f;
        if (hh >= 0 && hh < cH && wc >= 0 && wc < cW)
            v = xc[((size_t)b * cL + hh * cW + wc) * 128 + d];
        hal[r3][c18][d] = v;
    }
    __syncthreads();
    // depthwise + bias + silu; d constant per thread
    {
        int d = t & 127;
        const float* kw = dww + d * 9;
        float k0 = kw[0], k1 = kw[1], k2 = kw[2], k3 = kw[3], k4 = kw[4];
        float k5 = kw[5], k6 = kw[6], k7 = kw[7], k8 = kw[8];
        float bia = dwb[d];
#pragma unroll
        for (int i = 0; i < 8; i++) {
            int p = i * 2 + (t >> 7);
            float acc = bia
                + hal[0][p][d] * k0 + hal[0][p + 1][d] * k1 + hal[0][p + 2][d] * k2
                + hal[1][p][d] * k3 + hal[1][p + 1][d] * k4 + hal[1][p + 2][d] * k5
                + hal[2][p][d] * k6 + hal[2][p + 1][d] * k7 + hal[2][p + 2][d] * k8;
            float sv = silu(acc);
            av[p][d] = sv;
            xca[((size_t)b * cL + l0 + p) * 128 + d] = sv;
        }
    }
    __syncthreads();
    // x_dbl MFMA: N=144 split over 4 waves as ntiles {wv, wv+4, [8 for wv0]}
    int wv = t >> 6, lane = t & 63, ln = lane & 15, q = lane >> 4;
    int nmax = (wv == 0) ? 3 : 2;
    f32x4 acc[3] = {};
#pragma unroll
    for (int kt = 0; kt < 4; kt++) {
        s16x8 a = cvt8(&av[ln][kt * 32 + q * 8]);
        for (int i = 0; i < nmax; i++) {
            int nt = (i == 2) ? 8 : wv + i * 4;
            s16x8 bfr = *(const s16x8*)(xpk + (size_t)(((kt * 4 + q) * 9 + nt) * 16 + ln) * 8);
            acc[i] = __builtin_amdgcn_mfma_f32_16x16x32_bf16(a, bfr, acc[i], 0, 0, 0);
        }
    }
    for (int i = 0; i < nmax; i++) {
        int nt = (i == 2) ? 8 : wv + i * 4;
#pragma unroll
        for (int r = 0; r < 4; r++)
            Dt[q * 4 + r][nt * 16 + ln] = acc[i][r];
    }
    __syncthreads();
    // bc out: (bk, p_spatial, 32), coalesced
#pragma unroll
    for (int i = 0; i < 8; i++) {
        int id = i * 256 + t;
        int cc = id & 31, kk = (id >> 5) & 3, p = id >> 7;
        bc[((size_t)(b * 4 + kk) * cL + l0 + p) * 32 + cc] = Dt[p][kk * 36 + 4 + cc];
    }
    // delta = softplus(dtb + dts . dtw): (bk, p_spatial, 128), coalesced
    for (int i = 0; i < 32; i++) {
        int id = i * 256 + t;
        int d = id & 127, kk = (id >> 7) & 3, p = id >> 9;
        const float* wd = dtw + (size_t)(kk * 128 + d) * 4;
        float pre = dtb[kk * 128 + d] + wd[0] * Dt[p][kk * 36] + wd[1] * Dt[p][kk * 36 + 1]
                  + wd[2] * Dt[p][kk * 36 + 2] + wd[3] * Dt[p][kk * 36 + 3];
        float dl = pre > 20.f ? pre : log1pf(expf(pre));
        delta[((size_t)(b * 4 + kk) * cL + l0 + p) * 128 + d] = dl;
    }
}

// xs index mapping: offset into the (H*W) plane for direction k at scan pos l
__device__ __forceinline__ int xs_index(int k, int l) {
    int lp = (k & 2) ? (cL - 1 - l) : l;
    if (k & 1) { int w = lp / cH, h = lp % cH; return h * cW + w; }
    return lp;
}

// ------- scan pass 1: spatial-order inputs, incremental permuted offset -------
__global__ void __launch_bounds__(256) k_scan1(const float* __restrict__ delta, const float* __restrict__ xca,
                                               const float* __restrict__ bc, const float* __restrict__ Alogs,
                                               float* __restrict__ Pend, float* __restrict__ hend) {
    int blk = blockIdx.x;            // ((bk*8+dgq)*NCH + c)
    int c = blk & 31;
    if (c == NCH - 1) return;        // last chunk's P/h never consumed
    int g = blk >> 5;
    int dgq = g & 7, bk = g >> 3;
    int k = bk & 3, b = bk >> 2;
    int t = threadIdx.x;
    int n = t & 15;
    int d = dgq * 16 + (t >> 4);
    float A = -expf(Alogs[(k * 128 + d) * 16 + n]);
    const float* dp = delta + (size_t)bk * cL * 128 + d;
    const float* xp = xca + (size_t)b * cL * 128 + d;
    const float* bp = bc + (size_t)bk * cL * 32 + n;
    int off = xs_index(k, c * CHL);
    int step = (k == 0) ? 1 : (k == 1) ? cW : (k == 2) ? -1 : -cW;
    float P = 1.f, h = 0.f;
#pragma unroll 4
    for (int i = 0; i < CHL; i++) {
        float dl = dp[(size_t)off * 128];
        float a = expf(dl * A);
        h = a * h + dl * xp[(size_t)off * 128] * bp[(size_t)off * 32];
        P *= a;
        off += step;
        if (off >= cL) off -= (cL - 1);
        else if (off < 0) off += (cL - 1);
    }
    Pend[(size_t)blk * 256 + t] = P;
    hend[(size_t)blk * 256 + t] = h;
}

// ------- scan pass 2: sequential combine; writes h_in in-place into hend -------
__global__ void __launch_bounds__(256) k_scan2(const float* __restrict__ Pend, float* __restrict__ hend) {
    int id = blockIdx.x * 256 + threadIdx.x;  // 16384 total
    int t = id & 255;
    int g = id >> 8;
    float h = 0.f;
    for (int c = 0; c < NCH; c++) {
        size_t idx = ((size_t)g * NCH + c) * 256 + t;
        float tmp = hend[idx];
        float Pv = Pend[idx];
        hend[idx] = h;
        h = Pv * h + tmp;
    }
}

// ------- scan pass 3: re-scan; y written in SPATIAL order (bk, p, 128) -------
__global__ void __launch_bounds__(256) k_scan3(const float* __restrict__ delta, const float* __restrict__ xca,
                                               const float* __restrict__ bc, const float* __restrict__ Alogs,
                                               const float* __restrict__ Dsv, const float* __restrict__ hinb,
                                               float* __restrict__ y) {
    int blk = blockIdx.x;
    int c = blk & 31;
    int g = blk >> 5;
    int dgq = g & 7, bk = g >> 3;
    int k = bk & 3, b = bk >> 2;
    int t = threadIdx.x;
    int n = t & 15;
    int d = dgq * 16 + (t >> 4);
    float A = -expf(Alogs[(k * 128 + d) * 16 + n]);
    float Dsd = Dsv[k * 128 + d];
    const float* dp = delta + (size_t)bk * cL * 128 + d;
    const float* xp = xca + (size_t)b * cL * 128 + d;
    const float* bp = bc + (size_t)bk * cL * 32 + n;
    const float* cp = bc + (size_t)bk * cL * 32 + 16 + n;
    float* yb = y + (size_t)bk * cL * 128 + d;
    int off = xs_index(k, c * CHL);
    int step = (k == 0) ? 1 : (k == 1) ? cW : (k == 2) ? -1 : -cW;
    float h = hinb[(size_t)blk * 256 + t];
#pragma unroll 2
    for (int i = 0; i < CHL; i++) {
        float dl = dp[(size_t)off * 128];
        float xv = xp[(size_t)off * 128];
        float a = expf(dl * A);
        h = a * h + dl * xv * bp[(size_t)off * 32];
        float contrib = row_sum16(h * cp[(size_t)off * 32]);
        if (n == 0) yb[(size_t)off * 128] = contrib + xv * Dsd;
        off += step;
        if (off >= cL) off -= (cL - 1);
        else if (off < 0) off += (cL - 1);
    }
}

// ------- fused tail: 4-dir sum + LN + gate + out_proj + MLP + residual -------
__global__ void __launch_bounds__(256) k_tail(const float* __restrict__ y, const float* __restrict__ z,
                                              const float* __restrict__ lng, const float* __restrict__ lnb,
                                              const float* __restrict__ opw,
                                              const float* __restrict__ f1w, const float* __restrict__ f1b,
                                              const float* __restrict__ f2w, const float* __restrict__ f2b,
                                              float* __restrict__ out) {
    int blk = blockIdx.x;
    int b = blk / 144;
    int l0 = (blk % 144) * 16;
    int t = threadIdx.x;
    __shared__ float v[16][132];
    __shared__ float x1s[16][68];
    __shared__ float h1s[16][132];
    __shared__ float mus[16], rss[16];
    const float* yb = y + (size_t)b * 4 * cL * 128;
#pragma unroll
    for (int i = 0; i < 8; i++) {
        int id = i * 256 + t;
        int d = id & 127, p = id >> 7;
        size_t base = (size_t)(l0 + p) * 128 + d;
        v[p][d] = yb[base] + yb[(size_t)cL * 128 + base] + yb[(size_t)2 * cL * 128 + base] + yb[(size_t)3 * cL * 128 + base];
    }
    __syncthreads();
    {
        int p = t >> 4, c8 = (t & 15) * 8;
        float s = 0.f;
#pragma unroll
        for (int j = 0; j < 8; j++) s += v[p][c8 + j];
        s = row_sum16(s);
        float mu = s * (1.f / 128.f);
        float s2 = 0.f;
#pragma unroll
        for (int j = 0; j < 8; j++) { float dv = v[p][c8 + j] - mu; s2 += dv * dv; }
        s2 = row_sum16(s2);
        if ((t & 15) == 0) { mus[p] = mu; rss[p] = rsqrtf(s2 * (1.f / 128.f) + cEPS); }
    }
    __syncthreads();
#pragma unroll
    for (int i = 0; i < 8; i++) {
        int id = i * 256 + t;
        int d = id & 127, p = id >> 7;
        float zz = z[((size_t)b * cL + l0 + p) * 128 + d];
        v[p][d] = ((v[p][d] - mus[p]) * rss[p] * lng[d] + lnb[d]) * silu(zz);
    }
    __syncthreads();
#pragma unroll
    for (int i = 0; i < 4; i++) {
        int id = i * 256 + t;
        int p = id & 15, o = id >> 4;
        const float* wr = opw + o * 128;
        float acc = 0.f;
#pragma unroll 16
        for (int d2 = 0; d2 < 128; d2++) acc += v[p][d2] * wr[d2];
        x1s[p][o] = acc;
    }
    __syncthreads();
#pragma unroll
    for (int i = 0; i < 8; i++) {
        int id = i * 256 + t;
        int p = id & 15, j = id >> 4;
        const float* wr = f1w + j * 64;
        float acc = f1b[j];
#pragma unroll 16
        for (int c = 0; c < 64; c++) acc += x1s[p][c] * wr[c];
        h1s[p][j] = silu(acc);
    }
    __syncthreads();
#pragma unroll
    for (int i = 0; i < 4; i++) {
        int id = i * 256 + t;
        int p = id & 15, o = id >> 4;
        const float* wr = f2w + o * 128;
        float acc = f2b[o];
#pragma unroll 16
        for (int j = 0; j < 128; j++) acc += h1s[p][j] * wr[j];
        out[((size_t)b * 64 + o) * cL + l0 + p] = acc + x1s[p][o];
    }
}

extern "C" void kernel_launch(void* const* d_in, const int* in_sizes, int n_in,
                              void* d_out, int out_size, void* d_ws, size_t ws_size,
                              hipStream_t stream) {
    (void)in_sizes; (void)n_in; (void)out_size; (void)ws_size;
    const float* x    = (const float*)d_in[0];
    const float* s0g  = (const float*)d_in[1];
    const float* s0b  = (const float*)d_in[2];
    const float* s0w  = (const float*)d_in[3];
    const float* s1g  = (const float*)d_in[4];
    const float* s1b  = (const float*)d_in[5];
    const float* s1w  = (const float*)d_in[6];
    const float* s2g  = (const float*)d_in[7];
    const float* s2b  = (const float*)d_in[8];
    const float* s2w  = (const float*)d_in[9];
    const float* s3g  = (const float*)d_in[10];
    const float* s3b  = (const float*)d_in[11];
    const float* s3w  = (const float*)d_in[12];
    const float* s4g  = (const float*)d_in[13];
    const float* s4b  = (const float*)d_in[14];
    const float* s4w  = (const float*)d_in[15];
    const float* cg   = (const float*)d_in[16];
    const float* cbb  = (const float*)d_in[17];
    const float* cw   = (const float*)d_in[18];
    const float* scg  = (const float*)d_in[19];
    const float* scb  = (const float*)d_in[20];
    const float* scw  = (const float*)d_in[21];
    const float* ipw  = (const float*)d_in[22];
    const float* dww  = (const float*)d_in[23];
    const float* dwb  = (const float*)d_in[24];
    const float* xpw  = (const float*)d_in[25];
    const float* dtw  = (const float*)d_in[26];
    const float* dtb  = (const float*)d_in[27];
    const float* Alog = (const float*)d_in[28];
    const float* Dsv  = (const float*)d_in[29];
    const float* lng  = (const float*)d_in[30];
    const float* lnb  = (const float*)d_in[31];
    const float* opw  = (const float*)d_in[32];
    const float* f1w  = (const float*)d_in[33];
    const float* f1b  = (const float*)d_in[34];
    const float* f2w  = (const float*)d_in[35];
    const float* f2b  = (const float*)d_in[36];
    float* out = (float*)d_out;

    float* ws = (float*)d_ws;
    size_t off = 0;
    // --- region A: everything here is dead before k_dwx (dispatch 7) ---
    // float counts are EXACT: u16 buffers use elemcount/2 floats.
    float* pool3  = ws + off; off += 294912;   // cB*64*cL
    float* pool5  = ws + off; off += 73728;    // cB*64*576
    float* pool9  = ws + off; off += 18432;    // cB*64*144
    float* gmean  = ws + off; off += 128;      // cB*64
    float* c2cl   = ws + off; off += 147456;   // cB*576*128 (channel-last)
    float* c3cl   = ws + off; off += 36864;    // cB*144*128
    float* c4     = ws + off; off += 256;      // cB*128           -> 571776
    u16*   catbf  = (u16*)(ws + off); off += 1474560;  // cB*cL*640 u16 -> 2046336
    u16*   xbf    = (u16*)(ws + off); off += 147456;   // cB*cL*64 u16  -> 2193792
    u16*   w8     = (u16*)(ws + off); off += 186368;   // 64*KTOT u16   -> 2380160
    u16*   wcat   = (u16*)(ws + off); off += 8192;     // 2*128*64 u16  -> 2388352
    u16*   ipk    = (u16*)(ws + off); off += 8192;     // 256*64 u16    -> 2396544
    // delta overlay [0, 2359296) fits entirely inside region A (2396544) ✓
    // --- xc: written k_ip (6), read k_dwx (7); placed AFTER region A so it
    //     cannot clobber ipk/wcat (the round-8 bug). hend overlays it later. ---
    float* xc     = ws + off; off += 589824;   // [2396544, 2986368)
    u16*   xpk    = (u16*)(ws + off); off += 9216;     // 144*128 u16; read at (7) -> 2995584
    // --- live buffers ---
    float* xca    = ws + off; off += 589824;   // written (7), read scans
    float* zbuf   = ws + off; off += 589824;   // written (6), read k_tail
    float* bcbuf  = ws + off; off += 589824;   // written (7), read scans
    float* Pend   = ws + off; off += 524288;   // 2048*256
    float* ybuf   = ws + off; off += 2359296;  // scan3 out / part overlay
    off += 294912;                             // pad: part needs 9*294912 = 2654208 <= ybuf+pad ✓
    // overlays
    float* delta  = ws + 0;    // (bk, p_spatial, 128), 2359296 fl, written k_dwx (7)
    float* hend   = xc;        // 524288 <= 589824; xc dead after k_dwx (7), hend written scan1 (8)
    float* part   = ybuf;      // written k_comp (5), read k_ip (6); ybuf live from scan3 (10)

    k_pools<<<1640, 256, 0, stream>>>(x, pool3, pool5, pool9, gmean);
    k_prep<<<1656, 256, 0, stream>>>(cw, scw, s0w, s1w, ipw, xpw, w8, wcat, ipk, xpk);
    k_c1all<<<cB * 576 + cB * 144 + cB, 128, 0, stream>>>(pool5, pool9, gmean, s2g, s2b, s2w,
                                                          s3g, s3b, s3w, s4g, s4b, s4w, c2cl, c3cl, c4);
    k_cat2<<<cB * 144, 256, 0, stream>>>(x, pool3, c4, s0g, s0b, s1g, s1b, scg, scb, cg, cbb,
                                         wcat, c2cl, c3cl, catbf, xbf);
    k_comp<<<(cB * cL / 16) * 9, 64, 0, stream>>>(catbf, xbf, w8, part);
    k_ip<<<cB * cL / 16, 256, 0, stream>>>(part, ipk, xc, zbuf);
    k_dwx<<<cB * 144, 256, 0, stream>>>(xc, dww, dwb, xpk, dtw, dtb, xca, bcbuf, delta);
    k_scan1<<<64 * NCH, 256, 0, stream>>>(delta, xca, bcbuf, Alog, Pend, hend);
    k_scan2<<<64, 256, 0, stream>>>(Pend, hend);
    k_scan3<<<64 * NCH, 256, 0, stream>>>(delta, xca, bcbuf, Alog, Dsv, hend, ybuf);
    k_tail<<<cB * 144, 256, 0, stream>>>(ybuf, zbuf, lng, lnb, opw, f1w, f1b, f2w, f2b, out);
}

// Round 10
// 304.339 us; speedup vs baseline: 9.0054x; 1.0575x over previous
//
#include <hip/hip_runtime.h>
#include <math.h>

constexpr int cB = 2, cC = 64, cH = 48, cW = 48, cL = 48 * 48;
constexpr int cBR = 128, cDI = 128, cNS = 16, cRK = 4, cK = 4;
constexpr float cEPS = 1e-5f;
constexpr int NCH = 32;          // scan chunks
constexpr int CHL = cL / NCH;    // 72 positions per chunk
constexpr int KTOT = 5824;       // 9*640 conv + 64 shortcut

typedef unsigned short u16;
typedef unsigned int u32;
typedef short s16x8 __attribute__((ext_vector_type(8)));
typedef float f32x4 __attribute__((ext_vector_type(4)));

__device__ __forceinline__ float bnrelu(float v, float g, float b) {
    float y = v * (g * rsqrtf(1.0f + cEPS)) + b;
    return y > 0.f ? y : 0.f;
}
__device__ __forceinline__ float silu(float v) {
    return v / (1.f + expf(-v));
}
__device__ __forceinline__ u16 f2bf(float f) {
    u32 u = __float_as_uint(f);
    u = (u + 0x7fffu + ((u >> 16) & 1u)) >> 16;
    return (u16)u;
}
__device__ __forceinline__ s16x8 cvt8(const float* p) {
    s16x8 r;
#pragma unroll
    for (int i = 0; i < 8; i++) r[i] = (short)f2bf(p[i]);
    return r;
}
// sum over each aligned 16-lane row via DPP (full-rate VALU, no DS pipe)
__device__ __forceinline__ float row_sum16(float v) {
    v += __int_as_float(__builtin_amdgcn_update_dpp(0, __float_as_int(v), 0xB1, 0xF, 0xF, true));  // quad xor1
    v += __int_as_float(__builtin_amdgcn_update_dpp(0, __float_as_int(v), 0x4E, 0xF, 0xF, true));  // quad xor2
    v += __int_as_float(__builtin_amdgcn_update_dpp(0, __float_as_int(v), 0x124, 0xF, 0xF, true)); // row_ror:4
    v += __int_as_float(__builtin_amdgcn_update_dpp(0, __float_as_int(v), 0x128, 0xF, 0xF, true)); // row_ror:8
    return v;
}

// ------- fused pools: pool3 (1152 blk) | pool5 (288) | pool9 (72) | gmean (128) -------
__global__ void __launch_bounds__(256) k_pools(const float* __restrict__ x, float* __restrict__ pool3,
                                               float* __restrict__ pool5, float* __restrict__ pool9,
                                               float* __restrict__ gmean) {
    __shared__ float sm[4];
    int blk = blockIdx.x;
    int t = threadIdx.x;
    if (blk < 1152) {
        int idx = blk * 256 + t;
        int w = idx % cW, h = (idx / cW) % cH, bc = idx / cL;
        const float* p = x + bc * cL;
        float s = 0.f;
        for (int dh = -1; dh <= 1; dh++) {
            int hh = h + dh; if (hh < 0 || hh >= cH) continue;
            for (int dw = -1; dw <= 1; dw++) {
                int ww = w + dw; if (ww < 0 || ww >= cW) continue;
                s += p[hh * cW + ww];
            }
        }
        pool3[idx] = s * (1.f / 9.f);
    } else if (blk < 1440) {
        int idx = (blk - 1152) * 256 + t;   // 5x5 s2 p2 -> 24x24
        int w = idx % 24, h = (idx / 24) % 24, bc = idx / 576;
        const float* p = x + bc * cL;
        float s = 0.f;
        for (int kh = 0; kh < 5; kh++) {
            int hh = h * 2 - 2 + kh; if (hh < 0 || hh >= cH) continue;
            for (int kw = 0; kw < 5; kw++) {
                int ww = w * 2 - 2 + kw; if (ww < 0 || ww >= cW) continue;
                s += p[hh * cW + ww];
            }
        }
        pool5[idx] = s * (1.f / 25.f);
    } else if (blk < 1512) {
        int idx = (blk - 1440) * 256 + t;   // 9x9 s4 p4 -> 12x12
        int w = idx % 12, h = (idx / 12) % 12, bc = idx / 144;
        const float* p = x + bc * cL;
        float s = 0.f;
        for (int kh = 0; kh < 9; kh++) {
            int hh = h * 4 - 4 + kh; if (hh < 0 || hh >= cH) continue;
            for (int kw = 0; kw < 9; kw++) {
                int ww = w * 4 - 4 + kw; if (ww < 0 || ww >= cW) continue;
                s += p[hh * cW + ww];
            }
        }
        pool9[idx] = s * (1.f / 81.f);
    } else {
        int bc = blk - 1512;
        const float* p = x + bc * cL;
        float s = 0.f;
        for (int i = t; i < cL; i += 256) s += p[i];
        for (int m = 32; m > 0; m >>= 1) s += __shfl_down(s, m);
        if ((t & 63) == 0) sm[t >> 6] = s;
        __syncthreads();
        if (t == 0) gmean[bc] = (sm[0] + sm[1] + sm[2] + sm[3]) * (1.f / cL);
    }
}

// ------- fused weight prep: w8 (1456 blk) | wcat (64) | ipk (64) | xpk (72) -------
__global__ void __launch_bounds__(256) k_prep(const float* __restrict__ cw, const float* __restrict__ scw,
                                              const float* __restrict__ s0w, const float* __restrict__ s1w,
                                              const float* __restrict__ ipw, const float* __restrict__ xpw,
                                              u16* __restrict__ w8, u16* __restrict__ wcat,
                                              u16* __restrict__ ipk, u16* __restrict__ xpk) {
    int blk = blockIdx.x, t = threadIdx.x;
    if (blk < 1456) {
        int idx = blk * 256 + t;  // < 64*KTOT exactly
        int o = idx / KTOT, kx = idx % KTOT;
        float v;
        if (kx < 5760) { int tap = kx / 640, ch = kx % 640; v = cw[(o * 640 + ch) * 9 + tap]; }
        else v = scw[o * 64 + (kx - 5760)];
        w8[(((size_t)(kx >> 3) * 64) + o) * 8 + (kx & 7)] = f2bf(v);
    } else if (blk < 1520) {
        int idx = (blk - 1456) * 256 + t;
        int g = idx >> 13, r = idx & 8191;
        int o = r >> 6, c = r & 63;
        float v = (g ? s1w : s0w)[r];
        int kt = c >> 5, q = (c >> 3) & 3, j = c & 7, nt = o >> 4, ln = o & 15;
        wcat[(size_t)((((g * 2 + kt) * 4 + q) * 8 + nt) * 16 + ln) * 8 + j] = f2bf(v);
    } else if (blk < 1584) {
        int idx = (blk - 1520) * 256 + t;
        int o = idx >> 6, c = idx & 63;
        int kt = c >> 5, q = (c >> 3) & 3, j = c & 7, nt = o >> 4, ln = o & 15;
        ipk[(size_t)(((kt * 4 + q) * 16 + nt) * 16 + ln) * 8 + j] = f2bf(ipw[idx]);
    } else {
        int idx = (blk - 1584) * 256 + t;
        int o = idx >> 7, d = idx & 127;
        int kt = d >> 5, q = (d >> 3) & 3, j = d & 7, nt = o >> 4, ln = o & 15;
        xpk[(size_t)(((kt * 4 + q) * 9 + nt) * 16 + ln) * 8 + j] = f2bf(xpw[idx]);
    }
}

// ------- fused bn_relu + 1x1 conv (64->128), channel-LAST outputs -------
__global__ void __launch_bounds__(128) k_c1all(const float* __restrict__ pool5, const float* __restrict__ pool9,
                                               const float* __restrict__ gm,
                                               const float* __restrict__ s2g, const float* __restrict__ s2b,
                                               const float* __restrict__ s2w,
                                               const float* __restrict__ s3g, const float* __restrict__ s3b,
                                               const float* __restrict__ s3w,
                                               const float* __restrict__ s4g, const float* __restrict__ s4b,
                                               const float* __restrict__ s4w,
                                               float* __restrict__ c2cl, float* __restrict__ c3cl,
                                               float* __restrict__ c4) {
    int pos = blockIdx.x;
    const float *in, *g, *bb, *w;
    float* outp;
    int HW, b, pp;
    if (pos < cB * 576) { b = pos / 576; pp = pos % 576; in = pool5; g = s2g; bb = s2b; w = s2w; HW = 576; outp = c2cl + ((size_t)b * 576 + pp) * 128; }
    else if (pos < cB * 576 + cB * 144) { int r = pos - cB * 576; b = r / 144; pp = r % 144; in = pool9; g = s3g; bb = s3b; w = s3w; HW = 144; outp = c3cl + ((size_t)b * 144 + pp) * 128; }
    else { b = pos - cB * 576 - cB * 144; pp = 0; in = gm; g = s4g; bb = s4b; w = s4w; HW = 1; outp = c4 + (size_t)b * 128; }
    __shared__ float v[64];
    int t = threadIdx.x;
    if (t < 64) v[t] = bnrelu(in[(b * 64 + t) * HW + pp], g[t], bb[t]);
    __syncthreads();
    float acc = 0.f;
    const float* wr = w + t * 64;
#pragma unroll 16
    for (int c = 0; c < 64; c++) acc += v[c] * wr[c];
    outp[t] = acc;
}

// ------- cat build: staged loads + MFMA 1x1 convs + INLINE bilinear + fused epilogue -------
__global__ void __launch_bounds__(256) k_cat2(
    const float* __restrict__ x, const float* __restrict__ pool3, const float* __restrict__ c4,
    const float* __restrict__ s0g, const float* __restrict__ s0b,
    const float* __restrict__ s1g, const float* __restrict__ s1b,
    const float* __restrict__ scg, const float* __restrict__ scb,
    const float* __restrict__ cg, const float* __restrict__ cbb,
    const u16* __restrict__ wcat, const float* __restrict__ c2cl, const float* __restrict__ c3cl,
    u16* __restrict__ catbf, u16* __restrict__ xbf) {
    int blk = blockIdx.x;
    int b = blk / 144;
    int l0 = (blk % 144) * 16;
    int t = threadIdx.x;
    __shared__ float axv[16][68];
    __shared__ float ap3[16][68];
    __shared__ u16 axc[16][66];
    int pc = t >> 4, p = t & 15;
#pragma unroll
    for (int i = 0; i < 4; i++) {
        int c = i * 16 + pc;
        float xraw = x[(size_t)(b * 64 + c) * cL + l0 + p];
        float p3raw = pool3[(size_t)(b * 64 + c) * cL + l0 + p];
        axv[p][c] = bnrelu(xraw, s0g[c], s0b[c]);
        ap3[p][c] = bnrelu(p3raw, s1g[c], s1b[c]);
        axc[p][c] = f2bf(bnrelu(xraw, scg[c], scb[c]));
    }
    __syncthreads();
#pragma unroll
    for (int i = 0; i < 4; i++) {
        int idx = i * 256 + t;
        int pp = idx >> 6, cc = idx & 63;
        xbf[((size_t)b * cL + l0 + pp) * 64 + cc] = axc[pp][cc];
    }
    int wv = t >> 6, lane = t & 63, ln = lane & 15, q = lane >> 4;
    f32x4 ax[2] = {};
    f32x4 ay[2] = {};
#pragma unroll
    for (int kt = 0; kt < 2; kt++) {
        s16x8 a0 = cvt8(&axv[ln][kt * 32 + q * 8]);
        s16x8 a1 = cvt8(&ap3[ln][kt * 32 + q * 8]);
#pragma unroll
        for (int jj = 0; jj < 2; jj++) {
            int nt = wv * 2 + jj;
            s16x8 b0 = *(const s16x8*)(wcat + (size_t)((((0 * 2 + kt) * 4 + q) * 8 + nt) * 16 + ln) * 8);
            s16x8 b1 = *(const s16x8*)(wcat + (size_t)((((1 * 2 + kt) * 4 + q) * 8 + nt) * 16 + ln) * 8);
            ax[jj] = __builtin_amdgcn_mfma_f32_16x16x32_bf16(a0, b0, ax[jj], 0, 0, 0);
            ay[jj] = __builtin_amdgcn_mfma_f32_16x16x32_bf16(a1, b1, ay[jj], 0, 0, 0);
        }
    }
    // bilinear setup (row uniform per block)
    int hrow = l0 / cW, w0g = l0 % cW;
    float sy2 = hrow * 0.5f - 0.25f;
    float fy2 = floorf(sy2); int iy2 = (int)fy2; float ay2 = sy2 - fy2;
    int y20 = min(max(iy2, 0), 23), y21 = min(max(iy2 + 1, 0), 23);
    float sy3 = hrow * 0.25f - 0.375f;
    float fy3 = floorf(sy3); int iy3 = (int)fy3; float ay3 = sy3 - fy3;
    int y30 = min(max(iy3, 0), 11), y31 = min(max(iy3 + 1, 0), 11);
    const float* c2b = c2cl + (size_t)b * 576 * 128;
    const float* c3b = c3cl + (size_t)b * 144 * 128;
#pragma unroll
    for (int r = 0; r < 4; r++) {
        int pp = q * 4 + r;
        int wq = w0g + pp;
        float sx2 = wq * 0.5f - 0.25f;
        float fx2 = floorf(sx2); int ix2 = (int)fx2; float ax2 = sx2 - fx2;
        int x20 = min(max(ix2, 0), 23), x21 = min(max(ix2 + 1, 0), 23);
        float sx3 = wq * 0.25f - 0.375f;
        float fx3 = floorf(sx3); int ix3 = (int)fx3; float ax3 = sx3 - fx3;
        int x30 = min(max(ix3, 0), 11), x31 = min(max(ix3 + 1, 0), 11);
#pragma unroll
        for (int jj = 0; jj < 2; jj++) {
            int ch = (wv * 2 + jj) * 16 + ln;
            float v00 = c2b[(y20 * 24 + x20) * 128 + ch], v01 = c2b[(y20 * 24 + x21) * 128 + ch];
            float v10 = c2b[(y21 * 24 + x20) * 128 + ch], v11 = c2b[(y21 * 24 + x21) * 128 + ch];
            float t0 = v00 + (v01 - v00) * ax2, t1 = v10 + (v11 - v10) * ax2;
            float u2v = t0 + (t1 - t0) * ay2;
            float w00 = c3b[(y30 * 12 + x30) * 128 + ch], w01 = c3b[(y30 * 12 + x31) * 128 + ch];
            float w10 = c3b[(y31 * 12 + x30) * 128 + ch], w11 = c3b[(y31 * 12 + x31) * 128 + ch];
            float s0_ = w00 + (w01 - w00) * ax3, s1_ = w10 + (w11 - w10) * ax3;
            float u3v = s0_ + (s1_ - s0_) * ay3;
            float x0 = ax[jj][r];
            float y1 = ay[jj][r] + x0;
            float y2 = x0 + u2v;
            float y3 = x0 + u3v;
            float y4 = x0 + c4[b * 128 + ch];
            u16* base = catbf + ((size_t)b * cL + l0 + pp) * 640;
            base[ch]       = f2bf(bnrelu(x0, cg[ch],       cbb[ch]));
            base[128 + ch] = f2bf(bnrelu(y1, cg[128 + ch], cbb[128 + ch]));
            base[256 + ch] = f2bf(bnrelu(y2, cg[256 + ch], cbb[256 + ch]));
            base[384 + ch] = f2bf(bnrelu(y3, cg[384 + ch], cbb[384 + ch]));
            base[512 + ch] = f2bf(bnrelu(y4, cg[512 + ch], cbb[512 + ch]));
        }
    }
}

// ------- comp 3x3 conv + shortcut: split-K MFMA GEMM -------
__global__ void __launch_bounds__(64) k_comp(const u16* __restrict__ catbf,
                                             const u16* __restrict__ xbf,
                                             const u16* __restrict__ w8,
                                             float* __restrict__ part) {
    int blk = blockIdx.x;
    int slice = blk % 9;
    int pxt = blk / 9;
    int pix0 = pxt * 16;
    int b = pix0 / cL;
    int lane = threadIdx.x;
    int ln = lane & 15, q = lane >> 4;
    int la = (pix0 + ln) - b * cL;
    int h = la / cW, w = la % cW;
    int kh = slice / 3 - 1, kw = slice % 3 - 1;
    int hh = h + kh, ww = w + kw;
    bool ok = (hh >= 0) && (hh < cH) && (ww >= 0) && (ww < cW);
    const u16* ap = catbf + ((size_t)b * cL + hh * cW + ww) * 640 + q * 8;
    f32x4 acc[4] = {};
    int kb = slice * 640;
#pragma unroll 4
    for (int cc = 0; cc < 20; cc++) {
        s16x8 av;
        if (ok) av = *(const s16x8*)(ap + cc * 32);
        else av = s16x8{0, 0, 0, 0, 0, 0, 0, 0};
        const u16* wrow = w8 + (((size_t)((kb + cc * 32) >> 3) + q) * 64) * 8;
#pragma unroll
        for (int j = 0; j < 4; j++) {
            s16x8 bv = *(const s16x8*)(wrow + (size_t)(j * 16 + ln) * 8);
            acc[j] = __builtin_amdgcn_mfma_f32_16x16x32_bf16(av, bv, acc[j], 0, 0, 0);
        }
    }
    if (slice == 4) {
        const u16* xp = xbf + (size_t)(pix0 + ln) * 64 + q * 8;
#pragma unroll
        for (int cc = 0; cc < 2; cc++) {
            s16x8 av = *(const s16x8*)(xp + cc * 32);
            const u16* wrow = w8 + (((size_t)((5760 + cc * 32) >> 3) + q) * 64) * 8;
#pragma unroll
            for (int j = 0; j < 4; j++) {
                s16x8 bv = *(const s16x8*)(wrow + (size_t)(j * 16 + ln) * 8);
                acc[j] = __builtin_amdgcn_mfma_f32_16x16x32_bf16(av, bv, acc[j], 0, 0, 0);
            }
        }
    }
    float* pb = part + ((size_t)slice * (cB * cL) + pix0) * 64;
#pragma unroll
    for (int j = 0; j < 4; j++) {
#pragma unroll
        for (int r = 0; r < 4; r++) {
            pb[(size_t)(q * 4 + r) * 64 + j * 16 + ln] = acc[j][r];
        }
    }
}

// ------- fused split-K reduce + in_proj MFMA: part -> xc (B,L,128), z (B,L,128) -------
__global__ void __launch_bounds__(256) k_ip(const float* __restrict__ part, const u16* __restrict__ ipk,
                                            float* __restrict__ xc, float* __restrict__ z) {
    int px0 = blockIdx.x * 16;
    int t = threadIdx.x;
    __shared__ float pv[16][68];
#pragma unroll
    for (int i = 0; i < 4; i++) {
        int idx = i * 256 + t;
        int p = idx >> 6, c = idx & 63;
        float s = 0.f;
#pragma unroll
        for (int sl = 0; sl < 9; sl++)
            s += part[((size_t)sl * (cB * cL) + px0 + p) * 64 + c];
        pv[p][c] = s;
    }
    __syncthreads();
    int wv = t >> 6, lane = t & 63, ln = lane & 15, q = lane >> 4;
    f32x4 acc[4] = {};
#pragma unroll
    for (int kt = 0; kt < 2; kt++) {
        s16x8 a = cvt8(&pv[ln][kt * 32 + q * 8]);
#pragma unroll
        for (int jn = 0; jn < 4; jn++) {
            int nt = wv * 4 + jn;
            s16x8 bfr = *(const s16x8*)(ipk + (size_t)(((kt * 4 + q) * 16 + nt) * 16 + ln) * 8);
            acc[jn] = __builtin_amdgcn_mfma_f32_16x16x32_bf16(a, bfr, acc[jn], 0, 0, 0);
        }
    }
#pragma unroll
    for (int jn = 0; jn < 4; jn++) {
        int o = (wv * 4 + jn) * 16 + ln;
#pragma unroll
        for (int r = 0; r < 4; r++) {
            int p = q * 4 + r;
            if (o < 128) xc[((size_t)px0 + p) * 128 + o] = acc[jn][r];
            else         z[((size_t)px0 + p) * 128 + (o - 128)] = acc[jn][r];
        }
    }
}

// ------- depthwise 3x3 + bias + silu; channel-last in/out (grid-stride, 1152 blocks) -------
__global__ void k_dw(const float* __restrict__ xc, const float* __restrict__ dww,
                     const float* __restrict__ dwb, float* __restrict__ xca) {
    int idx = blockIdx.x * 256 + threadIdx.x;
    if (idx >= cB * cL * cDI) return;
    int d = idx & 127;
    int rest = idx >> 7;
    int l = rest % cL, b = rest / cL;
    int h = l / cW, w = l % cW;
    const float* base = xc + (size_t)b * cL * 128 + d;
    float acc = dwb[d];
    const float* kw = dww + d * 9;
    for (int i = 0; i < 3; i++) {
        int hh = h + i - 1; if (hh < 0 || hh >= cH) continue;
        for (int j = 0; j < 3; j++) {
            int ww = w + j - 1; if (ww < 0 || ww >= cW) continue;
            acc += base[(size_t)(hh * cW + ww) * 128] * kw[i * 3 + j];
        }
    }
    xca[idx] = silu(acc);
}

// ------- spatial x_dbl via MFMA + fused softplus; outputs in SPATIAL order -------
// 288 blocks (16 px), 256 thr = 4 waves; N=144 split as ntiles {wv, wv+4, [8 for wv0]}
__global__ void __launch_bounds__(256) k_xdbl4(const float* __restrict__ xca, const u16* __restrict__ xpk,
                                               const float* __restrict__ dtw, const float* __restrict__ dtb,
                                               float* __restrict__ bc, float* __restrict__ delta) {
    int blk = blockIdx.x;
    int b = blk / 144;
    int l0 = (blk % 144) * 16;
    int t = threadIdx.x;
    __shared__ float av[16][132];
    __shared__ float Dt[16][148];
#pragma unroll
    for (int i = 0; i < 8; i++) {
        int id = i * 256 + t;
        int d = id & 127, p = id >> 7;
        av[p][d] = xca[((size_t)b * cL + l0 + p) * 128 + d];
    }
    __syncthreads();
    int wv = t >> 6, lane = t & 63, ln = lane & 15, q = lane >> 4;
    int nmax = (wv == 0) ? 3 : 2;
    f32x4 acc[3] = {};
#pragma unroll
    for (int kt = 0; kt < 4; kt++) {
        s16x8 a = cvt8(&av[ln][kt * 32 + q * 8]);
        for (int i = 0; i < nmax; i++) {
            int nt = (i == 2) ? 8 : wv + i * 4;
            s16x8 bfr = *(const s16x8*)(xpk + (size_t)(((kt * 4 + q) * 9 + nt) * 16 + ln) * 8);
            acc[i] = __builtin_amdgcn_mfma_f32_16x16x32_bf16(a, bfr, acc[i], 0, 0, 0);
        }
    }
    for (int i = 0; i < nmax; i++) {
        int nt = (i == 2) ? 8 : wv + i * 4;
#pragma unroll
        for (int r = 0; r < 4; r++)
            Dt[q * 4 + r][nt * 16 + ln] = acc[i][r];
    }
    __syncthreads();
    // bc out: (bk, p_spatial, 32), coalesced
#pragma unroll
    for (int i = 0; i < 8; i++) {
        int id = i * 256 + t;
        int cc = id & 31, kk = (id >> 5) & 3, p = id >> 7;
        bc[((size_t)(b * 4 + kk) * cL + l0 + p) * 32 + cc] = Dt[p][kk * 36 + 4 + cc];
    }
    // delta = softplus(dtb + dts . dtw): (bk, p_spatial, 128), coalesced
    for (int i = 0; i < 32; i++) {
        int id = i * 256 + t;
        int d = id & 127, kk = (id >> 7) & 3, p = id >> 9;
        const float* wd = dtw + (size_t)(kk * 128 + d) * 4;
        float pre = dtb[kk * 128 + d] + wd[0] * Dt[p][kk * 36] + wd[1] * Dt[p][kk * 36 + 1]
                  + wd[2] * Dt[p][kk * 36 + 2] + wd[3] * Dt[p][kk * 36 + 3];
        float dl = pre > 20.f ? pre : log1pf(expf(pre));
        delta[((size_t)(b * 4 + kk) * cL + l0 + p) * 128 + d] = dl;
    }
}

// xs index mapping: offset into the (H*W) plane for direction k at scan pos l
__device__ __forceinline__ int xs_index(int k, int l) {
    int lp = (k & 2) ? (cL - 1 - l) : l;
    if (k & 1) { int w = lp / cH, h = lp % cH; return h * cW + w; }
    return lp;
}

// ------- scan pass 1: spatial-order inputs, incremental permuted offset -------
__global__ void __launch_bounds__(256) k_scan1(const float* __restrict__ delta, const float* __restrict__ xca,
                                               const float* __restrict__ bc, const float* __restrict__ Alogs,
                                               float* __restrict__ Pend, float* __restrict__ hend) {
    int blk = blockIdx.x;            // ((bk*8+dgq)*NCH + c)
    int c = blk & 31;
    if (c == NCH - 1) return;        // last chunk's P/h never consumed
    int g = blk >> 5;
    int dgq = g & 7, bk = g >> 3;
    int k = bk & 3, b = bk >> 2;
    int t = threadIdx.x;
    int n = t & 15;
    int d = dgq * 16 + (t >> 4);
    float A = -expf(Alogs[(k * 128 + d) * 16 + n]);
    const float* dp = delta + (size_t)bk * cL * 128 + d;
    const float* xp = xca + (size_t)b * cL * 128 + d;
    const float* bp = bc + (size_t)bk * cL * 32 + n;
    int off = xs_index(k, c * CHL);
    int step = (k == 0) ? 1 : (k == 1) ? cW : (k == 2) ? -1 : -cW;
    float P = 1.f, h = 0.f;
#pragma unroll 4
    for (int i = 0; i < CHL; i++) {
        float dl = dp[(size_t)off * 128];
        float a = expf(dl * A);
        h = a * h + dl * xp[(size_t)off * 128] * bp[(size_t)off * 32];
        P *= a;
        off += step;
        if (off >= cL) off -= (cL - 1);
        else if (off < 0) off += (cL - 1);
    }
    Pend[(size_t)blk * 256 + t] = P;
    hend[(size_t)blk * 256 + t] = h;
}

// ------- scan pass 2: sequential combine; writes h_in in-place into hend -------
__global__ void __launch_bounds__(256) k_scan2(const float* __restrict__ Pend, float* __restrict__ hend) {
    int id = blockIdx.x * 256 + threadIdx.x;  // 16384 total
    int t = id & 255;
    int g = id >> 8;
    float h = 0.f;
    for (int c = 0; c < NCH; c++) {
        size_t idx = ((size_t)g * NCH + c) * 256 + t;
        float tmp = hend[idx];
        float Pv = Pend[idx];
        hend[idx] = h;
        h = Pv * h + tmp;
    }
}

// ------- scan pass 3: re-scan; y written in SPATIAL order (bk, p, 128) -------
__global__ void __launch_bounds__(256) k_scan3(const float* __restrict__ delta, const float* __restrict__ xca,
                                               const float* __restrict__ bc, const float* __restrict__ Alogs,
                                               const float* __restrict__ Dsv, const float* __restrict__ hinb,
                                               float* __restrict__ y) {
    int blk = blockIdx.x;
    int c = blk & 31;
    int g = blk >> 5;
    int dgq = g & 7, bk = g >> 3;
    int k = bk & 3, b = bk >> 2;
    int t = threadIdx.x;
    int n = t & 15;
    int d = dgq * 16 + (t >> 4);
    float A = -expf(Alogs[(k * 128 + d) * 16 + n]);
    float Dsd = Dsv[k * 128 + d];
    const float* dp = delta + (size_t)bk * cL * 128 + d;
    const float* xp = xca + (size_t)b * cL * 128 + d;
    const float* bp = bc + (size_t)bk * cL * 32 + n;
    const float* cp = bc + (size_t)bk * cL * 32 + 16 + n;
    float* yb = y + (size_t)bk * cL * 128 + d;
    int off = xs_index(k, c * CHL);
    int step = (k == 0) ? 1 : (k == 1) ? cW : (k == 2) ? -1 : -cW;
    float h = hinb[(size_t)blk * 256 + t];
#pragma unroll 2
    for (int i = 0; i < CHL; i++) {
        float dl = dp[(size_t)off * 128];
        float xv = xp[(size_t)off * 128];
        float a = expf(dl * A);
        h = a * h + dl * xv * bp[(size_t)off * 32];
        float contrib = row_sum16(h * cp[(size_t)off * 32]);
        if (n == 0) yb[(size_t)off * 128] = contrib + xv * Dsd;
        off += step;
        if (off >= cL) off -= (cL - 1);
        else if (off < 0) off += (cL - 1);
    }
}

// ------- fused tail: 4-dir sum + LN + gate + out_proj + MLP + residual -------
__global__ void __launch_bounds__(256) k_tail(const float* __restrict__ y, const float* __restrict__ z,
                                              const float* __restrict__ lng, const float* __restrict__ lnb,
                                              const float* __restrict__ opw,
                                              const float* __restrict__ f1w, const float* __restrict__ f1b,
                                              const float* __restrict__ f2w, const float* __restrict__ f2b,
                                              float* __restrict__ out) {
    int blk = blockIdx.x;
    int b = blk / 144;
    int l0 = (blk % 144) * 16;
    int t = threadIdx.x;
    __shared__ float v[16][132];
    __shared__ float x1s[16][68];
    __shared__ float h1s[16][132];
    __shared__ float mus[16], rss[16];
    const float* yb = y + (size_t)b * 4 * cL * 128;
#pragma unroll
    for (int i = 0; i < 8; i++) {
        int id = i * 256 + t;
        int d = id & 127, p = id >> 7;
        size_t base = (size_t)(l0 + p) * 128 + d;
        v[p][d] = yb[base] + yb[(size_t)cL * 128 + base] + yb[(size_t)2 * cL * 128 + base] + yb[(size_t)3 * cL * 128 + base];
    }
    __syncthreads();
    {
        int p = t >> 4, c8 = (t & 15) * 8;
        float s = 0.f;
#pragma unroll
        for (int j = 0; j < 8; j++) s += v[p][c8 + j];
        s = row_sum16(s);
        float mu = s * (1.f / 128.f);
        float s2 = 0.f;
#pragma unroll
        for (int j = 0; j < 8; j++) { float dv = v[p][c8 + j] - mu; s2 += dv * dv; }
        s2 = row_sum16(s2);
        if ((t & 15) == 0) { mus[p] = mu; rss[p] = rsqrtf(s2 * (1.f / 128.f) + cEPS); }
    }
    __syncthreads();
#pragma unroll
    for (int i = 0; i < 8; i++) {
        int id = i * 256 + t;
        int d = id & 127, p = id >> 7;
        float zz = z[((size_t)b * cL + l0 + p) * 128 + d];
        v[p][d] = ((v[p][d] - mus[p]) * rss[p] * lng[d] + lnb[d]) * silu(zz);
    }
    __syncthreads();
#pragma unroll
    for (int i = 0; i < 4; i++) {
        int id = i * 256 + t;
        int p = id & 15, o = id >> 4;
        const float* wr = opw + o * 128;
        float acc = 0.f;
#pragma unroll 16
        for (int d2 = 0; d2 < 128; d2++) acc += v[p][d2] * wr[d2];
        x1s[p][o] = acc;
    }
    __syncthreads();
#pragma unroll
    for (int i = 0; i < 8; i++) {
        int id = i * 256 + t;
        int p = id & 15, j = id >> 4;
        const float* wr = f1w + j * 64;
        float acc = f1b[j];
#pragma unroll 16
        for (int c = 0; c < 64; c++) acc += x1s[p][c] * wr[c];
        h1s[p][j] = silu(acc);
    }
    __syncthreads();
#pragma unroll
    for (int i = 0; i < 4; i++) {
        int id = i * 256 + t;
        int p = id & 15, o = id >> 4;
        const float* wr = f2w + o * 128;
        float acc = f2b[o];
#pragma unroll 16
        for (int j = 0; j < 128; j++) acc += h1s[p][j] * wr[j];
        out[((size_t)b * 64 + o) * cL + l0 + p] = acc + x1s[p][o];
    }
}

extern "C" void kernel_launch(void* const* d_in, const int* in_sizes, int n_in,
                              void* d_out, int out_size, void* d_ws, size_t ws_size,
                              hipStream_t stream) {
    (void)in_sizes; (void)n_in; (void)out_size; (void)ws_size;
    const float* x    = (const float*)d_in[0];
    const float* s0g  = (const float*)d_in[1];
    const float* s0b  = (const float*)d_in[2];
    const float* s0w  = (const float*)d_in[3];
    const float* s1g  = (const float*)d_in[4];
    const float* s1b  = (const float*)d_in[5];
    const float* s1w  = (const float*)d_in[6];
    const float* s2g  = (const float*)d_in[7];
    const float* s2b  = (const float*)d_in[8];
    const float* s2w  = (const float*)d_in[9];
    const float* s3g  = (const float*)d_in[10];
    const float* s3b  = (const float*)d_in[11];
    const float* s3w  = (const float*)d_in[12];
    const float* s4g  = (const float*)d_in[13];
    const float* s4b  = (const float*)d_in[14];
    const float* s4w  = (const float*)d_in[15];
    const float* cg   = (const float*)d_in[16];
    const float* cbb  = (const float*)d_in[17];
    const float* cw   = (const float*)d_in[18];
    const float* scg  = (const float*)d_in[19];
    const float* scb  = (const float*)d_in[20];
    const float* scw  = (const float*)d_in[21];
    const float* ipw  = (const float*)d_in[22];
    const float* dww  = (const float*)d_in[23];
    const float* dwb  = (const float*)d_in[24];
    const float* xpw  = (const float*)d_in[25];
    const float* dtw  = (const float*)d_in[26];
    const float* dtb  = (const float*)d_in[27];
    const float* Alog = (const float*)d_in[28];
    const float* Dsv  = (const float*)d_in[29];
    const float* lng  = (const float*)d_in[30];
    const float* lnb  = (const float*)d_in[31];
    const float* opw  = (const float*)d_in[32];
    const float* f1w  = (const float*)d_in[33];
    const float* f1b  = (const float*)d_in[34];
    const float* f2w  = (const float*)d_in[35];
    const float* f2b  = (const float*)d_in[36];
    float* out = (float*)d_out;

    float* ws = (float*)d_ws;
    size_t off = 0;
    // --- region A: everything here is dead before k_xdbl4; delta overlays [0, 2359296) ---
    float* pool3  = ws + off; off += 294912;   // cB*64*cL
    float* pool5  = ws + off; off += 73728;    // cB*64*576
    float* pool9  = ws + off; off += 18432;    // cB*64*144
    float* gmean  = ws + off; off += 128;      // cB*64
    float* c2cl   = ws + off; off += 147456;   // cB*576*128 (channel-last)
    float* c3cl   = ws + off; off += 36864;    // cB*144*128
    float* c4     = ws + off; off += 256;      // cB*128           -> 571776
    u16*   catbf  = (u16*)(ws + off); off += 1474560;  // cB*cL*640 u16 -> 2046336
    u16*   xbf    = (u16*)(ws + off); off += 147456;   // cB*cL*64 u16  -> 2193792
    u16*   w8     = (u16*)(ws + off); off += 186368;   // 64*KTOT u16   -> 2380160
    u16*   wcat   = (u16*)(ws + off); off += 8192;     // 2*128*64 u16  -> 2388352
    u16*   ipk    = (u16*)(ws + off); off += 8192;     // 256*64 u16    -> 2396544
    // delta overlay [0, 2359296) fits entirely inside region A (2396544) ✓
    // --- xc: written k_ip, read k_dw; AFTER region A. hend overlays it later. ---
    float* xc     = ws + off; off += 589824;   // [2396544, 2986368)
    u16*   xpk    = (u16*)(ws + off); off += 9216;     // 144*128 u16; read by k_xdbl4
    // --- live buffers ---
    float* xca    = ws + off; off += 589824;   // written k_dw, read k_xdbl4 + scans
    float* zbuf   = ws + off; off += 589824;   // written k_ip, read k_tail
    float* bcbuf  = ws + off; off += 589824;   // written k_xdbl4, read scans
    float* Pend   = ws + off; off += 524288;   // 2048*256
    float* ybuf   = ws + off; off += 2359296;  // scan3 out / part overlay
    off += 294912;                             // pad: part needs 9*294912 = 2654208 <= ybuf+pad ✓
    // overlays
    float* delta  = ws + 0;    // (bk, p_spatial, 128), written k_xdbl4
    float* hend   = xc;        // 524288 <= 589824; xc dead after k_dw, hend written scan1
    float* part   = ybuf;      // written k_comp, read k_ip; ybuf live from scan3

    k_pools<<<1640, 256, 0, stream>>>(x, pool3, pool5, pool9, gmean);
    k_prep<<<1656, 256, 0, stream>>>(cw, scw, s0w, s1w, ipw, xpw, w8, wcat, ipk, xpk);
    k_c1all<<<cB * 576 + cB * 144 + cB, 128, 0, stream>>>(pool5, pool9, gmean, s2g, s2b, s2w,
                                                          s3g, s3b, s3w, s4g, s4b, s4w, c2cl, c3cl, c4);
    k_cat2<<<cB * 144, 256, 0, stream>>>(x, pool3, c4, s0g, s0b, s1g, s1b, scg, scb, cg, cbb,
                                         wcat, c2cl, c3cl, catbf, xbf);
    k_comp<<<(cB * cL / 16) * 9, 64, 0, stream>>>(catbf, xbf, w8, part);
    k_ip<<<cB * cL / 16, 256, 0, stream>>>(part, ipk, xc, zbuf);
    k_dw<<<(cB * cL * 128 + 255) / 256, 256, 0, stream>>>(xc, dww, dwb, xca);
    k_xdbl4<<<cB * 144, 256, 0, stream>>>(xca, xpk, dtw, dtb, bcbuf, delta);
    k_scan1<<<64 * NCH, 256, 0, stream>>>(delta, xca, bcbuf, Alog, Pend, hend);
    k_scan2<<<64, 256, 0, stream>>>(Pend, hend);
    k_scan3<<<64 * NCH, 256, 0, stream>>>(delta, xca, bcbuf, Alog, Dsv, hend, ybuf);
    k_tail<<<cB * 144, 256, 0, stream>>>(ybuf, zbuf, lng, lnb, opw, f1w, f1b, f2w, f2b, out);
}